// Round 3
// baseline (3806.960 us; speedup 1.0000x reference)
//
#include <hip/hip_runtime.h>
#include <hip/hip_bf16.h>

#define NS  2048
#define RR  116
#define LLY 4
#define HD  128
#define DN  348
#define DE  13456
#define KH  16384    // 128x128 per-sample slab
#define SP  136      // padded LDS slab row stride (ushorts)
#define XZC 2560
#define C1O 1024
#define EPSF 1e-5f

typedef __attribute__((ext_vector_type(8))) short short8;
typedef __attribute__((ext_vector_type(4))) float floatx4;

static __device__ __forceinline__ ushort f2bf(float x) {
  union { __hip_bfloat16 b; ushort u; } cv;
  cv.b = __float2bfloat16(x);
  return cv.u;
}
static __device__ __forceinline__ float bf2f(ushort u) {
  union { ushort u; __hip_bfloat16 b; } cv;
  cv.u = u;
  return __bfloat162float(cv.b);
}
static __device__ __forceinline__ float fexp2(float x) {
#if __has_builtin(__builtin_amdgcn_exp2f)
  return __builtin_amdgcn_exp2f(x);
#else
  return exp2f(x);
#endif
}

#define GLDS16(gsrc, ldst) __builtin_amdgcn_global_load_lds( \
    (const __attribute__((address_space(1))) unsigned int*)(gsrc), \
    (__attribute__((address_space(3))) unsigned int*)(ldst), 16, 0, 0)

// ---------------------------------------------------------------------------
// fp32 tiled GEMM (node heads), split-K atomic accumulate (no bias/relu here;
// headpost applies bias+relu+stats afterwards). C must be pre-zeroed.
// ---------------------------------------------------------------------------
__global__ __launch_bounds__(256) void gemm64(
    const float* __restrict__ A, int lda,
    const float* __restrict__ B, int ldb,
    float* __restrict__ C, int ldc, int cof,
    int M, int N, int K)
{
  const int m0 = blockIdx.y * 64, n0 = blockIdx.x * 64;
  const int ktiles = (K + 15) >> 4;
  const int kt0 = (int)((long long)ktiles * blockIdx.z / gridDim.z);
  const int kt1 = (int)((long long)ktiles * (blockIdx.z + 1) / gridDim.z);
  __shared__ float As[16][68];
  __shared__ float Bs[16][68];
  const int t = threadIdx.x;
  const int tx = t & 15, ty = t >> 4;
  float acc[4][4] = {};
  for (int kt = kt0; kt < kt1; kt++) {
    const int kb = kt * 16;
    {
      int mm = t >> 2, kk = (t & 3) << 2;
      int gm = m0 + mm, gk = kb + kk;
      float4 v = make_float4(0.f, 0.f, 0.f, 0.f);
      if (gm < M && gk < K) v = *(const float4*)(A + (size_t)gm * lda + gk);
      As[kk + 0][mm] = v.x; As[kk + 1][mm] = v.y; As[kk + 2][mm] = v.z; As[kk + 3][mm] = v.w;
      int gn = n0 + mm;
      float4 u = make_float4(0.f, 0.f, 0.f, 0.f);
      if (gn < N && gk < K) u = *(const float4*)(B + (size_t)gn * ldb + gk);
      Bs[kk + 0][mm] = u.x; Bs[kk + 1][mm] = u.y; Bs[kk + 2][mm] = u.z; Bs[kk + 3][mm] = u.w;
    }
    __syncthreads();
#pragma unroll
    for (int kk = 0; kk < 16; kk++) {
      float4 av = *(const float4*)&As[kk][ty << 2];
      float4 bv = *(const float4*)&Bs[kk][tx << 2];
      acc[0][0] += av.x * bv.x; acc[0][1] += av.x * bv.y; acc[0][2] += av.x * bv.z; acc[0][3] += av.x * bv.w;
      acc[1][0] += av.y * bv.x; acc[1][1] += av.y * bv.y; acc[1][2] += av.y * bv.z; acc[1][3] += av.y * bv.w;
      acc[2][0] += av.z * bv.x; acc[2][1] += av.z * bv.y; acc[2][2] += av.z * bv.z; acc[2][3] += av.z * bv.w;
      acc[3][0] += av.w * bv.x; acc[3][1] += av.w * bv.y; acc[3][2] += av.w * bv.z; acc[3][3] += av.w * bv.w;
    }
    __syncthreads();
  }
#pragma unroll
  for (int i = 0; i < 4; i++) {
    int m = m0 + (ty << 2) + i;
#pragma unroll
    for (int j = 0; j < 4; j++) {
      int n = n0 + (tx << 2) + j;
      if (m < M && n < N)
        atomicAdd(&C[(size_t)m * ldc + cof + n], acc[i][j]);
    }
  }
}

// ---------------------------------------------------------------------------
// bf16 MFMA TN GEMM (big heads): C += A[M][lka]*B[N][lkb]^T, split-K atomics.
// 2-phase double-buffered staging: stage(kt+1) issued before compute(kt),
// so the barrier's vmcnt drain lands after the MFMA phase (latency hidden).
// ---------------------------------------------------------------------------
__global__ __launch_bounds__(256) void gemm_mfma_tn(
    const ushort* __restrict__ A, int lka,
    const ushort* __restrict__ B, int lkb,
    float* __restrict__ C, int ldc, int cof,
    int ktiles)
{
  __shared__ __align__(16) ushort As[2][128 * 32];
  __shared__ __align__(16) ushort Bs[2][128 * 32];
  const int t = threadIdx.x;
  const int m0 = blockIdx.y * 128, n0 = blockIdx.x * 128;
  const int kt0 = (int)((long long)ktiles * blockIdx.z / gridDim.z);
  const int kt1 = (int)((long long)ktiles * (blockIdx.z + 1) / gridDim.z);
  const int w = t >> 6, lane = t & 63;
  const int wm = (w >> 1) << 6, wn = (w & 1) << 6;
  const int fr = lane & 15, quad = lane >> 4;
  const int row0 = t >> 2, row1 = (t + 256) >> 2;
  const int ko = (t & 3) * 8;
  auto stage = [&](int kt, int b) {
    const int kb = kt * 32;
    GLDS16(A + (size_t)(m0 + row0) * lka + kb + ko, &As[b][(size_t)t * 8]);
    GLDS16(A + (size_t)(m0 + row1) * lka + kb + ko, &As[b][2048 + (size_t)t * 8]);
    GLDS16(B + (size_t)(n0 + row0) * lkb + kb + ko, &Bs[b][(size_t)t * 8]);
    GLDS16(B + (size_t)(n0 + row1) * lkb + kb + ko, &Bs[b][2048 + (size_t)t * 8]);
  };
  floatx4 acc[4][4] = {};
  stage(kt0, 0);
  __syncthreads();
  for (int kt = kt0; kt < kt1; ++kt) {
    const int cur = (kt - kt0) & 1;
    if (kt + 1 < kt1) stage(kt + 1, cur ^ 1);
    short8 af[4], bf[4];
#pragma unroll
    for (int i = 0; i < 4; i++)
      af[i] = *(const short8*)&As[cur][(wm + i * 16 + fr) * 32 + quad * 8];
#pragma unroll
    for (int j = 0; j < 4; j++)
      bf[j] = *(const short8*)&Bs[cur][(wn + j * 16 + fr) * 32 + quad * 8];
#pragma unroll
    for (int i = 0; i < 4; i++)
#pragma unroll
      for (int j = 0; j < 4; j++)
        acc[i][j] = __builtin_amdgcn_mfma_f32_16x16x32_bf16(af[i], bf[j], acc[i][j], 0, 0, 0);
    __syncthreads();
  }
#pragma unroll
  for (int i = 0; i < 4; i++) {
#pragma unroll
    for (int j = 0; j < 4; j++) {
      int n = n0 + wn + j * 16 + fr;
#pragma unroll
      for (int r = 0; r < 4; r++) {
        int m = m0 + wm + i * 16 + quad * 4 + r;
        atomicAdd(&C[(size_t)m * ldc + cof + n], acc[i][j][r]);
      }
    }
  }
}

// ---------------------------------------------------------------------------
// fusedG12: per sample s:
//   G1: Vt[l][o] = sum_i Z[l][i]*w2[o][i] + b2[o]   (split-bf16, acc fp32)
//   G2: A[m][l]  = sum_k Vt[m][k]*att[l][k]         (att generated in-regs)
//   X1: X1[m]    = (A @ X) @ node_w  (+ fused X-branch BN stats)
// LDS: stage dbuf (2x32KB) / Vt slabs / fp32 A all union one pool -> 2 blk/CU.
// G1 is 2-phase double-buffered (stage kt+1 before compute kt).
// Softmax precompute reads Kf from global (uniform-address L2 broadcast) so it
// overlaps the stage-0 latency; single prologue barrier.
// ---------------------------------------------------------------------------
__global__ __launch_bounds__(256) void fusedG12(
    const ushort* __restrict__ ZHi, const ushort* __restrict__ ZLo,
    const ushort* __restrict__ WHi, const ushort* __restrict__ WLo,
    const float* __restrict__ b2, const float* __restrict__ Kf,
    ushort* __restrict__ AHi, ushort* __restrict__ ALo,
    const float* __restrict__ Xg, const float* __restrict__ nw,
    float* __restrict__ X1, float* __restrict__ xsum, float* __restrict__ xsq)
{
  // union pool: [G1 loop] stage dbuf 2x16384 ushorts | [G1 epi..G2] Vt hi/lo
  //             | [epilogue] fp32 A [128][133]
  __shared__ __align__(16) ushort pool[2 * 128 * SP];   // 69632 B
  ushort* VtHi = pool;
  ushort* VtLo = pool + 128 * SP;
  __shared__ float Ks0[128], Ks1[128], Ks2[128], Mrow[128], Minv[128];
  __shared__ float Xs[DN];
  const int s = blockIdx.x;
  const int t = threadIdx.x;
  const int w = t >> 6, lane = t & 63;
  const int wm = (w >> 1) << 6, wn = (w & 1) << 6;
  const int fr = lane & 15, quad = lane >> 4;
  const int r0 = t >> 2, c8 = (t & 3) * 8;

  auto stage = [&](int kt, int b) {
    ushort* bb = pool + b * 16384;
    const int kb = kt * 32;
    const size_t go = (size_t)s * KH + (size_t)r0 * 128 + kb + c8;
    GLDS16(ZHi + go,            bb + t * 8);
    GLDS16(ZHi + go + 64 * 128, bb + 2048 + t * 8);
    GLDS16(ZLo + go,            bb + 4096 + t * 8);
    GLDS16(ZLo + go + 64 * 128, bb + 6144 + t * 8);
    const size_t wo = (size_t)r0 * 128 + kb + c8;
    GLDS16(WHi + wo,            bb + 8192 + t * 8);
    GLDS16(WHi + wo + 64 * 128, bb + 10240 + t * 8);
    GLDS16(WLo + wo,            bb + 12288 + t * 8);
    GLDS16(WLo + wo + 64 * 128, bb + 14336 + t * 8);
  };

  stage(0, 0);   // stage-0 latency hides under the softmax precompute below
  const float lam  = 1.2011224087864498f;   // sqrt(log2 e)
  const float lam2 = 1.4426950408889634f;   // log2 e
  if (t < 128) {
    const float* kf = Kf + (size_t)s * 384;
    Ks0[t] = kf[t] * lam; Ks1[t] = kf[128 + t] * lam; Ks2[t] = kf[256 + t] * lam;
  }
  for (int ii = t; ii < DN; ii += 256) Xs[ii] = Xg[(size_t)s * DN + ii];
  if (t < 128) {
    if (t < RR) {
      const float* kf = Kf + (size_t)s * 384;
      float k0 = kf[t] * lam2, k1 = kf[128 + t] * lam2, k2 = kf[256 + t] * lam2;
      float mx = -3.0e38f;
      for (int k = 0; k < RR; k++)
        mx = fmaxf(mx, k0 * kf[k] + k1 * kf[128 + k] + k2 * kf[256 + k]);
      float sm = 0.f;
      for (int k = 0; k < RR; k++)
        sm += fexp2(k0 * kf[k] + k1 * kf[128 + k] + k2 * kf[256 + k] - mx);
      Mrow[t] = mx; Minv[t] = 1.f / sm;
    } else { Mrow[t] = 0.f; Minv[t] = 0.f; }
  }
  __syncthreads();   // Ks/Xs/Mrow visible + stage-0 drained

  // ---- G1 (2-phase dbuf) ----
  floatx4 acc[4][4] = {};
  for (int kt = 0; kt < 4; kt++) {
    const int cur = kt & 1;
    if (kt < 3) stage(kt + 1, cur ^ 1);
    const ushort* bb = pool + cur * 16384;
    short8 ah[4], al[4], bh[4], bl[4];
#pragma unroll
    for (int i = 0; i < 4; i++) {
      ah[i] = *(const short8*)&bb[(wm + i * 16 + fr) * 32 + quad * 8];
      al[i] = *(const short8*)&bb[4096 + (wm + i * 16 + fr) * 32 + quad * 8];
    }
#pragma unroll
    for (int j = 0; j < 4; j++) {
      bh[j] = *(const short8*)&bb[8192 + (wn + j * 16 + fr) * 32 + quad * 8];
      bl[j] = *(const short8*)&bb[12288 + (wn + j * 16 + fr) * 32 + quad * 8];
    }
#pragma unroll
    for (int i = 0; i < 4; i++)
#pragma unroll
      for (int j = 0; j < 4; j++) {
        acc[i][j] = __builtin_amdgcn_mfma_f32_16x16x32_bf16(ah[i], bh[j], acc[i][j], 0, 0, 0);
        acc[i][j] = __builtin_amdgcn_mfma_f32_16x16x32_bf16(al[i], bh[j], acc[i][j], 0, 0, 0);
        acc[i][j] = __builtin_amdgcn_mfma_f32_16x16x32_bf16(ah[i], bl[j], acc[i][j], 0, 0, 0);
      }
    __syncthreads();   // drains next-tile loads after compute; read-safety for dbuf
  }
  // bias + split into LDS Vt slabs (stage buffers dead past the final barrier)
#pragma unroll
  for (int i = 0; i < 4; i++) {
#pragma unroll
    for (int j = 0; j < 4; j++) {
      int n = wn + j * 16 + fr;
      float bb = (n < RR) ? b2[n] : 0.f;
#pragma unroll
      for (int r = 0; r < 4; r++) {
        int m = wm + i * 16 + quad * 4 + r;
        float v = acc[i][j][r] + bb;
        ushort h = f2bf(v);
        VtHi[m * SP + n] = h;
        VtLo[m * SP + n] = f2bf(v - bf2f(h));
      }
    }
  }
  __syncthreads();
  // ---- G2 ----
  float Lk0[4], Lk1[4], Lk2[4], Lnm[4];
#pragma unroll
  for (int j = 0; j < 4; j++) {
    int l = wn + j * 16 + fr;
    Lk0[j] = Ks0[l]; Lk1[j] = Ks1[l]; Lk2[j] = Ks2[l]; Lnm[j] = -Mrow[l];
  }
  floatx4 ac2[4][4] = {};
  for (int kt = 0; kt < 4; kt++) {
    const int kb = kt * 32;
    float K0e[8], K1e[8], K2e[8];
#pragma unroll
    for (int e = 0; e < 8; e++) {
      int k = kb + quad * 8 + e;
      K0e[e] = Ks0[k]; K1e[e] = Ks1[k]; K2e[e] = Ks2[k];
    }
    short8 ah[4], al[4];
#pragma unroll
    for (int i = 0; i < 4; i++) {
      ah[i] = *(const short8*)&VtHi[(wm + i * 16 + fr) * SP + kb + quad * 8];
      al[i] = *(const short8*)&VtLo[(wm + i * 16 + fr) * SP + kb + quad * 8];
    }
#pragma unroll
    for (int j = 0; j < 4; j++) {
      // no l/k guards: Vt[:,k>=RR]=0 kills k-pads; Minv[l>=RR]=0 kills l-pads
      short8 bh, bl;
#pragma unroll
      for (int e = 0; e < 8; e++) {
        float d = fmaf(Lk0[j], K0e[e], Lnm[j]);
        d = fmaf(Lk1[j], K1e[e], d);
        d = fmaf(Lk2[j], K2e[e], d);
        float a = fexp2(d);
        ushort h = f2bf(a);
        ((ushort*)&bh)[e] = h;
        ((ushort*)&bl)[e] = f2bf(a - bf2f(h));
      }
#pragma unroll
      for (int i = 0; i < 4; i++) {
        ac2[i][j] = __builtin_amdgcn_mfma_f32_16x16x32_bf16(ah[i], bh, ac2[i][j], 0, 0, 0);
        ac2[i][j] = __builtin_amdgcn_mfma_f32_16x16x32_bf16(al[i], bh, ac2[i][j], 0, 0, 0);
        ac2[i][j] = __builtin_amdgcn_mfma_f32_16x16x32_bf16(ah[i], bl, ac2[i][j], 0, 0, 0);
      }
    }
  }
  // all Vt reads done -> pool reusable as fp32 A [128][133]
  __syncthreads();
  float* Af = (float*)pool;
  ushort* CH = AHi + (size_t)s * KH;
  ushort* CL = ALo + (size_t)s * KH;
#pragma unroll
  for (int i = 0; i < 4; i++) {
#pragma unroll
    for (int j = 0; j < 4; j++) {
      int n = wn + j * 16 + fr;
      float iv = Minv[n];   // 0 for n>=RR -> pad cols stay 0
#pragma unroll
      for (int r = 0; r < 4; r++) {
        int m = wm + i * 16 + quad * 4 + r;
        float v = ac2[i][j][r] * iv;
        ushort h = f2bf(v);
        CH[m * 128 + n] = h;
        CL[m * 128 + n] = f2bf(v - bf2f(h));
        Af[m * 133 + n] = v;
      }
    }
  }
  __syncthreads();
  // ---- X1 = (A @ X) @ node_w + fused X-branch BN stats ----
  if (t < RR) {
    float t0 = 0.f, t1 = 0.f, t2 = 0.f;
    const float* ar = Af + t * 133;
    for (int l = 0; l < RR; l++) {
      float p = ar[l];
      t0 += p * Xs[l * 3 + 0];
      t1 += p * Xs[l * 3 + 1];
      t2 += p * Xs[l * 3 + 2];
    }
    float o0 = t0 * nw[0] + t1 * nw[3] + t2 * nw[6];
    float o1 = t0 * nw[1] + t1 * nw[4] + t2 * nw[7];
    float o2 = t0 * nw[2] + t1 * nw[5] + t2 * nw[8];
    float* Op = X1 + (size_t)s * DN + t * 3;
    Op[0] = o0; Op[1] = o1; Op[2] = o2;
    atomicAdd(&xsum[t], o0 + o1 + o2);
    atomicAdd(&xsq[t], o0 * o0 + o1 * o1 + o2 * o2);
  }
}

// ---------------------------------------------------------------------------
// fusedG34: per sample s:
//   G3: W1[j][l] = sum_k Z[j][k]*ewT[l][k]   -> W1T hi/lo slab in LDS (dbuf)
//   G4: Z2[i][l] = sum_j A[i][j]*W1T[l][j]   -> split store in place over A
//   + fused edge-branch BN stats (channel = row i) from fp32 registers
// ---------------------------------------------------------------------------
__global__ __launch_bounds__(256) void fusedG34(
    const ushort* __restrict__ ZHi, const ushort* __restrict__ ZLo,
    const ushort* __restrict__ EHi, const ushort* __restrict__ ELo,
    ushort* __restrict__ AHi, ushort* __restrict__ ALo,
    float* __restrict__ zsum, float* __restrict__ zsq)
{
  __shared__ __align__(16) ushort pool[2 * 128 * SP];   // 69632 B
  ushort* WtHi = pool;
  ushort* WtLo = pool + 128 * SP;
  const int s = blockIdx.x;
  const int t = threadIdx.x;
  const int w = t >> 6, lane = t & 63;
  const int wm = (w >> 1) << 6, wn = (w & 1) << 6;
  const int fr = lane & 15, quad = lane >> 4;
  const int r0 = t >> 2, c8 = (t & 3) * 8;

  auto stage = [&](int kt, int b) {
    ushort* bb = pool + b * 16384;
    const int kb = kt * 32;
    const size_t go = (size_t)s * KH + (size_t)r0 * 128 + kb + c8;
    GLDS16(ZHi + go,            bb + t * 8);
    GLDS16(ZHi + go + 64 * 128, bb + 2048 + t * 8);
    GLDS16(ZLo + go,            bb + 4096 + t * 8);
    GLDS16(ZLo + go + 64 * 128, bb + 6144 + t * 8);
    const size_t eo = (size_t)r0 * 128 + kb + c8;
    GLDS16(EHi + eo,            bb + 8192 + t * 8);
    GLDS16(EHi + eo + 64 * 128, bb + 10240 + t * 8);
    GLDS16(ELo + eo,            bb + 12288 + t * 8);
    GLDS16(ELo + eo + 64 * 128, bb + 14336 + t * 8);
  };

  // ---- G3 (2-phase dbuf) ----
  floatx4 acc[4][4] = {};
  stage(0, 0);
  __syncthreads();
  for (int kt = 0; kt < 4; kt++) {
    const int cur = kt & 1;
    if (kt < 3) stage(kt + 1, cur ^ 1);
    const ushort* bb = pool + cur * 16384;
    short8 ah[4], al[4], bh[4], bl[4];
#pragma unroll
    for (int i = 0; i < 4; i++) {
      ah[i] = *(const short8*)&bb[(wm + i * 16 + fr) * 32 + quad * 8];
      al[i] = *(const short8*)&bb[4096 + (wm + i * 16 + fr) * 32 + quad * 8];
    }
#pragma unroll
    for (int j = 0; j < 4; j++) {
      bh[j] = *(const short8*)&bb[8192 + (wn + j * 16 + fr) * 32 + quad * 8];
      bl[j] = *(const short8*)&bb[12288 + (wn + j * 16 + fr) * 32 + quad * 8];
    }
#pragma unroll
    for (int i = 0; i < 4; i++)
#pragma unroll
      for (int j = 0; j < 4; j++) {
        acc[i][j] = __builtin_amdgcn_mfma_f32_16x16x32_bf16(ah[i], bh[j], acc[i][j], 0, 0, 0);
        acc[i][j] = __builtin_amdgcn_mfma_f32_16x16x32_bf16(al[i], bh[j], acc[i][j], 0, 0, 0);
        acc[i][j] = __builtin_amdgcn_mfma_f32_16x16x32_bf16(ah[i], bl[j], acc[i][j], 0, 0, 0);
      }
    __syncthreads();
  }
  // transposed split store W1 -> W1T slabs (stage buffers dead past barrier)
#pragma unroll
  for (int i = 0; i < 4; i++) {
#pragma unroll
    for (int j = 0; j < 4; j++) {
      int n = wn + j * 16 + fr;
      int mb = wm + i * 16 + quad * 4;
      ushort4 ph, pl;
#pragma unroll
      for (int r = 0; r < 4; r++) {
        float v = acc[i][j][r];
        ushort h = f2bf(v);
        ((ushort*)&ph)[r] = h;
        ((ushort*)&pl)[r] = f2bf(v - bf2f(h));
      }
      *(ushort4*)&WtHi[n * SP + mb] = ph;
      *(ushort4*)&WtLo[n * SP + mb] = pl;
    }
  }
  __syncthreads();
  // ---- G4 ----  (A fragments straight from global; Wt from LDS; no barriers)
  const ushort* GAh = AHi + (size_t)s * KH;
  const ushort* GAl = ALo + (size_t)s * KH;
  floatx4 ac2[4][4] = {};
  for (int kt = 0; kt < 4; kt++) {
    const int kb = kt * 32;
    short8 ah[4], al[4], bh[4], bl[4];
#pragma unroll
    for (int i = 0; i < 4; i++) {
      const size_t ro = (size_t)(wm + i * 16 + fr) * 128 + kb + quad * 8;
      ah[i] = *(const short8*)(GAh + ro);
      al[i] = *(const short8*)(GAl + ro);
    }
#pragma unroll
    for (int j = 0; j < 4; j++) {
      bh[j] = *(const short8*)&WtHi[(wn + j * 16 + fr) * SP + kb + quad * 8];
      bl[j] = *(const short8*)&WtLo[(wn + j * 16 + fr) * SP + kb + quad * 8];
    }
#pragma unroll
    for (int i = 0; i < 4; i++)
#pragma unroll
      for (int j = 0; j < 4; j++) {
        ac2[i][j] = __builtin_amdgcn_mfma_f32_16x16x32_bf16(ah[i], bh[j], ac2[i][j], 0, 0, 0);
        ac2[i][j] = __builtin_amdgcn_mfma_f32_16x16x32_bf16(al[i], bh[j], ac2[i][j], 0, 0, 0);
        ac2[i][j] = __builtin_amdgcn_mfma_f32_16x16x32_bf16(ah[i], bl[j], ac2[i][j], 0, 0, 0);
      }
  }
  // all waves must finish READING A before anyone overwrites it in place
  __syncthreads();
  ushort* CH = AHi + (size_t)s * KH;
  ushort* CL = ALo + (size_t)s * KH;
#pragma unroll
  for (int i = 0; i < 4; i++) {
#pragma unroll
    for (int j = 0; j < 4; j++) {
      int n = wn + j * 16 + fr;
#pragma unroll
      for (int r = 0; r < 4; r++) {
        int m = wm + i * 16 + quad * 4 + r;
        float v = ac2[i][j][r];
        ushort h = f2bf(v);
        CH[m * 128 + n] = h;
        CL[m * 128 + n] = f2bf(v - bf2f(h));
      }
    }
  }
  // fused BN stats: channel = row m; sum over this wave's 64 cols via 16-lane
  // shfl reduction (cols n>=RR are exact zeros -> harmless)
#pragma unroll
  for (int i = 0; i < 4; i++) {
#pragma unroll
    for (int r = 0; r < 4; r++) {
      int m = wm + i * 16 + quad * 4 + r;
      float a = 0.f, q = 0.f;
#pragma unroll
      for (int j = 0; j < 4; j++) { float v = ac2[i][j][r]; a += v; q += v * v; }
      a += __shfl_xor(a, 1); q += __shfl_xor(q, 1);
      a += __shfl_xor(a, 2); q += __shfl_xor(q, 2);
      a += __shfl_xor(a, 4); q += __shfl_xor(q, 4);
      a += __shfl_xor(a, 8); q += __shfl_xor(q, 8);
      if ((lane & 15) == 0 && m < RR) {
        atomicAdd(&zsum[m], a);
        atomicAdd(&zsq[m], q);
      }
    }
  }
}

// K precompute: Kf[s][c*128+l] = conv1_w[c]·X[s][l] + b[c]  (0 for l>=RR)
__global__ void kprep(const float* __restrict__ Xb, const float* __restrict__ kw,
                      const float* __restrict__ kb, float* __restrict__ Kf)
{
  int idx = blockIdx.x * 256 + threadIdx.x;
  if (idx >= NS * 384) return;
  int s = idx / 384, r = idx - s * 384;
  int c = r >> 7, l = r & 127;
  float v = 0.f;
  if (l < RR) {
    const float* xp = Xb + (size_t)s * DN + l * 3;
    v = kw[c * 3 + 0] * xp[0] + kw[c * 3 + 1] * xp[1] + kw[c * 3 + 2] * xp[2] + kb[c];
  }
  Kf[idx] = v;
}

// initial Z -> hi/lo slabs (zero-padded)
__global__ __launch_bounds__(256) void cvtZ0(
    const float* __restrict__ Z, ushort* __restrict__ ZHi, ushort* __restrict__ ZLo)
{
  const int s = blockIdx.x;
  const float* Zp = Z + (size_t)s * DE;
  ushort* h = ZHi + (size_t)s * KH;
  ushort* lo = ZLo + (size_t)s * KH;
  for (int idx = threadIdx.x; idx < KH; idx += 256) {
    int l = idx >> 7, i = idx & 127;
    if ((l < RR) && (i < RR)) {
      float v = Zp[l * RR + i];
      ushort hh = f2bf(v);
      h[idx] = hh; lo[idx] = f2bf(v - bf2f(hh));
    } else { h[idx] = 0; lo[idx] = 0; }
  }
}

// weight prep: w2 pair [o][i]; ewT pair [l][k]=ew[k][l]  (padded, all layers)
__global__ void wprep2(const float* __restrict__ w2, const float* __restrict__ ew,
                       ushort* __restrict__ w2Hi, ushort* __restrict__ w2Lo,
                       ushort* __restrict__ eHi, ushort* __restrict__ eLo)
{
  int idx = blockIdx.x * 256 + threadIdx.x;   // 4*16384
  int ly = idx >> 14, k = idx & (KH - 1);
  int r = k >> 7, c = k & 127;
  bool v = (r < RR) && (c < RR);
  float a = v ? w2[ly * DE + r * RR + c] : 0.f;
  float b = v ? ew[ly * DE + c * RR + r] : 0.f;
  ushort ha = f2bf(a), hb = f2bf(b);
  w2Hi[idx] = ha; w2Lo[idx] = f2bf(a - bf2f(ha));
  eHi[idx] = hb; eLo[idx] = f2bf(b - bf2f(hb));
}

// lew head weights: [384][13456] fp32 -> [384][16384] bf16 hole-padded
__global__ void lewprep(const float* __restrict__ src, ushort* __restrict__ dst)
{
  int idx = blockIdx.x * 256 + threadIdx.x;   // 384*16384
  int h = idx >> 14, k = idx & (KH - 1);
  int l = k >> 7, i = k & 127;
  bool v = (l < RR) && (i < RR);
  dst[idx] = v ? f2bf(src[(size_t)h * DE + l * RR + i]) : (ushort)0;
}

// fp32 -> bf16 plain convert (c1 weights)
__global__ void cvt_pad(const float* __restrict__ src, ushort* __restrict__ dst,
                        long long total)
{
  long long idx = (long long)blockIdx.x * 256 + threadIdx.x;
  if (idx < total) dst[idx] = f2bf(src[idx]);
}

// ---------------------------------------------------------------------------
// BN helpers
// ---------------------------------------------------------------------------
__global__ __launch_bounds__(256) void headpost(
    float* __restrict__ Y, int ldy, int cof, int ncols, int chunk,
    const float* __restrict__ bias,
    float* __restrict__ sum, float* __restrict__ sq)
{
  const int cl = threadIdx.x & 63;
  const int c = blockIdx.x * 64 + cl;
  const int r4 = threadIdx.x >> 6;
  const int s0 = blockIdx.y * chunk;
  float a = 0.f, q = 0.f;
  if (c < ncols) {
    float bb = bias[c];
    for (int r = s0 + r4; r < s0 + chunk; r += 4) {
      size_t o = (size_t)r * ldy + cof + c;
      float v = fmaxf(Y[o] + bb, 0.f);
      Y[o] = v;
      a += v; q += v * v;
    }
  }
  __shared__ float la[4][64], lq[4][64];
  la[r4][cl] = a; lq[r4][cl] = q;
  __syncthreads();
  if (threadIdx.x < 64) {
    int cc = blockIdx.x * 64 + threadIdx.x;
    if (cc < ncols) {
      float aa = la[0][threadIdx.x] + la[1][threadIdx.x] + la[2][threadIdx.x] + la[3][threadIdx.x];
      float qq = lq[0][threadIdx.x] + lq[1][threadIdx.x] + lq[2][threadIdx.x] + lq[3][threadIdx.x];
      atomicAdd(&sum[cc], aa);
      atomicAdd(&sq[cc], qq);
    }
  }
}

template<int NC>
__global__ void colnormb(const float* __restrict__ Y, ushort* __restrict__ Yb,
                         int ldy, int cof, float rinv,
                         const float* __restrict__ sum, const float* __restrict__ sq,
                         const float* __restrict__ g, const float* __restrict__ b,
                         unsigned total)
{
  unsigned idx = blockIdx.x * 256u + threadIdx.x;
  if (idx >= total) return;
  unsigned r = idx / NC, c = idx - r * NC;
  float m = sum[c] * rinv;
  float v = sq[c] * rinv - m * m;
  float iv = rsqrtf(v + EPSF);
  size_t o = (size_t)r * ldy + cof + c;
  Yb[o] = f2bf((Y[o] - m) * iv * g[c] + b[c]);
}

// Z master (hi/lo) += relu(bn(Z2 pair))
__global__ void ncl_updatez_pair(
    ushort* __restrict__ ZHi, ushort* __restrict__ ZLo,
    const ushort* __restrict__ Z2Hi, const ushort* __restrict__ Z2Lo,
    const float* __restrict__ g, const float* __restrict__ b,
    const float* __restrict__ sum, const float* __restrict__ sq)
{
  unsigned idx = blockIdx.x * 256u + threadIdx.x;
  if (idx >= (unsigned)NS * DE) return;
  unsigned s = idx / DE, rem = idx - s * DE;
  unsigned i = rem / RR, l = rem - i * RR;
  size_t off = (size_t)s * KH + i * 128 + l;
  const float invcnt = 1.f / (float)(NS * RR);
  float m = sum[i] * invcnt;
  float v = sq[i] * invcnt - m * m;
  float iv = rsqrtf(v + EPSF);
  float z2 = bf2f(Z2Hi[off]) + bf2f(Z2Lo[off]);
  float z = (z2 - m) * iv * g[i] + b[i];
  float nv = bf2f(ZHi[off]) + bf2f(ZLo[off]) + fmaxf(z, 0.f);
  ushort h = f2bf(nv);
  ZHi[off] = h;
  ZLo[off] = f2bf(nv - bf2f(h));
}

template<int LC>
__global__ void ncl_update(float* __restrict__ dst, const float* __restrict__ src,
                           const float* __restrict__ g, const float* __restrict__ b,
                           const float* __restrict__ sum, const float* __restrict__ sq,
                           float invcnt, unsigned total)
{
  unsigned idx = blockIdx.x * 256u + threadIdx.x;
  if (idx >= total) return;
  int c = (int)((idx / LC) % RR);
  float m = sum[c] * invcnt;
  float v = sq[c] * invcnt - m * m;
  float iv = rsqrtf(v + EPSF);
  float z = (src[idx] - m) * iv * g[c] + b[c];
  dst[idx] += fmaxf(z, 0.f);
}

__global__ void hpost(float* __restrict__ Hh, const float* __restrict__ b, unsigned total)
{
  unsigned idx = blockIdx.x * 256u + threadIdx.x;
  if (idx >= total) return;
  Hh[idx] = fmaxf(Hh[idx] + b[idx & (C1O - 1)], 0.f);
}

__global__ __launch_bounds__(256) void c2k(const float* __restrict__ Hh,
                                           const float* __restrict__ w,
                                           const float* __restrict__ b,
                                           float* __restrict__ out)
{
  const int s = blockIdx.x;
  float a0 = 0.f, a1 = 0.f;
  for (int j = threadIdx.x; j < C1O; j += 256) {
    float h = Hh[(size_t)s * C1O + j];
    a0 += h * w[j];
    a1 += h * w[C1O + j];
  }
  for (int o = 32; o; o >>= 1) { a0 += __shfl_down(a0, o); a1 += __shfl_down(a1, o); }
  __shared__ float p0[4], p1[4];
  const int wv = threadIdx.x >> 6;
  if ((threadIdx.x & 63) == 0) { p0[wv] = a0; p1[wv] = a1; }
  __syncthreads();
  if (threadIdx.x == 0) {
    out[s * 2 + 0] = p0[0] + p0[1] + p0[2] + p0[3] + b[0];
    out[s * 2 + 1] = p1[0] + p1[1] + p1[2] + p1[3] + b[1];
  }
}

// ---------------------------------------------------------------------------
extern "C" void kernel_launch(void* const* d_in, const int* in_sizes, int n_in,
                              void* d_out, int out_size, void* d_ws, size_t ws_size,
                              hipStream_t stream)
{
  const float* X    = (const float*)d_in[0];
  const float* Z    = (const float*)d_in[1];
  const float* cv1w = (const float*)d_in[2];
  const float* cv1b = (const float*)d_in[3];
  const float* cv2w = (const float*)d_in[4];
  const float* cv2b = (const float*)d_in[5];
  const float* nw   = (const float*)d_in[6];
  const float* ew   = (const float*)d_in[7];
  const float* bng  = (const float*)d_in[8];
  const float* bnb  = (const float*)d_in[9];
  const float* beg  = (const float*)d_in[10];
  const float* beb  = (const float*)d_in[11];
  const float* lnw  = (const float*)d_in[12];
  const float* lnb  = (const float*)d_in[13];
  const float* lng  = (const float*)d_in[14];
  const float* lnbt = (const float*)d_in[15];
  const float* lew  = (const float*)d_in[16];
  const float* leb  = (const float*)d_in[17];
  const float* leg  = (const float*)d_in[18];
  const float* lebt = (const float*)d_in[19];
  const float* fc1w = (const float*)d_in[20];
  const float* fc1b = (const float*)d_in[21];
  const float* fc2w = (const float*)d_in[22];
  const float* fc2b = (const float*)d_in[23];
  float* out = (float*)d_out;

  // workspace layout (~320 MiB total, well under proven 381.5 MB)
  char* base = (char*)d_ws;
  ushort* ZHi  = (ushort*)base;                     base += (size_t)NS * KH * 2;
  ushort* ZLo  = (ushort*)base;                     base += (size_t)NS * KH * 2;
  ushort* ARHi = (ushort*)base;                     base += (size_t)NS * KH * 2;
  ushort* ARLo = (ushort*)base;                     base += (size_t)NS * KH * 2;
  ushort* XZb  = (ushort*)base;                     base += (size_t)NS * XZC * 2;
  ushort* c1wh = (ushort*)base;                     base += (size_t)C1O * XZC * 2;
  ushort* lewh = (ushort*)base;                     base += (size_t)384 * KH * 2;
  ushort* w2Hi = (ushort*)base;                     base += (size_t)4 * KH * 2;
  ushort* w2Lo = (ushort*)base;                     base += (size_t)4 * KH * 2;
  ushort* eHi  = (ushort*)base;                     base += (size_t)4 * KH * 2;
  ushort* eLo  = (ushort*)base;                     base += (size_t)4 * KH * 2;
  float* Xb = (float*)base;                         base += (size_t)NS * DN * 4;
  float* X1 = (float*)base;                         base += (size_t)NS * DN * 4;
  float* XZ = (float*)base;                         base += (size_t)NS * XZC * 4;
  float* HH = (float*)base;                         base += (size_t)NS * C1O * 4;
  float* Kf = (float*)base;                         base += (size_t)NS * 384 * 4;
  float* ST = (float*)base;

  hipMemcpyAsync(Xb, X, sizeof(float) * (size_t)NS * DN, hipMemcpyDeviceToDevice, stream);
  hipMemsetAsync(XZ, 0, sizeof(float) * (size_t)NS * XZC, stream);
  hipMemsetAsync(HH, 0, sizeof(float) * (size_t)NS * C1O, stream);
  cvt_pad<<<(unsigned)(((long long)C1O * XZC + 255) / 256), 256, 0, stream>>>(
      fc1w, c1wh, (long long)C1O * XZC);
  wprep2<<<(4 * KH) / 256, 256, 0, stream>>>(cv2w, ew, w2Hi, w2Lo, eHi, eLo);
  cvtZ0<<<NS, 256, 0, stream>>>(Z, ZHi, ZLo);

  const float rinv = 1.f / (float)NS;

  auto head384 = [&](int hd, int cof) {
    lewprep<<<(384 * KH) / 256, 256, 0, stream>>>(lew + (size_t)hd * 384 * DE, lewh);
    gemm_mfma_tn<<<dim3(3, 16, 12), 256, 0, stream>>>(
        ZHi, KH, lewh, KH, XZ, XZC, cof, KH / 32);
    hipMemsetAsync(ST, 0, sizeof(float) * 768, stream);
    headpost<<<dim3(6, 8), 256, 0, stream>>>(XZ, XZC, cof, 384, 256,
                                             leb + hd * 384, ST, ST + 384);
    colnormb<384><<<(NS * 384 + 255) / 256, 256, 0, stream>>>(
        XZ, XZb, XZC, cof, rinv, ST, ST + 384, leg + hd * 384, lebt + hd * 384, NS * 384);
  };
  auto head128 = [&](int hd, int cof) {
    gemm64<<<dim3(2, NS / 64, 4), 256, 0, stream>>>(
        Xb, DN, lnw + (size_t)hd * HD * DN, DN, XZ, XZC, cof, NS, HD, DN);
    hipMemsetAsync(ST, 0, sizeof(float) * 768, stream);
    headpost<<<dim3(2, 8), 256, 0, stream>>>(XZ, XZC, cof, HD, 256,
                                             lnb + hd * HD, ST, ST + 384);
    colnormb<HD><<<(NS * HD + 255) / 256, 256, 0, stream>>>(
        XZ, XZb, XZC, cof, rinv, ST, ST + 384, lng + hd * HD, lnbt + hd * HD, NS * HD);
  };

  head128(0, 0);
  head384(0, 640);

  for (int i = 0; i < LLY; i++) {
    // K for this layer (old X)
    kprep<<<(NS * 384 + 255) / 256, 256, 0, stream>>>(Xb, cv1w + i * 9, cv1b + i * 3, Kf);
    // zero BN-stat slots (filled by fused epilogues below)
    hipMemsetAsync(ST + 768, 0, sizeof(float) * 512, stream);
    // G1+G2 fused + in-block X1 (=pTx_node) + fused X-branch stats
    fusedG12<<<NS, 256, 0, stream>>>(ZHi, ZLo, w2Hi + (size_t)i * KH, w2Lo + (size_t)i * KH,
                                     cv2b + i * RR, Kf, ARHi, ARLo,
                                     Xb, nw + i * 9, X1,
                                     ST + 768 + 256, ST + 768 + 384);
    // G3+G4 fused: Z2 pair in place over A_ref pair + fused edge-branch stats
    fusedG34<<<NS, 256, 0, stream>>>(ZHi, ZLo, eHi + (size_t)i * KH, eLo + (size_t)i * KH,
                                     ARHi, ARLo, ST + 768, ST + 768 + 128);
    // BN + residual
    ncl_updatez_pair<<<((unsigned)NS * DE + 255) / 256, 256, 0, stream>>>(
        ZHi, ZLo, ARHi, ARLo, beg + i * RR, beb + i * RR, ST + 768, ST + 768 + 128);
    ncl_update<3><<<((unsigned)NS * DN + 255) / 256, 256, 0, stream>>>(
        Xb, X1, bng + i * RR, bnb + i * RR, ST + 768 + 256, ST + 768 + 384,
        1.f / (float)(NS * 3), (unsigned)NS * DN);
    // heads on updated Z and X
    head384(i + 1, 640 + (i + 1) * 384);
    head128(i + 1, (i + 1) * HD);
  }

  // c1: h = relu(XZb @ c1_w^T + b) via bf16 MFMA split-K=4
  gemm_mfma_tn<<<dim3(C1O / 128, NS / 128, 4), 256, 0, stream>>>(
      XZb, XZC, c1wh, XZC, HH, C1O, 0, XZC / 32);
  hpost<<<((unsigned)NS * C1O + 255) / 256, 256, 0, stream>>>(HH, fc1b, (unsigned)NS * C1O);
  c2k<<<NS, 256, 0, stream>>>(HH, fc2w, fc2b, out);
}

// Round 4
// 3794.776 us; speedup vs baseline: 1.0032x; 1.0032x over previous
//
#include <hip/hip_runtime.h>
#include <hip/hip_bf16.h>

#define NS  2048
#define RR  116
#define LLY 4
#define HD  128
#define DN  348
#define DE  13456
#define KH  16384    // 128x128 per-sample slab
#define SP  136      // padded LDS slab row stride (ushorts)
#define XZC 2560
#define C1O 1024
#define EPSF 1e-5f

typedef __attribute__((ext_vector_type(8))) short short8;
typedef __attribute__((ext_vector_type(4))) float floatx4;

static __device__ __forceinline__ ushort f2bf(float x) {
  union { __hip_bfloat16 b; ushort u; } cv;
  cv.b = __float2bfloat16(x);
  return cv.u;
}
static __device__ __forceinline__ float bf2f(ushort u) {
  union { ushort u; __hip_bfloat16 b; } cv;
  cv.u = u;
  return __bfloat162float(cv.b);
}
static __device__ __forceinline__ float fexp2(float x) {
#if __has_builtin(__builtin_amdgcn_exp2f)
  return __builtin_amdgcn_exp2f(x);
#else
  return exp2f(x);
#endif
}

#define GLDS16(gsrc, ldst) __builtin_amdgcn_global_load_lds( \
    (const __attribute__((address_space(1))) unsigned int*)(gsrc), \
    (__attribute__((address_space(3))) unsigned int*)(ldst), 16, 0, 0)

// ---------------------------------------------------------------------------
// fp32 tiled GEMM (node heads), split-K atomic accumulate (bias/relu/stats in
// headpost afterwards). C must be pre-zeroed.
// ---------------------------------------------------------------------------
__global__ __launch_bounds__(256) void gemm64(
    const float* __restrict__ A, int lda,
    const float* __restrict__ B, int ldb,
    float* __restrict__ C, int ldc, int cof,
    int M, int N, int K)
{
  const int m0 = blockIdx.y * 64, n0 = blockIdx.x * 64;
  const int ktiles = (K + 15) >> 4;
  const int kt0 = (int)((long long)ktiles * blockIdx.z / gridDim.z);
  const int kt1 = (int)((long long)ktiles * (blockIdx.z + 1) / gridDim.z);
  __shared__ float As[16][68];
  __shared__ float Bs[16][68];
  const int t = threadIdx.x;
  const int tx = t & 15, ty = t >> 4;
  float acc[4][4] = {};
  for (int kt = kt0; kt < kt1; kt++) {
    const int kb = kt * 16;
    {
      int mm = t >> 2, kk = (t & 3) << 2;
      int gm = m0 + mm, gk = kb + kk;
      float4 v = make_float4(0.f, 0.f, 0.f, 0.f);
      if (gm < M && gk < K) v = *(const float4*)(A + (size_t)gm * lda + gk);
      As[kk + 0][mm] = v.x; As[kk + 1][mm] = v.y; As[kk + 2][mm] = v.z; As[kk + 3][mm] = v.w;
      int gn = n0 + mm;
      float4 u = make_float4(0.f, 0.f, 0.f, 0.f);
      if (gn < N && gk < K) u = *(const float4*)(B + (size_t)gn * ldb + gk);
      Bs[kk + 0][mm] = u.x; Bs[kk + 1][mm] = u.y; Bs[kk + 2][mm] = u.z; Bs[kk + 3][mm] = u.w;
    }
    __syncthreads();
#pragma unroll
    for (int kk = 0; kk < 16; kk++) {
      float4 av = *(const float4*)&As[kk][ty << 2];
      float4 bv = *(const float4*)&Bs[kk][tx << 2];
      acc[0][0] += av.x * bv.x; acc[0][1] += av.x * bv.y; acc[0][2] += av.x * bv.z; acc[0][3] += av.x * bv.w;
      acc[1][0] += av.y * bv.x; acc[1][1] += av.y * bv.y; acc[1][2] += av.y * bv.z; acc[1][3] += av.y * bv.w;
      acc[2][0] += av.z * bv.x; acc[2][1] += av.z * bv.y; acc[2][2] += av.z * bv.z; acc[2][3] += av.z * bv.w;
      acc[3][0] += av.w * bv.x; acc[3][1] += av.w * bv.y; acc[3][2] += av.w * bv.z; acc[3][3] += av.w * bv.w;
    }
    __syncthreads();
  }
#pragma unroll
  for (int i = 0; i < 4; i++) {
    int m = m0 + (ty << 2) + i;
#pragma unroll
    for (int j = 0; j < 4; j++) {
      int n = n0 + (tx << 2) + j;
      if (m < M && n < N)
        atomicAdd(&C[(size_t)m * ldc + cof + n], acc[i][j]);
    }
  }
}

// ---------------------------------------------------------------------------
// bf16 MFMA TN GEMM (big heads): C += A[M][lka]*B[N][lkb]^T, split-K atomics.
// Single-buffer stage->barrier->compute->barrier (proven: cross-block wave
// overlap at 2 blk/CU hides the drain; explicit dbuf regressed in R3).
// ---------------------------------------------------------------------------
__global__ __launch_bounds__(256) void gemm_mfma_tn(
    const ushort* __restrict__ A, int lka,
    const ushort* __restrict__ B, int lkb,
    float* __restrict__ C, int ldc, int cof,
    int ktiles)
{
  __shared__ __align__(16) ushort As[128 * 32];
  __shared__ __align__(16) ushort Bs[128 * 32];
  const int t = threadIdx.x;
  const int m0 = blockIdx.y * 128, n0 = blockIdx.x * 128;
  const int kt0 = (int)((long long)ktiles * blockIdx.z / gridDim.z);
  const int kt1 = (int)((long long)ktiles * (blockIdx.z + 1) / gridDim.z);
  const int w = t >> 6, lane = t & 63;
  const int wm = (w >> 1) << 6, wn = (w & 1) << 6;
  const int fr = lane & 15, quad = lane >> 4;
  const int row0 = t >> 2, row1 = (t + 256) >> 2;
  const int ko = (t & 3) * 8;
  floatx4 acc[4][4] = {};
  for (int kt = kt0; kt < kt1; ++kt) {
    const int kb = kt * 32;
    GLDS16(A + (size_t)(m0 + row0) * lka + kb + ko, &As[(size_t)t * 8]);
    GLDS16(A + (size_t)(m0 + row1) * lka + kb + ko, &As[(size_t)(t + 256) * 8]);
    GLDS16(B + (size_t)(n0 + row0) * lkb + kb + ko, &Bs[(size_t)t * 8]);
    GLDS16(B + (size_t)(n0 + row1) * lkb + kb + ko, &Bs[(size_t)(t + 256) * 8]);
    __syncthreads();
    short8 af[4], bf[4];
#pragma unroll
    for (int i = 0; i < 4; i++)
      af[i] = *(const short8*)&As[(wm + i * 16 + fr) * 32 + quad * 8];
#pragma unroll
    for (int j = 0; j < 4; j++)
      bf[j] = *(const short8*)&Bs[(wn + j * 16 + fr) * 32 + quad * 8];
#pragma unroll
    for (int i = 0; i < 4; i++)
#pragma unroll
      for (int j = 0; j < 4; j++)
        acc[i][j] = __builtin_amdgcn_mfma_f32_16x16x32_bf16(af[i], bf[j], acc[i][j], 0, 0, 0);
    __syncthreads();
  }
#pragma unroll
  for (int i = 0; i < 4; i++) {
#pragma unroll
    for (int j = 0; j < 4; j++) {
      int n = n0 + wn + j * 16 + fr;
#pragma unroll
      for (int r = 0; r < 4; r++) {
        int m = m0 + wm + i * 16 + quad * 4 + r;
        atomicAdd(&C[(size_t)m * ldc + cof + n], acc[i][j][r]);
      }
    }
  }
}

// ---------------------------------------------------------------------------
// fusedG12: per sample s:
//   G1: Vt[l][o] = sum_i Z[l][i]*w2[o][i] + b2[o]   (split-bf16, acc fp32)
//   G2: A[m][l]  = sum_k Vt[m][k]*att[l][k]         (att generated in-regs)
//   X1: X1[m]    = (A @ X) @ node_w  (+ fused X-branch BN stats)
// LDS: stage buffers / Vt slabs / fp32 A union one pool -> 2 blk/CU.
// Proven R2 single-buffer K-loop (explicit dbuf regressed, R3 post-mortem).
// ---------------------------------------------------------------------------
__global__ __launch_bounds__(256) void fusedG12(
    const ushort* __restrict__ ZHi, const ushort* __restrict__ ZLo,
    const ushort* __restrict__ WHi, const ushort* __restrict__ WLo,
    const float* __restrict__ b2, const float* __restrict__ Kf,
    ushort* __restrict__ AHi, ushort* __restrict__ ALo,
    const float* __restrict__ Xg, const float* __restrict__ nw,
    float* __restrict__ X1, float* __restrict__ xsum, float* __restrict__ xsq)
{
  __shared__ __align__(16) ushort pool[2 * 128 * SP];   // 69632 B
  ushort* VtHi = pool;
  ushort* VtLo = pool + 128 * SP;
  ushort* tAhi = pool;
  ushort* tAlo = pool + 4096;
  ushort* tBhi = pool + 8192;
  ushort* tBlo = pool + 12288;
  __shared__ float Ks0[128], Ks1[128], Ks2[128], Mrow[128], Minv[128];
  __shared__ float Xs[DN];
  const int s = blockIdx.x;
  const int t = threadIdx.x;
  if (t < 128) {
    const float* kf = Kf + (size_t)s * 384;
    const float lam = 1.2011224087864498f;  // sqrt(log2 e): dots land in log2 domain
    Ks0[t] = kf[t] * lam; Ks1[t] = kf[128 + t] * lam; Ks2[t] = kf[256 + t] * lam;
  }
  for (int ii = t; ii < DN; ii += 256) Xs[ii] = Xg[(size_t)s * DN + ii];
  __syncthreads();
  if (t < 128) {
    if (t < RR) {
      float k0 = Ks0[t], k1 = Ks1[t], k2 = Ks2[t];
      float mx = -3.0e38f;
      for (int k = 0; k < RR; k++)
        mx = fmaxf(mx, k0 * Ks0[k] + k1 * Ks1[k] + k2 * Ks2[k]);
      float sm = 0.f;
      for (int k = 0; k < RR; k++)
        sm += fexp2(k0 * Ks0[k] + k1 * Ks1[k] + k2 * Ks2[k] - mx);
      Mrow[t] = mx; Minv[t] = 1.f / sm;
    } else { Mrow[t] = 0.f; Minv[t] = 0.f; }
  }
  const int w = t >> 6, lane = t & 63;
  const int wm = (w >> 1) << 6, wn = (w & 1) << 6;
  const int fr = lane & 15, quad = lane >> 4;
  const int r0 = t >> 2, c8 = (t & 3) * 8;
  // ---- G1 ----
  floatx4 acc[4][4] = {};
  for (int kt = 0; kt < 4; kt++) {
    const int kb = kt * 32;
    const size_t go = (size_t)s * KH + (size_t)r0 * 128 + kb + c8;
    GLDS16(ZHi + go, &tAhi[t * 8]);
    GLDS16(ZHi + go + 64 * 128, &tAhi[2048 + t * 8]);
    GLDS16(ZLo + go, &tAlo[t * 8]);
    GLDS16(ZLo + go + 64 * 128, &tAlo[2048 + t * 8]);
    const size_t wo = (size_t)r0 * 128 + kb + c8;
    GLDS16(WHi + wo, &tBhi[t * 8]);
    GLDS16(WHi + wo + 64 * 128, &tBhi[2048 + t * 8]);
    GLDS16(WLo + wo, &tBlo[t * 8]);
    GLDS16(WLo + wo + 64 * 128, &tBlo[2048 + t * 8]);
    __syncthreads();
    short8 ah[4], al[4], bh[4], bl[4];
#pragma unroll
    for (int i = 0; i < 4; i++) {
      ah[i] = *(const short8*)&tAhi[(wm + i * 16 + fr) * 32 + quad * 8];
      al[i] = *(const short8*)&tAlo[(wm + i * 16 + fr) * 32 + quad * 8];
    }
#pragma unroll
    for (int j = 0; j < 4; j++) {
      bh[j] = *(const short8*)&tBhi[(wn + j * 16 + fr) * 32 + quad * 8];
      bl[j] = *(const short8*)&tBlo[(wn + j * 16 + fr) * 32 + quad * 8];
    }
#pragma unroll
    for (int i = 0; i < 4; i++)
#pragma unroll
      for (int j = 0; j < 4; j++) {
        acc[i][j] = __builtin_amdgcn_mfma_f32_16x16x32_bf16(ah[i], bh[j], acc[i][j], 0, 0, 0);
        acc[i][j] = __builtin_amdgcn_mfma_f32_16x16x32_bf16(al[i], bh[j], acc[i][j], 0, 0, 0);
        acc[i][j] = __builtin_amdgcn_mfma_f32_16x16x32_bf16(ah[i], bl[j], acc[i][j], 0, 0, 0);
      }
    __syncthreads();
  }
  // bias + split into LDS Vt slabs (stage buffers are dead past this barrier)
#pragma unroll
  for (int i = 0; i < 4; i++) {
#pragma unroll
    for (int j = 0; j < 4; j++) {
      int n = wn + j * 16 + fr;
      float bb = (n < RR) ? b2[n] : 0.f;
#pragma unroll
      for (int r = 0; r < 4; r++) {
        int m = wm + i * 16 + quad * 4 + r;
        float v = acc[i][j][r] + bb;
        ushort h = f2bf(v);
        VtHi[m * SP + n] = h;
        VtLo[m * SP + n] = f2bf(v - bf2f(h));
      }
    }
  }
  __syncthreads();
  // ---- G2 ----
  float Lk0[4], Lk1[4], Lk2[4], Lnm[4];
#pragma unroll
  for (int j = 0; j < 4; j++) {
    int l = wn + j * 16 + fr;
    Lk0[j] = Ks0[l]; Lk1[j] = Ks1[l]; Lk2[j] = Ks2[l]; Lnm[j] = -Mrow[l];
  }
  floatx4 ac2[4][4] = {};
  for (int kt = 0; kt < 4; kt++) {
    const int kb = kt * 32;
    float K0e[8], K1e[8], K2e[8];
#pragma unroll
    for (int e = 0; e < 8; e++) {
      int k = kb + quad * 8 + e;
      K0e[e] = Ks0[k]; K1e[e] = Ks1[k]; K2e[e] = Ks2[k];
    }
    short8 ah[4], al[4];
#pragma unroll
    for (int i = 0; i < 4; i++) {
      ah[i] = *(const short8*)&VtHi[(wm + i * 16 + fr) * SP + kb + quad * 8];
      al[i] = *(const short8*)&VtLo[(wm + i * 16 + fr) * SP + kb + quad * 8];
    }
#pragma unroll
    for (int j = 0; j < 4; j++) {
      // no l/k guards: Vt[:,k>=RR]=0 kills k-pads; Minv[l>=RR]=0 kills l-pads
      short8 bh, bl;
#pragma unroll
      for (int e = 0; e < 8; e++) {
        float d = fmaf(Lk0[j], K0e[e], Lnm[j]);
        d = fmaf(Lk1[j], K1e[e], d);
        d = fmaf(Lk2[j], K2e[e], d);
        float a = fexp2(d);
        ushort h = f2bf(a);
        ((ushort*)&bh)[e] = h;
        ((ushort*)&bl)[e] = f2bf(a - bf2f(h));
      }
#pragma unroll
      for (int i = 0; i < 4; i++) {
        ac2[i][j] = __builtin_amdgcn_mfma_f32_16x16x32_bf16(ah[i], bh, ac2[i][j], 0, 0, 0);
        ac2[i][j] = __builtin_amdgcn_mfma_f32_16x16x32_bf16(al[i], bh, ac2[i][j], 0, 0, 0);
        ac2[i][j] = __builtin_amdgcn_mfma_f32_16x16x32_bf16(ah[i], bl, ac2[i][j], 0, 0, 0);
      }
    }
  }
  // all Vt reads done -> pool reusable as fp32 A [128][133]
  __syncthreads();
  float* Af = (float*)pool;
  ushort* CH = AHi + (size_t)s * KH;
  ushort* CL = ALo + (size_t)s * KH;
#pragma unroll
  for (int i = 0; i < 4; i++) {
#pragma unroll
    for (int j = 0; j < 4; j++) {
      int n = wn + j * 16 + fr;
      float iv = Minv[n];   // 0 for n>=RR -> pad cols stay 0
#pragma unroll
      for (int r = 0; r < 4; r++) {
        int m = wm + i * 16 + quad * 4 + r;
        float v = ac2[i][j][r] * iv;
        ushort h = f2bf(v);
        CH[m * 128 + n] = h;
        CL[m * 128 + n] = f2bf(v - bf2f(h));
        Af[m * 133 + n] = v;
      }
    }
  }
  __syncthreads();
  // ---- X1 = (A @ X) @ node_w + fused X-branch BN stats ----
  if (t < RR) {
    float t0 = 0.f, t1 = 0.f, t2 = 0.f;
    const float* ar = Af + t * 133;
    for (int l = 0; l < RR; l++) {
      float p = ar[l];
      t0 += p * Xs[l * 3 + 0];
      t1 += p * Xs[l * 3 + 1];
      t2 += p * Xs[l * 3 + 2];
    }
    float o0 = t0 * nw[0] + t1 * nw[3] + t2 * nw[6];
    float o1 = t0 * nw[1] + t1 * nw[4] + t2 * nw[7];
    float o2 = t0 * nw[2] + t1 * nw[5] + t2 * nw[8];
    float* Op = X1 + (size_t)s * DN + t * 3;
    Op[0] = o0; Op[1] = o1; Op[2] = o2;
    atomicAdd(&xsum[t], o0 + o1 + o2);
    atomicAdd(&xsq[t], o0 * o0 + o1 * o1 + o2 * o2);
  }
}

// ---------------------------------------------------------------------------
// fusedG34: per sample s:
//   G3: W1[j][l] = sum_k Z[j][k]*ewT[l][k]   -> W1T hi/lo slab in LDS
//   G4: Z2[i][l] = sum_j A[i][j]*W1T[l][j]   -> split store in place over A
//   + fused edge-branch BN stats (channel = row i) from fp32 registers
// Proven R2 single-buffer K-loop.
// ---------------------------------------------------------------------------
__global__ __launch_bounds__(256) void fusedG34(
    const ushort* __restrict__ ZHi, const ushort* __restrict__ ZLo,
    const ushort* __restrict__ EHi, const ushort* __restrict__ ELo,
    ushort* __restrict__ AHi, ushort* __restrict__ ALo,
    float* __restrict__ zsum, float* __restrict__ zsq)
{
  __shared__ __align__(16) ushort pool[2 * 128 * SP];   // 69632 B
  ushort* WtHi = pool;
  ushort* WtLo = pool + 128 * SP;
  ushort* tAhi = pool;
  ushort* tAlo = pool + 4096;
  ushort* tBhi = pool + 8192;
  ushort* tBlo = pool + 12288;
  const int s = blockIdx.x;
  const int t = threadIdx.x;
  const int w = t >> 6, lane = t & 63;
  const int wm = (w >> 1) << 6, wn = (w & 1) << 6;
  const int fr = lane & 15, quad = lane >> 4;
  const int r0 = t >> 2, c8 = (t & 3) * 8;
  // ---- G3 ----
  floatx4 acc[4][4] = {};
  for (int kt = 0; kt < 4; kt++) {
    const int kb = kt * 32;
    const size_t go = (size_t)s * KH + (size_t)r0 * 128 + kb + c8;
    GLDS16(ZHi + go, &tAhi[t * 8]);
    GLDS16(ZHi + go + 64 * 128, &tAhi[2048 + t * 8]);
    GLDS16(ZLo + go, &tAlo[t * 8]);
    GLDS16(ZLo + go + 64 * 128, &tAlo[2048 + t * 8]);
    const size_t eo = (size_t)r0 * 128 + kb + c8;
    GLDS16(EHi + eo, &tBhi[t * 8]);
    GLDS16(EHi + eo + 64 * 128, &tBhi[2048 + t * 8]);
    GLDS16(ELo + eo, &tBlo[t * 8]);
    GLDS16(ELo + eo + 64 * 128, &tBlo[2048 + t * 8]);
    __syncthreads();
    short8 ah[4], al[4], bh[4], bl[4];
#pragma unroll
    for (int i = 0; i < 4; i++) {
      ah[i] = *(const short8*)&tAhi[(wm + i * 16 + fr) * 32 + quad * 8];
      al[i] = *(const short8*)&tAlo[(wm + i * 16 + fr) * 32 + quad * 8];
    }
#pragma unroll
    for (int j = 0; j < 4; j++) {
      bh[j] = *(const short8*)&tBhi[(wn + j * 16 + fr) * 32 + quad * 8];
      bl[j] = *(const short8*)&tBlo[(wn + j * 16 + fr) * 32 + quad * 8];
    }
#pragma unroll
    for (int i = 0; i < 4; i++)
#pragma unroll
      for (int j = 0; j < 4; j++) {
        acc[i][j] = __builtin_amdgcn_mfma_f32_16x16x32_bf16(ah[i], bh[j], acc[i][j], 0, 0, 0);
        acc[i][j] = __builtin_amdgcn_mfma_f32_16x16x32_bf16(al[i], bh[j], acc[i][j], 0, 0, 0);
        acc[i][j] = __builtin_amdgcn_mfma_f32_16x16x32_bf16(ah[i], bl[j], acc[i][j], 0, 0, 0);
      }
    __syncthreads();
  }
  // transposed split store W1 -> W1T slabs (stage buffers dead past barrier)
#pragma unroll
  for (int i = 0; i < 4; i++) {
#pragma unroll
    for (int j = 0; j < 4; j++) {
      int n = wn + j * 16 + fr;
      int mb = wm + i * 16 + quad * 4;
      ushort4 ph, pl;
#pragma unroll
      for (int r = 0; r < 4; r++) {
        float v = acc[i][j][r];
        ushort h = f2bf(v);
        ((ushort*)&ph)[r] = h;
        ((ushort*)&pl)[r] = f2bf(v - bf2f(h));
      }
      *(ushort4*)&WtHi[n * SP + mb] = ph;
      *(ushort4*)&WtLo[n * SP + mb] = pl;
    }
  }
  __syncthreads();
  // ---- G4 ----  (A fragments straight from global; Wt from LDS; no barriers)
  const ushort* GAh = AHi + (size_t)s * KH;
  const ushort* GAl = ALo + (size_t)s * KH;
  floatx4 ac2[4][4] = {};
  for (int kt = 0; kt < 4; kt++) {
    const int kb = kt * 32;
    short8 ah[4], al[4], bh[4], bl[4];
#pragma unroll
    for (int i = 0; i < 4; i++) {
      const size_t ro = (size_t)(wm + i * 16 + fr) * 128 + kb + quad * 8;
      ah[i] = *(const short8*)(GAh + ro);
      al[i] = *(const short8*)(GAl + ro);
    }
#pragma unroll
    for (int j = 0; j < 4; j++) {
      bh[j] = *(const short8*)&WtHi[(wn + j * 16 + fr) * SP + kb + quad * 8];
      bl[j] = *(const short8*)&WtLo[(wn + j * 16 + fr) * SP + kb + quad * 8];
    }
#pragma unroll
    for (int i = 0; i < 4; i++)
#pragma unroll
      for (int j = 0; j < 4; j++) {
        ac2[i][j] = __builtin_amdgcn_mfma_f32_16x16x32_bf16(ah[i], bh[j], ac2[i][j], 0, 0, 0);
        ac2[i][j] = __builtin_amdgcn_mfma_f32_16x16x32_bf16(al[i], bh[j], ac2[i][j], 0, 0, 0);
        ac2[i][j] = __builtin_amdgcn_mfma_f32_16x16x32_bf16(ah[i], bl[j], ac2[i][j], 0, 0, 0);
      }
  }
  // all waves must finish READING A before anyone overwrites it in place
  __syncthreads();
  ushort* CH = AHi + (size_t)s * KH;
  ushort* CL = ALo + (size_t)s * KH;
#pragma unroll
  for (int i = 0; i < 4; i++) {
#pragma unroll
    for (int j = 0; j < 4; j++) {
      int n = wn + j * 16 + fr;
#pragma unroll
      for (int r = 0; r < 4; r++) {
        int m = wm + i * 16 + quad * 4 + r;
        float v = ac2[i][j][r];
        ushort h = f2bf(v);
        CH[m * 128 + n] = h;
        CL[m * 128 + n] = f2bf(v - bf2f(h));
      }
    }
  }
  // fused BN stats: channel = row m; sum this wave's 64 cols via 16-lane shfl
  // (cols n>=RR are exact zeros -> harmless)
#pragma unroll
  for (int i = 0; i < 4; i++) {
#pragma unroll
    for (int r = 0; r < 4; r++) {
      int m = wm + i * 16 + quad * 4 + r;
      float a = 0.f, q = 0.f;
#pragma unroll
      for (int j = 0; j < 4; j++) { float v = ac2[i][j][r]; a += v; q += v * v; }
      a += __shfl_xor(a, 1); q += __shfl_xor(q, 1);
      a += __shfl_xor(a, 2); q += __shfl_xor(q, 2);
      a += __shfl_xor(a, 4); q += __shfl_xor(q, 4);
      a += __shfl_xor(a, 8); q += __shfl_xor(q, 8);
      if ((lane & 15) == 0 && m < RR) {
        atomicAdd(&zsum[m], a);
        atomicAdd(&zsq[m], q);
      }
    }
  }
}

// K precompute: Kf[s][c*128+l] = conv1_w[c]·X[s][l] + b[c]  (0 for l>=RR)
__global__ void kprep(const float* __restrict__ Xb, const float* __restrict__ kw,
                      const float* __restrict__ kb, float* __restrict__ Kf)
{
  int idx = blockIdx.x * 256 + threadIdx.x;
  if (idx >= NS * 384) return;
  int s = idx / 384, r = idx - s * 384;
  int c = r >> 7, l = r & 127;
  float v = 0.f;
  if (l < RR) {
    const float* xp = Xb + (size_t)s * DN + l * 3;
    v = kw[c * 3 + 0] * xp[0] + kw[c * 3 + 1] * xp[1] + kw[c * 3 + 2] * xp[2] + kb[c];
  }
  Kf[idx] = v;
}

// initial Z -> hi/lo slabs (zero-padded)
__global__ __launch_bounds__(256) void cvtZ0(
    const float* __restrict__ Z, ushort* __restrict__ ZHi, ushort* __restrict__ ZLo)
{
  const int s = blockIdx.x;
  const float* Zp = Z + (size_t)s * DE;
  ushort* h = ZHi + (size_t)s * KH;
  ushort* lo = ZLo + (size_t)s * KH;
  for (int idx = threadIdx.x; idx < KH; idx += 256) {
    int l = idx >> 7, i = idx & 127;
    if ((l < RR) && (i < RR)) {
      float v = Zp[l * RR + i];
      ushort hh = f2bf(v);
      h[idx] = hh; lo[idx] = f2bf(v - bf2f(hh));
    } else { h[idx] = 0; lo[idx] = 0; }
  }
}

// weight prep: w2 pair [o][i]; ewT pair [l][k]=ew[k][l]  (padded, all layers)
__global__ void wprep2(const float* __restrict__ w2, const float* __restrict__ ew,
                       ushort* __restrict__ w2Hi, ushort* __restrict__ w2Lo,
                       ushort* __restrict__ eHi, ushort* __restrict__ eLo)
{
  int idx = blockIdx.x * 256 + threadIdx.x;   // 4*16384
  int ly = idx >> 14, k = idx & (KH - 1);
  int r = k >> 7, c = k & 127;
  bool v = (r < RR) && (c < RR);
  float a = v ? w2[ly * DE + r * RR + c] : 0.f;
  float b = v ? ew[ly * DE + c * RR + r] : 0.f;
  ushort ha = f2bf(a), hb = f2bf(b);
  w2Hi[idx] = ha; w2Lo[idx] = f2bf(a - bf2f(ha));
  eHi[idx] = hb; eLo[idx] = f2bf(b - bf2f(hb));
}

// lew head weights: [384][13456] fp32 -> [384][16384] bf16 hole-padded
__global__ void lewprep(const float* __restrict__ src, ushort* __restrict__ dst)
{
  int idx = blockIdx.x * 256 + threadIdx.x;   // 384*16384
  int h = idx >> 14, k = idx & (KH - 1);
  int l = k >> 7, i = k & 127;
  bool v = (l < RR) && (i < RR);
  dst[idx] = v ? f2bf(src[(size_t)h * DE + l * RR + i]) : (ushort)0;
}

// fp32 -> bf16 plain convert (c1 weights)
__global__ void cvt_pad(const float* __restrict__ src, ushort* __restrict__ dst,
                        long long total)
{
  long long idx = (long long)blockIdx.x * 256 + threadIdx.x;
  if (idx < total) dst[idx] = f2bf(src[idx]);
}

// ---------------------------------------------------------------------------
// BN helpers
// ---------------------------------------------------------------------------
__global__ __launch_bounds__(256) void headpost(
    float* __restrict__ Y, int ldy, int cof, int ncols, int chunk,
    const float* __restrict__ bias,
    float* __restrict__ sum, float* __restrict__ sq)
{
  const int cl = threadIdx.x & 63;
  const int c = blockIdx.x * 64 + cl;
  const int r4 = threadIdx.x >> 6;
  const int s0 = blockIdx.y * chunk;
  float a = 0.f, q = 0.f;
  if (c < ncols) {
    float bb = bias[c];
    for (int r = s0 + r4; r < s0 + chunk; r += 4) {
      size_t o = (size_t)r * ldy + cof + c;
      float v = fmaxf(Y[o] + bb, 0.f);
      Y[o] = v;
      a += v; q += v * v;
    }
  }
  __shared__ float la[4][64], lq[4][64];
  la[r4][cl] = a; lq[r4][cl] = q;
  __syncthreads();
  if (threadIdx.x < 64) {
    int cc = blockIdx.x * 64 + threadIdx.x;
    if (cc < ncols) {
      float aa = la[0][threadIdx.x] + la[1][threadIdx.x] + la[2][threadIdx.x] + la[3][threadIdx.x];
      float qq = lq[0][threadIdx.x] + lq[1][threadIdx.x] + lq[2][threadIdx.x] + lq[3][threadIdx.x];
      atomicAdd(&sum[cc], aa);
      atomicAdd(&sq[cc], qq);
    }
  }
}

template<int NC>
__global__ void colnormb(const float* __restrict__ Y, ushort* __restrict__ Yb,
                         int ldy, int cof, float rinv,
                         const float* __restrict__ sum, const float* __restrict__ sq,
                         const float* __restrict__ g, const float* __restrict__ b,
                         unsigned total)
{
  unsigned idx = blockIdx.x * 256u + threadIdx.x;
  if (idx >= total) return;
  unsigned r = idx / NC, c = idx - r * NC;
  float m = sum[c] * rinv;
  float v = sq[c] * rinv - m * m;
  float iv = rsqrtf(v + EPSF);
  size_t o = (size_t)r * ldy + cof + c;
  Yb[o] = f2bf((Y[o] - m) * iv * g[c] + b[c]);
}

// Z master (hi/lo) += relu(bn(Z2 pair))
__global__ void ncl_updatez_pair(
    ushort* __restrict__ ZHi, ushort* __restrict__ ZLo,
    const ushort* __restrict__ Z2Hi, const ushort* __restrict__ Z2Lo,
    const float* __restrict__ g, const float* __restrict__ b,
    const float* __restrict__ sum, const float* __restrict__ sq)
{
  unsigned idx = blockIdx.x * 256u + threadIdx.x;
  if (idx >= (unsigned)NS * DE) return;
  unsigned s = idx / DE, rem = idx - s * DE;
  unsigned i = rem / RR, l = rem - i * RR;
  size_t off = (size_t)s * KH + i * 128 + l;
  const float invcnt = 1.f / (float)(NS * RR);
  float m = sum[i] * invcnt;
  float v = sq[i] * invcnt - m * m;
  float iv = rsqrtf(v + EPSF);
  float z2 = bf2f(Z2Hi[off]) + bf2f(Z2Lo[off]);
  float z = (z2 - m) * iv * g[i] + b[i];
  float nv = bf2f(ZHi[off]) + bf2f(ZLo[off]) + fmaxf(z, 0.f);
  ushort h = f2bf(nv);
  ZHi[off] = h;
  ZLo[off] = f2bf(nv - bf2f(h));
}

template<int LC>
__global__ void ncl_update(float* __restrict__ dst, const float* __restrict__ src,
                           const float* __restrict__ g, const float* __restrict__ b,
                           const float* __restrict__ sum, const float* __restrict__ sq,
                           float invcnt, unsigned total)
{
  unsigned idx = blockIdx.x * 256u + threadIdx.x;
  if (idx >= total) return;
  int c = (int)((idx / LC) % RR);
  float m = sum[c] * invcnt;
  float v = sq[c] * invcnt - m * m;
  float iv = rsqrtf(v + EPSF);
  float z = (src[idx] - m) * iv * g[c] + b[c];
  dst[idx] += fmaxf(z, 0.f);
}

__global__ void hpost(float* __restrict__ Hh, const float* __restrict__ b, unsigned total)
{
  unsigned idx = blockIdx.x * 256u + threadIdx.x;
  if (idx >= total) return;
  Hh[idx] = fmaxf(Hh[idx] + b[idx & (C1O - 1)], 0.f);
}

__global__ __launch_bounds__(256) void c2k(const float* __restrict__ Hh,
                                           const float* __restrict__ w,
                                           const float* __restrict__ b,
                                           float* __restrict__ out)
{
  const int s = blockIdx.x;
  float a0 = 0.f, a1 = 0.f;
  for (int j = threadIdx.x; j < C1O; j += 256) {
    float h = Hh[(size_t)s * C1O + j];
    a0 += h * w[j];
    a1 += h * w[C1O + j];
  }
  for (int o = 32; o; o >>= 1) { a0 += __shfl_down(a0, o); a1 += __shfl_down(a1, o); }
  __shared__ float p0[4], p1[4];
  const int wv = threadIdx.x >> 6;
  if ((threadIdx.x & 63) == 0) { p0[wv] = a0; p1[wv] = a1; }
  __syncthreads();
  if (threadIdx.x == 0) {
    out[s * 2 + 0] = p0[0] + p0[1] + p0[2] + p0[3] + b[0];
    out[s * 2 + 1] = p1[0] + p1[1] + p1[2] + p1[3] + b[1];
  }
}

// ---------------------------------------------------------------------------
extern "C" void kernel_launch(void* const* d_in, const int* in_sizes, int n_in,
                              void* d_out, int out_size, void* d_ws, size_t ws_size,
                              hipStream_t stream)
{
  const float* X    = (const float*)d_in[0];
  const float* Z    = (const float*)d_in[1];
  const float* cv1w = (const float*)d_in[2];
  const float* cv1b = (const float*)d_in[3];
  const float* cv2w = (const float*)d_in[4];
  const float* cv2b = (const float*)d_in[5];
  const float* nw   = (const float*)d_in[6];
  const float* ew   = (const float*)d_in[7];
  const float* bng  = (const float*)d_in[8];
  const float* bnb  = (const float*)d_in[9];
  const float* beg  = (const float*)d_in[10];
  const float* beb  = (const float*)d_in[11];
  const float* lnw  = (const float*)d_in[12];
  const float* lnb  = (const float*)d_in[13];
  const float* lng  = (const float*)d_in[14];
  const float* lnbt = (const float*)d_in[15];
  const float* lew  = (const float*)d_in[16];
  const float* leb  = (const float*)d_in[17];
  const float* leg  = (const float*)d_in[18];
  const float* lebt = (const float*)d_in[19];
  const float* fc1w = (const float*)d_in[20];
  const float* fc1b = (const float*)d_in[21];
  const float* fc2w = (const float*)d_in[22];
  const float* fc2b = (const float*)d_in[23];
  float* out = (float*)d_out;

  // workspace layout (~320 MiB total, well under proven 381.5 MB)
  char* base = (char*)d_ws;
  ushort* ZHi  = (ushort*)base;                     base += (size_t)NS * KH * 2;
  ushort* ZLo  = (ushort*)base;                     base += (size_t)NS * KH * 2;
  ushort* ARHi = (ushort*)base;                     base += (size_t)NS * KH * 2;
  ushort* ARLo = (ushort*)base;                     base += (size_t)NS * KH * 2;
  ushort* XZb  = (ushort*)base;                     base += (size_t)NS * XZC * 2;
  ushort* c1wh = (ushort*)base;                     base += (size_t)C1O * XZC * 2;
  ushort* lewh = (ushort*)base;                     base += (size_t)384 * KH * 2;
  ushort* w2Hi = (ushort*)base;                     base += (size_t)4 * KH * 2;
  ushort* w2Lo = (ushort*)base;                     base += (size_t)4 * KH * 2;
  ushort* eHi  = (ushort*)base;                     base += (size_t)4 * KH * 2;
  ushort* eLo  = (ushort*)base;                     base += (size_t)4 * KH * 2;
  float* Xb = (float*)base;                         base += (size_t)NS * DN * 4;
  float* X1 = (float*)base;                         base += (size_t)NS * DN * 4;
  float* XZ = (float*)base;                         base += (size_t)NS * XZC * 4;
  float* HH = (float*)base;                         base += (size_t)NS * C1O * 4;
  float* Kf = (float*)base;                         base += (size_t)NS * 384 * 4;
  float* ST = (float*)base;

  hipMemcpyAsync(Xb, X, sizeof(float) * (size_t)NS * DN, hipMemcpyDeviceToDevice, stream);
  hipMemsetAsync(XZ, 0, sizeof(float) * (size_t)NS * XZC, stream);
  hipMemsetAsync(HH, 0, sizeof(float) * (size_t)NS * C1O, stream);
  cvt_pad<<<(unsigned)(((long long)C1O * XZC + 255) / 256), 256, 0, stream>>>(
      fc1w, c1wh, (long long)C1O * XZC);
  wprep2<<<(4 * KH) / 256, 256, 0, stream>>>(cv2w, ew, w2Hi, w2Lo, eHi, eLo);
  cvtZ0<<<NS, 256, 0, stream>>>(Z, ZHi, ZLo);

  const float rinv = 1.f / (float)NS;

  auto head384 = [&](int hd, int cof) {
    lewprep<<<(384 * KH) / 256, 256, 0, stream>>>(lew + (size_t)hd * 384 * DE, lewh);
    gemm_mfma_tn<<<dim3(3, 16, 12), 256, 0, stream>>>(
        ZHi, KH, lewh, KH, XZ, XZC, cof, KH / 32);
    hipMemsetAsync(ST, 0, sizeof(float) * 768, stream);
    headpost<<<dim3(6, 8), 256, 0, stream>>>(XZ, XZC, cof, 384, 256,
                                             leb + hd * 384, ST, ST + 384);
    colnormb<384><<<(NS * 384 + 255) / 256, 256, 0, stream>>>(
        XZ, XZb, XZC, cof, rinv, ST, ST + 384, leg + hd * 384, lebt + hd * 384, NS * 384);
  };
  auto head128 = [&](int hd, int cof) {
    gemm64<<<dim3(2, NS / 64, 4), 256, 0, stream>>>(
        Xb, DN, lnw + (size_t)hd * HD * DN, DN, XZ, XZC, cof, NS, HD, DN);
    hipMemsetAsync(ST, 0, sizeof(float) * 768, stream);
    headpost<<<dim3(2, 8), 256, 0, stream>>>(XZ, XZC, cof, HD, 256,
                                             lnb + hd * HD, ST, ST + 384);
    colnormb<HD><<<(NS * HD + 255) / 256, 256, 0, stream>>>(
        XZ, XZb, XZC, cof, rinv, ST, ST + 384, lng + hd * HD, lnbt + hd * HD, NS * HD);
  };

  head128(0, 0);
  head384(0, 640);

  for (int i = 0; i < LLY; i++) {
    // K for this layer (old X)
    kprep<<<(NS * 384 + 255) / 256, 256, 0, stream>>>(Xb, cv1w + i * 9, cv1b + i * 3, Kf);
    // zero BN-stat slots (filled by fused epilogues below)
    hipMemsetAsync(ST + 768, 0, sizeof(float) * 512, stream);
    // G1+G2 fused + in-block X1 (=pTx_node) + fused X-branch stats
    fusedG12<<<NS, 256, 0, stream>>>(ZHi, ZLo, w2Hi + (size_t)i * KH, w2Lo + (size_t)i * KH,
                                     cv2b + i * RR, Kf, ARHi, ARLo,
                                     Xb, nw + i * 9, X1,
                                     ST + 768 + 256, ST + 768 + 384);
    // G3+G4 fused: Z2 pair in place over A_ref pair + fused edge-branch stats
    fusedG34<<<NS, 256, 0, stream>>>(ZHi, ZLo, eHi + (size_t)i * KH, eLo + (size_t)i * KH,
                                     ARHi, ARLo, ST + 768, ST + 768 + 128);
    // BN + residual
    ncl_updatez_pair<<<((unsigned)NS * DE + 255) / 256, 256, 0, stream>>>(
        ZHi, ZLo, ARHi, ARLo, beg + i * RR, beb + i * RR, ST + 768, ST + 768 + 128);
    ncl_update<3><<<((unsigned)NS * DN + 255) / 256, 256, 0, stream>>>(
        Xb, X1, bng + i * RR, bnb + i * RR, ST + 768 + 256, ST + 768 + 384,
        1.f / (float)(NS * 3), (unsigned)NS * DN);
    // heads on updated Z and X
    head384(i + 1, 640 + (i + 1) * 384);
    head128(i + 1, (i + 1) * HD);
  }

  // c1: h = relu(XZb @ c1_w^T + b) via bf16 MFMA split-K=4
  gemm_mfma_tn<<<dim3(C1O / 128, NS / 128, 4), 256, 0, stream>>>(
      XZb, XZC, c1wh, XZC, HH, C1O, 0, XZC / 32);
  hpost<<<((unsigned)NS * C1O + 255) / 256, 256, 0, stream>>>(HH, fc1b, (unsigned)NS * C1O);
  c2k<<<NS, 256, 0, stream>>>(HH, fc2w, fc2b, out);
}

// Round 6
// 2618.216 us; speedup vs baseline: 1.4540x; 1.4494x over previous
//
#include <hip/hip_runtime.h>
#include <hip/hip_bf16.h>

#define NS  2048
#define RR  116
#define LLY 4
#define HD  128
#define DN  348
#define DE  13456
#define KH  16384    // 128x128 per-sample slab
#define SP  136      // padded LDS slab row stride (ushorts)
#define XZC 2560
#define C1O 1024
#define EPSF 1e-5f
#define NREP 64      // stat-replica buckets (atomic contention 4096 -> 64)

typedef __attribute__((ext_vector_type(8))) short short8;
typedef __attribute__((ext_vector_type(4))) float floatx4;

static __device__ __forceinline__ ushort f2bf(float x) {
  union { __hip_bfloat16 b; ushort u; } cv;
  cv.b = __float2bfloat16(x);
  return cv.u;
}
static __device__ __forceinline__ float bf2f(ushort u) {
  union { ushort u; __hip_bfloat16 b; } cv;
  cv.u = u;
  return __bfloat162float(cv.b);
}
static __device__ __forceinline__ float fexp2(float x) {
#if __has_builtin(__builtin_amdgcn_exp2f)
  return __builtin_amdgcn_exp2f(x);
#else
  return exp2f(x);
#endif
}

#define GLDS16(gsrc, ldst) __builtin_amdgcn_global_load_lds( \
    (const __attribute__((address_space(1))) unsigned int*)(gsrc), \
    (__attribute__((address_space(3))) unsigned int*)(ldst), 16, 0, 0)

// ---------------------------------------------------------------------------
// fp32 tiled GEMM (node heads), split-K atomic accumulate (bias/relu/stats in
// headpost afterwards). C must be pre-zeroed.
// ---------------------------------------------------------------------------
__global__ __launch_bounds__(256) void gemm64(
    const float* __restrict__ A, int lda,
    const float* __restrict__ B, int ldb,
    float* __restrict__ C, int ldc, int cof,
    int M, int N, int K)
{
  const int m0 = blockIdx.y * 64, n0 = blockIdx.x * 64;
  const int ktiles = (K + 15) >> 4;
  const int kt0 = (int)((long long)ktiles * blockIdx.z / gridDim.z);
  const int kt1 = (int)((long long)ktiles * (blockIdx.z + 1) / gridDim.z);
  __shared__ float As[16][68];
  __shared__ float Bs[16][68];
  const int t = threadIdx.x;
  const int tx = t & 15, ty = t >> 4;
  float acc[4][4] = {};
  for (int kt = kt0; kt < kt1; kt++) {
    const int kb = kt * 16;
    {
      int mm = t >> 2, kk = (t & 3) << 2;
      int gm = m0 + mm, gk = kb + kk;
      float4 v = make_float4(0.f, 0.f, 0.f, 0.f);
      if (gm < M && gk < K) v = *(const float4*)(A + (size_t)gm * lda + gk);
      As[kk + 0][mm] = v.x; As[kk + 1][mm] = v.y; As[kk + 2][mm] = v.z; As[kk + 3][mm] = v.w;
      int gn = n0 + mm;
      float4 u = make_float4(0.f, 0.f, 0.f, 0.f);
      if (gn < N && gk < K) u = *(const float4*)(B + (size_t)gn * ldb + gk);
      Bs[kk + 0][mm] = u.x; Bs[kk + 1][mm] = u.y; Bs[kk + 2][mm] = u.z; Bs[kk + 3][mm] = u.w;
    }
    __syncthreads();
#pragma unroll
    for (int kk = 0; kk < 16; kk++) {
      float4 av = *(const float4*)&As[kk][ty << 2];
      float4 bv = *(const float4*)&Bs[kk][tx << 2];
      acc[0][0] += av.x * bv.x; acc[0][1] += av.x * bv.y; acc[0][2] += av.x * bv.z; acc[0][3] += av.x * bv.w;
      acc[1][0] += av.y * bv.x; acc[1][1] += av.y * bv.y; acc[1][2] += av.y * bv.z; acc[1][3] += av.y * bv.w;
      acc[2][0] += av.z * bv.x; acc[2][1] += av.z * bv.y; acc[2][2] += av.z * bv.z; acc[2][3] += av.z * bv.w;
      acc[3][0] += av.w * bv.x; acc[3][1] += av.w * bv.y; acc[3][2] += av.w * bv.z; acc[3][3] += av.w * bv.w;
    }
    __syncthreads();
  }
#pragma unroll
  for (int i = 0; i < 4; i++) {
    int m = m0 + (ty << 2) + i;
#pragma unroll
    for (int j = 0; j < 4; j++) {
      int n = n0 + (tx << 2) + j;
      if (m < M && n < N)
        atomicAdd(&C[(size_t)m * ldc + cof + n], acc[i][j]);
    }
  }
}

// ---------------------------------------------------------------------------
// bf16 MFMA TN GEMM (big heads): C += A[M][lka]*B[N][lkb]^T, split-K atomics.
// Single-buffer stage->barrier->compute->barrier (proven R2 structure).
// ---------------------------------------------------------------------------
__global__ __launch_bounds__(256) void gemm_mfma_tn(
    const ushort* __restrict__ A, int lka,
    const ushort* __restrict__ B, int lkb,
    float* __restrict__ C, int ldc, int cof,
    int ktiles)
{
  __shared__ __align__(16) ushort As[128 * 32];
  __shared__ __align__(16) ushort Bs[128 * 32];
  const int t = threadIdx.x;
  const int m0 = blockIdx.y * 128, n0 = blockIdx.x * 128;
  const int kt0 = (int)((long long)ktiles * blockIdx.z / gridDim.z);
  const int kt1 = (int)((long long)ktiles * (blockIdx.z + 1) / gridDim.z);
  const int w = t >> 6, lane = t & 63;
  const int wm = (w >> 1) << 6, wn = (w & 1) << 6;
  const int fr = lane & 15, quad = lane >> 4;
  const int row0 = t >> 2, row1 = (t + 256) >> 2;
  const int ko = (t & 3) * 8;
  floatx4 acc[4][4] = {};
  for (int kt = kt0; kt < kt1; ++kt) {
    const int kb = kt * 32;
    GLDS16(A + (size_t)(m0 + row0) * lka + kb + ko, &As[(size_t)t * 8]);
    GLDS16(A + (size_t)(m0 + row1) * lka + kb + ko, &As[(size_t)(t + 256) * 8]);
    GLDS16(B + (size_t)(n0 + row0) * lkb + kb + ko, &Bs[(size_t)t * 8]);
    GLDS16(B + (size_t)(n0 + row1) * lkb + kb + ko, &Bs[(size_t)(t + 256) * 8]);
    __syncthreads();
    short8 af[4], bf[4];
#pragma unroll
    for (int i = 0; i < 4; i++)
      af[i] = *(const short8*)&As[(wm + i * 16 + fr) * 32 + quad * 8];
#pragma unroll
    for (int j = 0; j < 4; j++)
      bf[j] = *(const short8*)&Bs[(wn + j * 16 + fr) * 32 + quad * 8];
#pragma unroll
    for (int i = 0; i < 4; i++)
#pragma unroll
      for (int j = 0; j < 4; j++)
        acc[i][j] = __builtin_amdgcn_mfma_f32_16x16x32_bf16(af[i], bf[j], acc[i][j], 0, 0, 0);
    __syncthreads();
  }
#pragma unroll
  for (int i = 0; i < 4; i++) {
#pragma unroll
    for (int j = 0; j < 4; j++) {
      int n = n0 + wn + j * 16 + fr;
#pragma unroll
      for (int r = 0; r < 4; r++) {
        int m = m0 + wm + i * 16 + quad * 4 + r;
        atomicAdd(&C[(size_t)m * ldc + cof + n], acc[i][j][r]);
      }
    }
  }
}

// ---------------------------------------------------------------------------
// fusedG12: per sample s:
//   G1: Vt[l][o] = sum_i Z[l][i]*w2[o][i] + b2[o]   (split-bf16, acc fp32)
//   G2: A[m][l]  = sum_k Vt[m][k]*att[l][k]         (att generated in-regs)
//   X1: X1[m]    = (A @ X) @ node_w  (+ X-branch BN stats into replica bucket)
// Stats go to strep[(s&63)*512 + 256/384 + m] -> ~32 same-addr atomics/bucket.
// ---------------------------------------------------------------------------
__global__ __launch_bounds__(256) void fusedG12(
    const ushort* __restrict__ ZHi, const ushort* __restrict__ ZLo,
    const ushort* __restrict__ WHi, const ushort* __restrict__ WLo,
    const float* __restrict__ b2, const float* __restrict__ Kf,
    ushort* __restrict__ AHi, ushort* __restrict__ ALo,
    const float* __restrict__ Xg, const float* __restrict__ nw,
    float* __restrict__ X1, float* __restrict__ strep)
{
  __shared__ __align__(16) ushort pool[2 * 128 * SP];   // 69632 B
  ushort* VtHi = pool;
  ushort* VtLo = pool + 128 * SP;
  ushort* tAhi = pool;
  ushort* tAlo = pool + 4096;
  ushort* tBhi = pool + 8192;
  ushort* tBlo = pool + 12288;
  __shared__ float Ks0[128], Ks1[128], Ks2[128], Mrow[128], Minv[128];
  __shared__ float Xs[DN];
  const int s = blockIdx.x;
  const int t = threadIdx.x;
  if (t < 128) {
    const float* kf = Kf + (size_t)s * 384;
    const float lam = 1.2011224087864498f;  // sqrt(log2 e): dots land in log2 domain
    Ks0[t] = kf[t] * lam; Ks1[t] = kf[128 + t] * lam; Ks2[t] = kf[256 + t] * lam;
  }
  for (int ii = t; ii < DN; ii += 256) Xs[ii] = Xg[(size_t)s * DN + ii];
  __syncthreads();
  if (t < 128) {
    if (t < RR) {
      float k0 = Ks0[t], k1 = Ks1[t], k2 = Ks2[t];
      float mx = -3.0e38f;
      for (int k = 0; k < RR; k++)
        mx = fmaxf(mx, k0 * Ks0[k] + k1 * Ks1[k] + k2 * Ks2[k]);
      float sm = 0.f;
      for (int k = 0; k < RR; k++)
        sm += fexp2(k0 * Ks0[k] + k1 * Ks1[k] + k2 * Ks2[k] - mx);
      Mrow[t] = mx; Minv[t] = 1.f / sm;
    } else { Mrow[t] = 0.f; Minv[t] = 0.f; }
  }
  const int w = t >> 6, lane = t & 63;
  const int wm = (w >> 1) << 6, wn = (w & 1) << 6;
  const int fr = lane & 15, quad = lane >> 4;
  const int r0 = t >> 2, c8 = (t & 3) * 8;
  // ---- G1 ----
  floatx4 acc[4][4] = {};
  for (int kt = 0; kt < 4; kt++) {
    const int kb = kt * 32;
    const size_t go = (size_t)s * KH + (size_t)r0 * 128 + kb + c8;
    GLDS16(ZHi + go, &tAhi[t * 8]);
    GLDS16(ZHi + go + 64 * 128, &tAhi[2048 + t * 8]);
    GLDS16(ZLo + go, &tAlo[t * 8]);
    GLDS16(ZLo + go + 64 * 128, &tAlo[2048 + t * 8]);
    const size_t wo = (size_t)r0 * 128 + kb + c8;
    GLDS16(WHi + wo, &tBhi[t * 8]);
    GLDS16(WHi + wo + 64 * 128, &tBhi[2048 + t * 8]);
    GLDS16(WLo + wo, &tBlo[t * 8]);
    GLDS16(WLo + wo + 64 * 128, &tBlo[2048 + t * 8]);
    __syncthreads();
    short8 ah[4], al[4], bh[4], bl[4];
#pragma unroll
    for (int i = 0; i < 4; i++) {
      ah[i] = *(const short8*)&tAhi[(wm + i * 16 + fr) * 32 + quad * 8];
      al[i] = *(const short8*)&tAlo[(wm + i * 16 + fr) * 32 + quad * 8];
    }
#pragma unroll
    for (int j = 0; j < 4; j++) {
      bh[j] = *(const short8*)&tBhi[(wn + j * 16 + fr) * 32 + quad * 8];
      bl[j] = *(const short8*)&tBlo[(wn + j * 16 + fr) * 32 + quad * 8];
    }
#pragma unroll
    for (int i = 0; i < 4; i++)
#pragma unroll
      for (int j = 0; j < 4; j++) {
        acc[i][j] = __builtin_amdgcn_mfma_f32_16x16x32_bf16(ah[i], bh[j], acc[i][j], 0, 0, 0);
        acc[i][j] = __builtin_amdgcn_mfma_f32_16x16x32_bf16(al[i], bh[j], acc[i][j], 0, 0, 0);
        acc[i][j] = __builtin_amdgcn_mfma_f32_16x16x32_bf16(ah[i], bl[j], acc[i][j], 0, 0, 0);
      }
    __syncthreads();
  }
  // bias + split into LDS Vt slabs (stage buffers are dead past this barrier)
#pragma unroll
  for (int i = 0; i < 4; i++) {
#pragma unroll
    for (int j = 0; j < 4; j++) {
      int n = wn + j * 16 + fr;
      float bb = (n < RR) ? b2[n] : 0.f;
#pragma unroll
      for (int r = 0; r < 4; r++) {
        int m = wm + i * 16 + quad * 4 + r;
        float v = acc[i][j][r] + bb;
        ushort h = f2bf(v);
        VtHi[m * SP + n] = h;
        VtLo[m * SP + n] = f2bf(v - bf2f(h));
      }
    }
  }
  __syncthreads();
  // ---- G2 ----
  float Lk0[4], Lk1[4], Lk2[4], Lnm[4];
#pragma unroll
  for (int j = 0; j < 4; j++) {
    int l = wn + j * 16 + fr;
    Lk0[j] = Ks0[l]; Lk1[j] = Ks1[l]; Lk2[j] = Ks2[l]; Lnm[j] = -Mrow[l];
  }
  floatx4 ac2[4][4] = {};
  for (int kt = 0; kt < 4; kt++) {
    const int kb = kt * 32;
    float K0e[8], K1e[8], K2e[8];
#pragma unroll
    for (int e = 0; e < 8; e++) {
      int k = kb + quad * 8 + e;
      K0e[e] = Ks0[k]; K1e[e] = Ks1[k]; K2e[e] = Ks2[k];
    }
    short8 ah[4], al[4];
#pragma unroll
    for (int i = 0; i < 4; i++) {
      ah[i] = *(const short8*)&VtHi[(wm + i * 16 + fr) * SP + kb + quad * 8];
      al[i] = *(const short8*)&VtLo[(wm + i * 16 + fr) * SP + kb + quad * 8];
    }
#pragma unroll
    for (int j = 0; j < 4; j++) {
      // no l/k guards: Vt[:,k>=RR]=0 kills k-pads; Minv[l>=RR]=0 kills l-pads
      short8 bh, bl;
#pragma unroll
      for (int e = 0; e < 8; e++) {
        float d = fmaf(Lk0[j], K0e[e], Lnm[j]);
        d = fmaf(Lk1[j], K1e[e], d);
        d = fmaf(Lk2[j], K2e[e], d);
        float a = fexp2(d);
        ushort h = f2bf(a);
        ((ushort*)&bh)[e] = h;
        ((ushort*)&bl)[e] = f2bf(a - bf2f(h));
      }
#pragma unroll
      for (int i = 0; i < 4; i++) {
        ac2[i][j] = __builtin_amdgcn_mfma_f32_16x16x32_bf16(ah[i], bh, ac2[i][j], 0, 0, 0);
        ac2[i][j] = __builtin_amdgcn_mfma_f32_16x16x32_bf16(al[i], bh, ac2[i][j], 0, 0, 0);
        ac2[i][j] = __builtin_amdgcn_mfma_f32_16x16x32_bf16(ah[i], bl, ac2[i][j], 0, 0, 0);
      }
    }
  }
  // all Vt reads done -> pool reusable as fp32 A [128][133]
  __syncthreads();
  float* Af = (float*)pool;
  ushort* CH = AHi + (size_t)s * KH;
  ushort* CL = ALo + (size_t)s * KH;
#pragma unroll
  for (int i = 0; i < 4; i++) {
#pragma unroll
    for (int j = 0; j < 4; j++) {
      int n = wn + j * 16 + fr;
      float iv = Minv[n];   // 0 for n>=RR -> pad cols stay 0
#pragma unroll
      for (int r = 0; r < 4; r++) {
        int m = wm + i * 16 + quad * 4 + r;
        float v = ac2[i][j][r] * iv;
        ushort h = f2bf(v);
        CH[m * 128 + n] = h;
        CL[m * 128 + n] = f2bf(v - bf2f(h));
        Af[m * 133 + n] = v;
      }
    }
  }
  __syncthreads();
  // ---- X1 = (A @ X) @ node_w + X-branch BN stats (replica bucket) ----
  if (t < RR) {
    float t0 = 0.f, t1 = 0.f, t2 = 0.f;
    const float* ar = Af + t * 133;
    for (int l = 0; l < RR; l++) {
      float p = ar[l];
      t0 += p * Xs[l * 3 + 0];
      t1 += p * Xs[l * 3 + 1];
      t2 += p * Xs[l * 3 + 2];
    }
    float o0 = t0 * nw[0] + t1 * nw[3] + t2 * nw[6];
    float o1 = t0 * nw[1] + t1 * nw[4] + t2 * nw[7];
    float o2 = t0 * nw[2] + t1 * nw[5] + t2 * nw[8];
    float* Op = X1 + (size_t)s * DN + t * 3;
    Op[0] = o0; Op[1] = o1; Op[2] = o2;
    float* rep = strep + (size_t)(s & (NREP - 1)) * 512;
    atomicAdd(&rep[256 + t], o0 + o1 + o2);
    atomicAdd(&rep[384 + t], o0 * o0 + o1 * o1 + o2 * o2);
  }
}

// ---------------------------------------------------------------------------
// fusedG34: per sample s:
//   G3: W1[j][l] = sum_k Z[j][k]*ewT[l][k]   -> W1T hi/lo slab in LDS
//   G4: Z2[i][l] = sum_j A[i][j]*W1T[l][j]   -> split store in place over A
//   + edge-branch BN stats (channel = row i) into replica bucket (s&63)
// ---------------------------------------------------------------------------
__global__ __launch_bounds__(256) void fusedG34(
    const ushort* __restrict__ ZHi, const ushort* __restrict__ ZLo,
    const ushort* __restrict__ EHi, const ushort* __restrict__ ELo,
    ushort* __restrict__ AHi, ushort* __restrict__ ALo,
    float* __restrict__ strep)
{
  __shared__ __align__(16) ushort pool[2 * 128 * SP];   // 69632 B
  ushort* WtHi = pool;
  ushort* WtLo = pool + 128 * SP;
  ushort* tAhi = pool;
  ushort* tAlo = pool + 4096;
  ushort* tBhi = pool + 8192;
  ushort* tBlo = pool + 12288;
  const int s = blockIdx.x;
  const int t = threadIdx.x;
  const int w = t >> 6, lane = t & 63;
  const int wm = (w >> 1) << 6, wn = (w & 1) << 6;
  const int fr = lane & 15, quad = lane >> 4;
  const int r0 = t >> 2, c8 = (t & 3) * 8;
  // ---- G3 ----
  floatx4 acc[4][4] = {};
  for (int kt = 0; kt < 4; kt++) {
    const int kb = kt * 32;
    const size_t go = (size_t)s * KH + (size_t)r0 * 128 + kb + c8;
    GLDS16(ZHi + go, &tAhi[t * 8]);
    GLDS16(ZHi + go + 64 * 128, &tAhi[2048 + t * 8]);
    GLDS16(ZLo + go, &tAlo[t * 8]);
    GLDS16(ZLo + go + 64 * 128, &tAlo[2048 + t * 8]);
    const size_t eo = (size_t)r0 * 128 + kb + c8;
    GLDS16(EHi + eo, &tBhi[t * 8]);
    GLDS16(EHi + eo + 64 * 128, &tBhi[2048 + t * 8]);
    GLDS16(ELo + eo, &tBlo[t * 8]);
    GLDS16(ELo + eo + 64 * 128, &tBlo[2048 + t * 8]);
    __syncthreads();
    short8 ah[4], al[4], bh[4], bl[4];
#pragma unroll
    for (int i = 0; i < 4; i++) {
      ah[i] = *(const short8*)&tAhi[(wm + i * 16 + fr) * 32 + quad * 8];
      al[i] = *(const short8*)&tAlo[(wm + i * 16 + fr) * 32 + quad * 8];
    }
#pragma unroll
    for (int j = 0; j < 4; j++) {
      bh[j] = *(const short8*)&tBhi[(wn + j * 16 + fr) * 32 + quad * 8];
      bl[j] = *(const short8*)&tBlo[(wn + j * 16 + fr) * 32 + quad * 8];
    }
#pragma unroll
    for (int i = 0; i < 4; i++)
#pragma unroll
      for (int j = 0; j < 4; j++) {
        acc[i][j] = __builtin_amdgcn_mfma_f32_16x16x32_bf16(ah[i], bh[j], acc[i][j], 0, 0, 0);
        acc[i][j] = __builtin_amdgcn_mfma_f32_16x16x32_bf16(al[i], bh[j], acc[i][j], 0, 0, 0);
        acc[i][j] = __builtin_amdgcn_mfma_f32_16x16x32_bf16(ah[i], bl[j], acc[i][j], 0, 0, 0);
      }
    __syncthreads();
  }
  // transposed split store W1 -> W1T slabs (stage buffers dead past barrier)
#pragma unroll
  for (int i = 0; i < 4; i++) {
#pragma unroll
    for (int j = 0; j < 4; j++) {
      int n = wn + j * 16 + fr;
      int mb = wm + i * 16 + quad * 4;
      ushort4 ph, pl;
#pragma unroll
      for (int r = 0; r < 4; r++) {
        float v = acc[i][j][r];
        ushort h = f2bf(v);
        ((ushort*)&ph)[r] = h;
        ((ushort*)&pl)[r] = f2bf(v - bf2f(h));
      }
      *(ushort4*)&WtHi[n * SP + mb] = ph;
      *(ushort4*)&WtLo[n * SP + mb] = pl;
    }
  }
  __syncthreads();
  // ---- G4 ----  (A fragments straight from global; Wt from LDS; no barriers)
  const ushort* GAh = AHi + (size_t)s * KH;
  const ushort* GAl = ALo + (size_t)s * KH;
  floatx4 ac2[4][4] = {};
  for (int kt = 0; kt < 4; kt++) {
    const int kb = kt * 32;
    short8 ah[4], al[4], bh[4], bl[4];
#pragma unroll
    for (int i = 0; i < 4; i++) {
      const size_t ro = (size_t)(wm + i * 16 + fr) * 128 + kb + quad * 8;
      ah[i] = *(const short8*)(GAh + ro);
      al[i] = *(const short8*)(GAl + ro);
    }
#pragma unroll
    for (int j = 0; j < 4; j++) {
      bh[j] = *(const short8*)&WtHi[(wn + j * 16 + fr) * SP + kb + quad * 8];
      bl[j] = *(const short8*)&WtLo[(wn + j * 16 + fr) * SP + kb + quad * 8];
    }
#pragma unroll
    for (int i = 0; i < 4; i++)
#pragma unroll
      for (int j = 0; j < 4; j++) {
        ac2[i][j] = __builtin_amdgcn_mfma_f32_16x16x32_bf16(ah[i], bh[j], ac2[i][j], 0, 0, 0);
        ac2[i][j] = __builtin_amdgcn_mfma_f32_16x16x32_bf16(al[i], bh[j], ac2[i][j], 0, 0, 0);
        ac2[i][j] = __builtin_amdgcn_mfma_f32_16x16x32_bf16(ah[i], bl[j], ac2[i][j], 0, 0, 0);
      }
  }
  // all waves must finish READING A before anyone overwrites it in place
  __syncthreads();
  ushort* CH = AHi + (size_t)s * KH;
  ushort* CL = ALo + (size_t)s * KH;
#pragma unroll
  for (int i = 0; i < 4; i++) {
#pragma unroll
    for (int j = 0; j < 4; j++) {
      int n = wn + j * 16 + fr;
#pragma unroll
      for (int r = 0; r < 4; r++) {
        int m = wm + i * 16 + quad * 4 + r;
        float v = ac2[i][j][r];
        ushort h = f2bf(v);
        CH[m * 128 + n] = h;
        CL[m * 128 + n] = f2bf(v - bf2f(h));
      }
    }
  }
  // edge-branch BN stats into replica bucket: channel = row m; this wave's 64
  // cols reduced via 16-lane shfl (cols n>=RR are exact zeros -> harmless)
  float* rep = strep + (size_t)(s & (NREP - 1)) * 512;
#pragma unroll
  for (int i = 0; i < 4; i++) {
#pragma unroll
    for (int r = 0; r < 4; r++) {
      int m = wm + i * 16 + quad * 4 + r;
      float a = 0.f, q = 0.f;
#pragma unroll
      for (int j = 0; j < 4; j++) { float v = ac2[i][j][r]; a += v; q += v * v; }
      a += __shfl_xor(a, 1); q += __shfl_xor(q, 1);
      a += __shfl_xor(a, 2); q += __shfl_xor(q, 2);
      a += __shfl_xor(a, 4); q += __shfl_xor(q, 4);
      a += __shfl_xor(a, 8); q += __shfl_xor(q, 8);
      if ((lane & 15) == 0 && m < RR) {
        atomicAdd(&rep[m], a);
        atomicAdd(&rep[128 + m], q);
      }
    }
  }
}

// fold NREP stat replicas [NREP][512] -> final [512]
__global__ __launch_bounds__(256) void foldstats(
    const float* __restrict__ rep, float* __restrict__ outp)
{
  int c = blockIdx.x * 256 + threadIdx.x;   // 512 channels
  float a = 0.f;
  for (int r = 0; r < NREP; r++) a += rep[(size_t)r * 512 + c];
  outp[c] = a;
}

// K precompute: Kf[s][c*128+l] = conv1_w[c]·X[s][l] + b[c]  (0 for l>=RR)
__global__ void kprep(const float* __restrict__ Xb, const float* __restrict__ kw,
                      const float* __restrict__ kb, float* __restrict__ Kf)
{
  int idx = blockIdx.x * 256 + threadIdx.x;
  if (idx >= NS * 384) return;
  int s = idx / 384, r = idx - s * 384;
  int c = r >> 7, l = r & 127;
  float v = 0.f;
  if (l < RR) {
    const float* xp = Xb + (size_t)s * DN + l * 3;
    v = kw[c * 3 + 0] * xp[0] + kw[c * 3 + 1] * xp[1] + kw[c * 3 + 2] * xp[2] + kb[c];
  }
  Kf[idx] = v;
}

// initial Z -> hi/lo slabs (zero-padded)
__global__ __launch_bounds__(256) void cvtZ0(
    const float* __restrict__ Z, ushort* __restrict__ ZHi, ushort* __restrict__ ZLo)
{
  const int s = blockIdx.x;
  const float* Zp = Z + (size_t)s * DE;
  ushort* h = ZHi + (size_t)s * KH;
  ushort* lo = ZLo + (size_t)s * KH;
  for (int idx = threadIdx.x; idx < KH; idx += 256) {
    int l = idx >> 7, i = idx & 127;
    if ((l < RR) && (i < RR)) {
      float v = Zp[l * RR + i];
      ushort hh = f2bf(v);
      h[idx] = hh; lo[idx] = f2bf(v - bf2f(hh));
    } else { h[idx] = 0; lo[idx] = 0; }
  }
}

// weight prep: w2 pair [o][i]; ewT pair [l][k]=ew[k][l]  (padded, all layers)
__global__ void wprep2(const float* __restrict__ w2, const float* __restrict__ ew,
                       ushort* __restrict__ w2Hi, ushort* __restrict__ w2Lo,
                       ushort* __restrict__ eHi, ushort* __restrict__ eLo)
{
  int idx = blockIdx.x * 256 + threadIdx.x;   // 4*16384
  int ly = idx >> 14, k = idx & (KH - 1);
  int r = k >> 7, c = k & 127;
  bool v = (r < RR) && (c < RR);
  float a = v ? w2[ly * DE + r * RR + c] : 0.f;
  float b = v ? ew[ly * DE + c * RR + r] : 0.f;
  ushort ha = f2bf(a), hb = f2bf(b);
  w2Hi[idx] = ha; w2Lo[idx] = f2bf(a - bf2f(ha));
  eHi[idx] = hb; eLo[idx] = f2bf(b - bf2f(hb));
}

// lew head weights: [384][13456] fp32 -> [384][16384] bf16 hole-padded
__global__ void lewprep(const float* __restrict__ src, ushort* __restrict__ dst)
{
  int idx = blockIdx.x * 256 + threadIdx.x;   // 384*16384
  int h = idx >> 14, k = idx & (KH - 1);
  int l = k >> 7, i = k & 127;
  bool v = (l < RR) && (i < RR);
  dst[idx] = v ? f2bf(src[(size_t)h * DE + l * RR + i]) : (ushort)0;
}

// fp32 -> bf16 plain convert (c1 weights)
__global__ void cvt_pad(const float* __restrict__ src, ushort* __restrict__ dst,
                        long long total)
{
  long long idx = (long long)blockIdx.x * 256 + threadIdx.x;
  if (idx < total) dst[idx] = f2bf(src[idx]);
}

// ---------------------------------------------------------------------------
// BN helpers
// ---------------------------------------------------------------------------
__global__ __launch_bounds__(256) void headpost(
    float* __restrict__ Y, int ldy, int cof, int ncols, int chunk,
    const float* __restrict__ bias,
    float* __restrict__ sum, float* __restrict__ sq)
{
  const int cl = threadIdx.x & 63;
  const int c = blockIdx.x * 64 + cl;
  const int r4 = threadIdx.x >> 6;
  const int s0 = blockIdx.y * chunk;
  float a = 0.f, q = 0.f;
  if (c < ncols) {
    float bb = bias[c];
    for (int r = s0 + r4; r < s0 + chunk; r += 4) {
      size_t o = (size_t)r * ldy + cof + c;
      float v = fmaxf(Y[o] + bb, 0.f);
      Y[o] = v;
      a += v; q += v * v;
    }
  }
  __shared__ float la[4][64], lq[4][64];
  la[r4][cl] = a; lq[r4][cl] = q;
  __syncthreads();
  if (threadIdx.x < 64) {
    int cc = blockIdx.x * 64 + threadIdx.x;
    if (cc < ncols) {
      float aa = la[0][threadIdx.x] + la[1][threadIdx.x] + la[2][threadIdx.x] + la[3][threadIdx.x];
      float qq = lq[0][threadIdx.x] + lq[1][threadIdx.x] + lq[2][threadIdx.x] + lq[3][threadIdx.x];
      atomicAdd(&sum[cc], aa);
      atomicAdd(&sq[cc], qq);
    }
  }
}

template<int NC>
__global__ void colnormb(const float* __restrict__ Y, ushort* __restrict__ Yb,
                         int ldy, int cof, float rinv,
                         const float* __restrict__ sum, const float* __restrict__ sq,
                         const float* __restrict__ g, const float* __restrict__ b,
                         unsigned total)
{
  unsigned idx = blockIdx.x * 256u + threadIdx.x;
  if (idx >= total) return;
  unsigned r = idx / NC, c = idx - r * NC;
  float m = sum[c] * rinv;
  float v = sq[c] * rinv - m * m;
  float iv = rsqrtf(v + EPSF);
  size_t o = (size_t)r * ldy + cof + c;
  Yb[o] = f2bf((Y[o] - m) * iv * g[c] + b[c]);
}

// Z master (hi/lo) += relu(bn(Z2 pair))
__global__ void ncl_updatez_pair(
    ushort* __restrict__ ZHi, ushort* __restrict__ ZLo,
    const ushort* __restrict__ Z2Hi, const ushort* __restrict__ Z2Lo,
    const float* __restrict__ g, const float* __restrict__ b,
    const float* __restrict__ sum, const float* __restrict__ sq)
{
  unsigned idx = blockIdx.x * 256u + threadIdx.x;
  if (idx >= (unsigned)NS * DE) return;
  unsigned s = idx / DE, rem = idx - s * DE;
  unsigned i = rem / RR, l = rem - i * RR;
  size_t off = (size_t)s * KH + i * 128 + l;
  const float invcnt = 1.f / (float)(NS * RR);
  float m = sum[i] * invcnt;
  float v = sq[i] * invcnt - m * m;
  float iv = rsqrtf(v + EPSF);
  float z2 = bf2f(Z2Hi[off]) + bf2f(Z2Lo[off]);
  float z = (z2 - m) * iv * g[i] + b[i];
  float nv = bf2f(ZHi[off]) + bf2f(ZLo[off]) + fmaxf(z, 0.f);
  ushort h = f2bf(nv);
  ZHi[off] = h;
  ZLo[off] = f2bf(nv - bf2f(h));
}

template<int LC>
__global__ void ncl_update(float* __restrict__ dst, const float* __restrict__ src,
                           const float* __restrict__ g, const float* __restrict__ b,
                           const float* __restrict__ sum, const float* __restrict__ sq,
                           float invcnt, unsigned total)
{
  unsigned idx = blockIdx.x * 256u + threadIdx.x;
  if (idx >= total) return;
  int c = (int)((idx / LC) % RR);
  float m = sum[c] * invcnt;
  float v = sq[c] * invcnt - m * m;
  float iv = rsqrtf(v + EPSF);
  float z = (src[idx] - m) * iv * g[c] + b[c];
  dst[idx] += fmaxf(z, 0.f);
}

__global__ void hpost(float* __restrict__ Hh, const float* __restrict__ b, unsigned total)
{
  unsigned idx = blockIdx.x * 256u + threadIdx.x;
  if (idx >= total) return;
  Hh[idx] = fmaxf(Hh[idx] + b[idx & (C1O - 1)], 0.f);
}

__global__ __launch_bounds__(256) void c2k(const float* __restrict__ Hh,
                                           const float* __restrict__ w,
                                           const float* __restrict__ b,
                                           float* __restrict__ out)
{
  const int s = blockIdx.x;
  float a0 = 0.f, a1 = 0.f;
  for (int j = threadIdx.x; j < C1O; j += 256) {
    float h = Hh[(size_t)s * C1O + j];
    a0 += h * w[j];
    a1 += h * w[C1O + j];
  }
  for (int o = 32; o; o >>= 1) { a0 += __shfl_down(a0, o); a1 += __shfl_down(a1, o); }
  __shared__ float p0[4], p1[4];
  const int wv = threadIdx.x >> 6;
  if ((threadIdx.x & 63) == 0) { p0[wv] = a0; p1[wv] = a1; }
  __syncthreads();
  if (threadIdx.x == 0) {
    out[s * 2 + 0] = p0[0] + p0[1] + p0[2] + p0[3] + b[0];
    out[s * 2 + 1] = p1[0] + p1[1] + p1[2] + p1[3] + b[1];
  }
}

// ---------------------------------------------------------------------------
extern "C" void kernel_launch(void* const* d_in, const int* in_sizes, int n_in,
                              void* d_out, int out_size, void* d_ws, size_t ws_size,
                              hipStream_t stream)
{
  const float* X    = (const float*)d_in[0];
  const float* Z    = (const float*)d_in[1];
  const float* cv1w = (const float*)d_in[2];
  const float* cv1b = (const float*)d_in[3];
  const float* cv2w = (const float*)d_in[4];
  const float* cv2b = (const float*)d_in[5];
  const float* nw   = (const float*)d_in[6];
  const float* ew   = (const float*)d_in[7];
  const float* bng  = (const float*)d_in[8];
  const float* bnb  = (const float*)d_in[9];
  const float* beg  = (const float*)d_in[10];
  const float* beb  = (const float*)d_in[11];
  const float* lnw  = (const float*)d_in[12];
  const float* lnb  = (const float*)d_in[13];
  const float* lng  = (const float*)d_in[14];
  const float* lnbt = (const float*)d_in[15];
  const float* lew  = (const float*)d_in[16];
  const float* leb  = (const float*)d_in[17];
  const float* leg  = (const float*)d_in[18];
  const float* lebt = (const float*)d_in[19];
  const float* fc1w = (const float*)d_in[20];
  const float* fc1b = (const float*)d_in[21];
  const float* fc2w = (const float*)d_in[22];
  const float* fc2b = (const float*)d_in[23];
  float* out = (float*)d_out;

  // workspace layout (~320 MiB total, well under proven 381.5 MB)
  char* base = (char*)d_ws;
  ushort* ZHi  = (ushort*)base;                     base += (size_t)NS * KH * 2;
  ushort* ZLo  = (ushort*)base;                     base += (size_t)NS * KH * 2;
  ushort* ARHi = (ushort*)base;                     base += (size_t)NS * KH * 2;
  ushort* ARLo = (ushort*)base;                     base += (size_t)NS * KH * 2;
  ushort* XZb  = (ushort*)base;                     base += (size_t)NS * XZC * 2;
  ushort* c1wh = (ushort*)base;                     base += (size_t)C1O * XZC * 2;
  ushort* lewh = (ushort*)base;                     base += (size_t)384 * KH * 2;
  ushort* w2Hi = (ushort*)base;                     base += (size_t)4 * KH * 2;
  ushort* w2Lo = (ushort*)base;                     base += (size_t)4 * KH * 2;
  ushort* eHi  = (ushort*)base;                     base += (size_t)4 * KH * 2;
  ushort* eLo  = (ushort*)base;                     base += (size_t)4 * KH * 2;
  float* Xb = (float*)base;                         base += (size_t)NS * DN * 4;
  float* X1 = (float*)base;                         base += (size_t)NS * DN * 4;
  float* XZ = (float*)base;                         base += (size_t)NS * XZC * 4;
  float* HH = (float*)base;                         base += (size_t)NS * C1O * 4;
  float* Kf = (float*)base;                         base += (size_t)NS * 384 * 4;
  float* ST = (float*)base;                         base += 2048 * 4;
  float* STrep = (float*)base;   // NREP x 512 replicated stat buckets

  hipMemcpyAsync(Xb, X, sizeof(float) * (size_t)NS * DN, hipMemcpyDeviceToDevice, stream);
  hipMemsetAsync(XZ, 0, sizeof(float) * (size_t)NS * XZC, stream);
  hipMemsetAsync(HH, 0, sizeof(float) * (size_t)NS * C1O, stream);
  cvt_pad<<<(unsigned)(((long long)C1O * XZC + 255) / 256), 256, 0, stream>>>(
      fc1w, c1wh, (long long)C1O * XZC);
  wprep2<<<(4 * KH) / 256, 256, 0, stream>>>(cv2w, ew, w2Hi, w2Lo, eHi, eLo);
  cvtZ0<<<NS, 256, 0, stream>>>(Z, ZHi, ZLo);

  const float rinv = 1.f / (float)NS;

  auto head384 = [&](int hd, int cof) {
    lewprep<<<(384 * KH) / 256, 256, 0, stream>>>(lew + (size_t)hd * 384 * DE, lewh);
    gemm_mfma_tn<<<dim3(3, 16, 12), 256, 0, stream>>>(
        ZHi, KH, lewh, KH, XZ, XZC, cof, KH / 32);
    hipMemsetAsync(ST, 0, sizeof(float) * 768, stream);
    headpost<<<dim3(6, 8), 256, 0, stream>>>(XZ, XZC, cof, 384, 256,
                                             leb + hd * 384, ST, ST + 384);
    colnormb<384><<<(NS * 384 + 255) / 256, 256, 0, stream>>>(
        XZ, XZb, XZC, cof, rinv, ST, ST + 384, leg + hd * 384, lebt + hd * 384, NS * 384);
  };
  auto head128 = [&](int hd, int cof) {
    gemm64<<<dim3(2, NS / 64, 4), 256, 0, stream>>>(
        Xb, DN, lnw + (size_t)hd * HD * DN, DN, XZ, XZC, cof, NS, HD, DN);
    hipMemsetAsync(ST, 0, sizeof(float) * 768, stream);
    headpost<<<dim3(2, 8), 256, 0, stream>>>(XZ, XZC, cof, HD, 256,
                                             lnb + hd * HD, ST, ST + 384);
    colnormb<HD><<<(NS * HD + 255) / 256, 256, 0, stream>>>(
        XZ, XZb, XZC, cof, rinv, ST, ST + 384, lng + hd * HD, lnbt + hd * HD, NS * HD);
  };

  head128(0, 0);
  head384(0, 640);

  for (int i = 0; i < LLY; i++) {
    // K for this layer (old X)
    kprep<<<(NS * 384 + 255) / 256, 256, 0, stream>>>(Xb, cv1w + i * 9, cv1b + i * 3, Kf);
    // zero replicated stat buckets (filled by fused epilogues below)
    hipMemsetAsync(STrep, 0, sizeof(float) * NREP * 512, stream);
    // G1+G2 fused + in-block X1 (=pTx_node) + X-branch stats (replicated)
    fusedG12<<<NS, 256, 0, stream>>>(ZHi, ZLo, w2Hi + (size_t)i * KH, w2Lo + (size_t)i * KH,
                                     cv2b + i * RR, Kf, ARHi, ARLo,
                                     Xb, nw + i * 9, X1, STrep);
    // G3+G4 fused: Z2 pair in place over A_ref pair + edge stats (replicated)
    fusedG34<<<NS, 256, 0, stream>>>(ZHi, ZLo, eHi + (size_t)i * KH, eLo + (size_t)i * KH,
                                     ARHi, ARLo, STrep);
    // fold replicas -> final stats [zsum|zsq|xsum|xsq]
    foldstats<<<2, 256, 0, stream>>>(STrep, ST + 768);
    // BN + residual
    ncl_updatez_pair<<<((unsigned)NS * DE + 255) / 256, 256, 0, stream>>>(
        ZHi, ZLo, ARHi, ARLo, beg + i * RR, beb + i * RR, ST + 768, ST + 768 + 128);
    ncl_update<3><<<((unsigned)NS * DN + 255) / 256, 256, 0, stream>>>(
        Xb, X1, bng + i * RR, bnb + i * RR, ST + 768 + 256, ST + 768 + 384,
        1.f / (float)(NS * 3), (unsigned)NS * DN);
    // heads on updated Z and X
    head384(i + 1, 640 + (i + 1) * 384);
    head128(i + 1, (i + 1) * HD);
  }

  // c1: h = relu(XZb @ c1_w^T + b) via bf16 MFMA split-K=4
  gemm_mfma_tn<<<dim3(C1O / 128, NS / 128, 4), 256, 0, stream>>>(
      XZb, XZC, c1wh, XZC, HH, C1O, 0, XZC / 32);
  hpost<<<((unsigned)NS * C1O + 255) / 256, 256, 0, stream>>>(HH, fc1b, (unsigned)NS * C1O);
  c2k<<<NS, 256, 0, stream>>>(HH, fc2w, fc2b, out);
}

// Round 7
// 2565.772 us; speedup vs baseline: 1.4837x; 1.0204x over previous
//
#include <hip/hip_runtime.h>
#include <hip/hip_bf16.h>

#define NS  2048
#define RR  116
#define LLY 4
#define HD  128
#define DN  348
#define DE  13456
#define KH  16384    // 128x128 per-sample slab
#define SP  136      // padded LDS slab row stride (ushorts)
#define XZC 2560
#define C1O 1024
#define EPSF 1e-5f
#define NREP 64      // stat-replica buckets (atomic contention 4096 -> 64)

typedef __attribute__((ext_vector_type(8))) short short8;
typedef __attribute__((ext_vector_type(4))) float floatx4;

static __device__ __forceinline__ ushort f2bf(float x) {
  union { __hip_bfloat16 b; ushort u; } cv;
  cv.b = __float2bfloat16(x);
  return cv.u;
}
static __device__ __forceinline__ float bf2f(ushort u) {
  union { ushort u; __hip_bfloat16 b; } cv;
  cv.u = u;
  return __bfloat162float(cv.b);
}
static __device__ __forceinline__ float fexp2(float x) {
#if __has_builtin(__builtin_amdgcn_exp2f)
  return __builtin_amdgcn_exp2f(x);
#else
  return exp2f(x);
#endif
}

#define GLDS16(gsrc, ldst) __builtin_amdgcn_global_load_lds( \
    (const __attribute__((address_space(1))) unsigned int*)(gsrc), \
    (__attribute__((address_space(3))) unsigned int*)(ldst), 16, 0, 0)

// ---------------------------------------------------------------------------
// fp32 tiled GEMM (node heads), split-K atomic accumulate (bias/relu/stats in
// headpost afterwards). C must be pre-zeroed.
// ---------------------------------------------------------------------------
__global__ __launch_bounds__(256) void gemm64(
    const float* __restrict__ A, int lda,
    const float* __restrict__ B, int ldb,
    float* __restrict__ C, int ldc, int cof,
    int M, int N, int K)
{
  const int m0 = blockIdx.y * 64, n0 = blockIdx.x * 64;
  const int ktiles = (K + 15) >> 4;
  const int kt0 = (int)((long long)ktiles * blockIdx.z / gridDim.z);
  const int kt1 = (int)((long long)ktiles * (blockIdx.z + 1) / gridDim.z);
  __shared__ float As[16][68];
  __shared__ float Bs[16][68];
  const int t = threadIdx.x;
  const int tx = t & 15, ty = t >> 4;
  float acc[4][4] = {};
  for (int kt = kt0; kt < kt1; kt++) {
    const int kb = kt * 16;
    {
      int mm = t >> 2, kk = (t & 3) << 2;
      int gm = m0 + mm, gk = kb + kk;
      float4 v = make_float4(0.f, 0.f, 0.f, 0.f);
      if (gm < M && gk < K) v = *(const float4*)(A + (size_t)gm * lda + gk);
      As[kk + 0][mm] = v.x; As[kk + 1][mm] = v.y; As[kk + 2][mm] = v.z; As[kk + 3][mm] = v.w;
      int gn = n0 + mm;
      float4 u = make_float4(0.f, 0.f, 0.f, 0.f);
      if (gn < N && gk < K) u = *(const float4*)(B + (size_t)gn * ldb + gk);
      Bs[kk + 0][mm] = u.x; Bs[kk + 1][mm] = u.y; Bs[kk + 2][mm] = u.z; Bs[kk + 3][mm] = u.w;
    }
    __syncthreads();
#pragma unroll
    for (int kk = 0; kk < 16; kk++) {
      float4 av = *(const float4*)&As[kk][ty << 2];
      float4 bv = *(const float4*)&Bs[kk][tx << 2];
      acc[0][0] += av.x * bv.x; acc[0][1] += av.x * bv.y; acc[0][2] += av.x * bv.z; acc[0][3] += av.x * bv.w;
      acc[1][0] += av.y * bv.x; acc[1][1] += av.y * bv.y; acc[1][2] += av.y * bv.z; acc[1][3] += av.y * bv.w;
      acc[2][0] += av.z * bv.x; acc[2][1] += av.z * bv.y; acc[2][2] += av.z * bv.z; acc[2][3] += av.z * bv.w;
      acc[3][0] += av.w * bv.x; acc[3][1] += av.w * bv.y; acc[3][2] += av.w * bv.z; acc[3][3] += av.w * bv.w;
    }
    __syncthreads();
  }
#pragma unroll
  for (int i = 0; i < 4; i++) {
    int m = m0 + (ty << 2) + i;
#pragma unroll
    for (int j = 0; j < 4; j++) {
      int n = n0 + (tx << 2) + j;
      if (m < M && n < N)
        atomicAdd(&C[(size_t)m * ldc + cof + n], acc[i][j]);
    }
  }
}

// ---------------------------------------------------------------------------
// bf16 MFMA TN GEMM (big heads): C += A[M][lka]*B[N][lkb]^T, split-K atomics.
// Single-buffer stage->barrier->compute->barrier (proven R2 structure).
// ---------------------------------------------------------------------------
__global__ __launch_bounds__(256) void gemm_mfma_tn(
    const ushort* __restrict__ A, int lka,
    const ushort* __restrict__ B, int lkb,
    float* __restrict__ C, int ldc, int cof,
    int ktiles)
{
  __shared__ __align__(16) ushort As[128 * 32];
  __shared__ __align__(16) ushort Bs[128 * 32];
  const int t = threadIdx.x;
  const int m0 = blockIdx.y * 128, n0 = blockIdx.x * 128;
  const int kt0 = (int)((long long)ktiles * blockIdx.z / gridDim.z);
  const int kt1 = (int)((long long)ktiles * (blockIdx.z + 1) / gridDim.z);
  const int w = t >> 6, lane = t & 63;
  const int wm = (w >> 1) << 6, wn = (w & 1) << 6;
  const int fr = lane & 15, quad = lane >> 4;
  const int row0 = t >> 2, row1 = (t + 256) >> 2;
  const int ko = (t & 3) * 8;
  floatx4 acc[4][4] = {};
  for (int kt = kt0; kt < kt1; ++kt) {
    const int kb = kt * 32;
    GLDS16(A + (size_t)(m0 + row0) * lka + kb + ko, &As[(size_t)t * 8]);
    GLDS16(A + (size_t)(m0 + row1) * lka + kb + ko, &As[(size_t)(t + 256) * 8]);
    GLDS16(B + (size_t)(n0 + row0) * lkb + kb + ko, &Bs[(size_t)t * 8]);
    GLDS16(B + (size_t)(n0 + row1) * lkb + kb + ko, &Bs[(size_t)(t + 256) * 8]);
    __syncthreads();
    short8 af[4], bf[4];
#pragma unroll
    for (int i = 0; i < 4; i++)
      af[i] = *(const short8*)&As[(wm + i * 16 + fr) * 32 + quad * 8];
#pragma unroll
    for (int j = 0; j < 4; j++)
      bf[j] = *(const short8*)&Bs[(wn + j * 16 + fr) * 32 + quad * 8];
#pragma unroll
    for (int i = 0; i < 4; i++)
#pragma unroll
      for (int j = 0; j < 4; j++)
        acc[i][j] = __builtin_amdgcn_mfma_f32_16x16x32_bf16(af[i], bf[j], acc[i][j], 0, 0, 0);
    __syncthreads();
  }
#pragma unroll
  for (int i = 0; i < 4; i++) {
#pragma unroll
    for (int j = 0; j < 4; j++) {
      int n = n0 + wn + j * 16 + fr;
#pragma unroll
      for (int r = 0; r < 4; r++) {
        int m = m0 + wm + i * 16 + quad * 4 + r;
        atomicAdd(&C[(size_t)m * ldc + cof + n], acc[i][j][r]);
      }
    }
  }
}

// ---------------------------------------------------------------------------
// fusedG12: per sample s:
//   G1: Vt[l][o] = sum_i Z[l][i]*w2[o][i] + b2[o]   (split-bf16, acc fp32)
//   G2: A[m][l]  = sum_k Vt[m][k]*att[l][k]         (att generated in-regs)
//   X1: X1[m]    = (A @ X) @ node_w  (+ X-branch BN stats into replica bucket)
// Stats go to strep[(s&63)*512 + 256/384 + m] -> ~32 same-addr atomics/bucket.
// ---------------------------------------------------------------------------
__global__ __launch_bounds__(256) void fusedG12(
    const ushort* __restrict__ ZHi, const ushort* __restrict__ ZLo,
    const ushort* __restrict__ WHi, const ushort* __restrict__ WLo,
    const float* __restrict__ b2, const float* __restrict__ Kf,
    ushort* __restrict__ AHi, ushort* __restrict__ ALo,
    const float* __restrict__ Xg, const float* __restrict__ nw,
    float* __restrict__ X1, float* __restrict__ strep)
{
  __shared__ __align__(16) ushort pool[2 * 128 * SP];   // 69632 B
  ushort* VtHi = pool;
  ushort* VtLo = pool + 128 * SP;
  ushort* tAhi = pool;
  ushort* tAlo = pool + 4096;
  ushort* tBhi = pool + 8192;
  ushort* tBlo = pool + 12288;
  __shared__ float Ks0[128], Ks1[128], Ks2[128], Mrow[128], Minv[128];
  __shared__ float Xs[DN];
  const int s = blockIdx.x;
  const int t = threadIdx.x;
  if (t < 128) {
    const float* kf = Kf + (size_t)s * 384;
    const float lam = 1.2011224087864498f;  // sqrt(log2 e): dots land in log2 domain
    Ks0[t] = kf[t] * lam; Ks1[t] = kf[128 + t] * lam; Ks2[t] = kf[256 + t] * lam;
  }
  for (int ii = t; ii < DN; ii += 256) Xs[ii] = Xg[(size_t)s * DN + ii];
  __syncthreads();
  if (t < 128) {
    if (t < RR) {
      float k0 = Ks0[t], k1 = Ks1[t], k2 = Ks2[t];
      float mx = -3.0e38f;
      for (int k = 0; k < RR; k++)
        mx = fmaxf(mx, k0 * Ks0[k] + k1 * Ks1[k] + k2 * Ks2[k]);
      float sm = 0.f;
      for (int k = 0; k < RR; k++)
        sm += fexp2(k0 * Ks0[k] + k1 * Ks1[k] + k2 * Ks2[k] - mx);
      Mrow[t] = mx; Minv[t] = 1.f / sm;
    } else { Mrow[t] = 0.f; Minv[t] = 0.f; }
  }
  const int w = t >> 6, lane = t & 63;
  const int wm = (w >> 1) << 6, wn = (w & 1) << 6;
  const int fr = lane & 15, quad = lane >> 4;
  const int r0 = t >> 2, c8 = (t & 3) * 8;
  // ---- G1 ----
  floatx4 acc[4][4] = {};
  for (int kt = 0; kt < 4; kt++) {
    const int kb = kt * 32;
    const size_t go = (size_t)s * KH + (size_t)r0 * 128 + kb + c8;
    GLDS16(ZHi + go, &tAhi[t * 8]);
    GLDS16(ZHi + go + 64 * 128, &tAhi[2048 + t * 8]);
    GLDS16(ZLo + go, &tAlo[t * 8]);
    GLDS16(ZLo + go + 64 * 128, &tAlo[2048 + t * 8]);
    const size_t wo = (size_t)r0 * 128 + kb + c8;
    GLDS16(WHi + wo, &tBhi[t * 8]);
    GLDS16(WHi + wo + 64 * 128, &tBhi[2048 + t * 8]);
    GLDS16(WLo + wo, &tBlo[t * 8]);
    GLDS16(WLo + wo + 64 * 128, &tBlo[2048 + t * 8]);
    __syncthreads();
    short8 ah[4], al[4], bh[4], bl[4];
#pragma unroll
    for (int i = 0; i < 4; i++) {
      ah[i] = *(const short8*)&tAhi[(wm + i * 16 + fr) * 32 + quad * 8];
      al[i] = *(const short8*)&tAlo[(wm + i * 16 + fr) * 32 + quad * 8];
    }
#pragma unroll
    for (int j = 0; j < 4; j++) {
      bh[j] = *(const short8*)&tBhi[(wn + j * 16 + fr) * 32 + quad * 8];
      bl[j] = *(const short8*)&tBlo[(wn + j * 16 + fr) * 32 + quad * 8];
    }
#pragma unroll
    for (int i = 0; i < 4; i++)
#pragma unroll
      for (int j = 0; j < 4; j++) {
        acc[i][j] = __builtin_amdgcn_mfma_f32_16x16x32_bf16(ah[i], bh[j], acc[i][j], 0, 0, 0);
        acc[i][j] = __builtin_amdgcn_mfma_f32_16x16x32_bf16(al[i], bh[j], acc[i][j], 0, 0, 0);
        acc[i][j] = __builtin_amdgcn_mfma_f32_16x16x32_bf16(ah[i], bl[j], acc[i][j], 0, 0, 0);
      }
    __syncthreads();
  }
  // bias + split into LDS Vt slabs (stage buffers are dead past this barrier)
#pragma unroll
  for (int i = 0; i < 4; i++) {
#pragma unroll
    for (int j = 0; j < 4; j++) {
      int n = wn + j * 16 + fr;
      float bb = (n < RR) ? b2[n] : 0.f;
#pragma unroll
      for (int r = 0; r < 4; r++) {
        int m = wm + i * 16 + quad * 4 + r;
        float v = acc[i][j][r] + bb;
        ushort h = f2bf(v);
        VtHi[m * SP + n] = h;
        VtLo[m * SP + n] = f2bf(v - bf2f(h));
      }
    }
  }
  __syncthreads();
  // ---- G2 ----
  float Lk0[4], Lk1[4], Lk2[4], Lnm[4];
#pragma unroll
  for (int j = 0; j < 4; j++) {
    int l = wn + j * 16 + fr;
    Lk0[j] = Ks0[l]; Lk1[j] = Ks1[l]; Lk2[j] = Ks2[l]; Lnm[j] = -Mrow[l];
  }
  floatx4 ac2[4][4] = {};
  for (int kt = 0; kt < 4; kt++) {
    const int kb = kt * 32;
    float K0e[8], K1e[8], K2e[8];
#pragma unroll
    for (int e = 0; e < 8; e++) {
      int k = kb + quad * 8 + e;
      K0e[e] = Ks0[k]; K1e[e] = Ks1[k]; K2e[e] = Ks2[k];
    }
    short8 ah[4], al[4];
#pragma unroll
    for (int i = 0; i < 4; i++) {
      ah[i] = *(const short8*)&VtHi[(wm + i * 16 + fr) * SP + kb + quad * 8];
      al[i] = *(const short8*)&VtLo[(wm + i * 16 + fr) * SP + kb + quad * 8];
    }
#pragma unroll
    for (int j = 0; j < 4; j++) {
      // no l/k guards: Vt[:,k>=RR]=0 kills k-pads; Minv[l>=RR]=0 kills l-pads
      short8 bh, bl;
#pragma unroll
      for (int e = 0; e < 8; e++) {
        float d = fmaf(Lk0[j], K0e[e], Lnm[j]);
        d = fmaf(Lk1[j], K1e[e], d);
        d = fmaf(Lk2[j], K2e[e], d);
        float a = fexp2(d);
        ushort h = f2bf(a);
        ((ushort*)&bh)[e] = h;
        ((ushort*)&bl)[e] = f2bf(a - bf2f(h));
      }
#pragma unroll
      for (int i = 0; i < 4; i++) {
        ac2[i][j] = __builtin_amdgcn_mfma_f32_16x16x32_bf16(ah[i], bh, ac2[i][j], 0, 0, 0);
        ac2[i][j] = __builtin_amdgcn_mfma_f32_16x16x32_bf16(al[i], bh, ac2[i][j], 0, 0, 0);
        ac2[i][j] = __builtin_amdgcn_mfma_f32_16x16x32_bf16(ah[i], bl, ac2[i][j], 0, 0, 0);
      }
    }
  }
  // all Vt reads done -> pool reusable as fp32 A [128][133]
  __syncthreads();
  float* Af = (float*)pool;
  ushort* CH = AHi + (size_t)s * KH;
  ushort* CL = ALo + (size_t)s * KH;
#pragma unroll
  for (int i = 0; i < 4; i++) {
#pragma unroll
    for (int j = 0; j < 4; j++) {
      int n = wn + j * 16 + fr;
      float iv = Minv[n];   // 0 for n>=RR -> pad cols stay 0
#pragma unroll
      for (int r = 0; r < 4; r++) {
        int m = wm + i * 16 + quad * 4 + r;
        float v = ac2[i][j][r] * iv;
        ushort h = f2bf(v);
        CH[m * 128 + n] = h;
        CL[m * 128 + n] = f2bf(v - bf2f(h));
        Af[m * 133 + n] = v;
      }
    }
  }
  __syncthreads();
  // ---- X1 = (A @ X) @ node_w + X-branch BN stats (replica bucket) ----
  if (t < RR) {
    float t0 = 0.f, t1 = 0.f, t2 = 0.f;
    const float* ar = Af + t * 133;
    for (int l = 0; l < RR; l++) {
      float p = ar[l];
      t0 += p * Xs[l * 3 + 0];
      t1 += p * Xs[l * 3 + 1];
      t2 += p * Xs[l * 3 + 2];
    }
    float o0 = t0 * nw[0] + t1 * nw[3] + t2 * nw[6];
    float o1 = t0 * nw[1] + t1 * nw[4] + t2 * nw[7];
    float o2 = t0 * nw[2] + t1 * nw[5] + t2 * nw[8];
    float* Op = X1 + (size_t)s * DN + t * 3;
    Op[0] = o0; Op[1] = o1; Op[2] = o2;
    float* rep = strep + (size_t)(s & (NREP - 1)) * 512;
    atomicAdd(&rep[256 + t], o0 + o1 + o2);
    atomicAdd(&rep[384 + t], o0 * o0 + o1 * o1 + o2 * o2);
  }
}

// ---------------------------------------------------------------------------
// fusedG34: per sample s:
//   G3: W1[j][l] = sum_k Z[j][k]*ewT[l][k]   -> W1T hi/lo slab in LDS
//   G4: Z2[i][l] = sum_j A[i][j]*W1T[l][j]   -> split store in place over A
//   + edge-branch BN stats (channel = row i) into replica bucket (s&63)
// ---------------------------------------------------------------------------
__global__ __launch_bounds__(256) void fusedG34(
    const ushort* __restrict__ ZHi, const ushort* __restrict__ ZLo,
    const ushort* __restrict__ EHi, const ushort* __restrict__ ELo,
    ushort* __restrict__ AHi, ushort* __restrict__ ALo,
    float* __restrict__ strep)
{
  __shared__ __align__(16) ushort pool[2 * 128 * SP];   // 69632 B
  ushort* WtHi = pool;
  ushort* WtLo = pool + 128 * SP;
  ushort* tAhi = pool;
  ushort* tAlo = pool + 4096;
  ushort* tBhi = pool + 8192;
  ushort* tBlo = pool + 12288;
  const int s = blockIdx.x;
  const int t = threadIdx.x;
  const int w = t >> 6, lane = t & 63;
  const int wm = (w >> 1) << 6, wn = (w & 1) << 6;
  const int fr = lane & 15, quad = lane >> 4;
  const int r0 = t >> 2, c8 = (t & 3) * 8;
  // ---- G3 ----
  floatx4 acc[4][4] = {};
  for (int kt = 0; kt < 4; kt++) {
    const int kb = kt * 32;
    const size_t go = (size_t)s * KH + (size_t)r0 * 128 + kb + c8;
    GLDS16(ZHi + go, &tAhi[t * 8]);
    GLDS16(ZHi + go + 64 * 128, &tAhi[2048 + t * 8]);
    GLDS16(ZLo + go, &tAlo[t * 8]);
    GLDS16(ZLo + go + 64 * 128, &tAlo[2048 + t * 8]);
    const size_t eo = (size_t)r0 * 128 + kb + c8;
    GLDS16(EHi + eo, &tBhi[t * 8]);
    GLDS16(EHi + eo + 64 * 128, &tBhi[2048 + t * 8]);
    GLDS16(ELo + eo, &tBlo[t * 8]);
    GLDS16(ELo + eo + 64 * 128, &tBlo[2048 + t * 8]);
    __syncthreads();
    short8 ah[4], al[4], bh[4], bl[4];
#pragma unroll
    for (int i = 0; i < 4; i++) {
      ah[i] = *(const short8*)&tAhi[(wm + i * 16 + fr) * 32 + quad * 8];
      al[i] = *(const short8*)&tAlo[(wm + i * 16 + fr) * 32 + quad * 8];
    }
#pragma unroll
    for (int j = 0; j < 4; j++) {
      bh[j] = *(const short8*)&tBhi[(wn + j * 16 + fr) * 32 + quad * 8];
      bl[j] = *(const short8*)&tBlo[(wn + j * 16 + fr) * 32 + quad * 8];
    }
#pragma unroll
    for (int i = 0; i < 4; i++)
#pragma unroll
      for (int j = 0; j < 4; j++) {
        acc[i][j] = __builtin_amdgcn_mfma_f32_16x16x32_bf16(ah[i], bh[j], acc[i][j], 0, 0, 0);
        acc[i][j] = __builtin_amdgcn_mfma_f32_16x16x32_bf16(al[i], bh[j], acc[i][j], 0, 0, 0);
        acc[i][j] = __builtin_amdgcn_mfma_f32_16x16x32_bf16(ah[i], bl[j], acc[i][j], 0, 0, 0);
      }
    __syncthreads();
  }
  // transposed split store W1 -> W1T slabs (stage buffers dead past barrier)
#pragma unroll
  for (int i = 0; i < 4; i++) {
#pragma unroll
    for (int j = 0; j < 4; j++) {
      int n = wn + j * 16 + fr;
      int mb = wm + i * 16 + quad * 4;
      ushort4 ph, pl;
#pragma unroll
      for (int r = 0; r < 4; r++) {
        float v = acc[i][j][r];
        ushort h = f2bf(v);
        ((ushort*)&ph)[r] = h;
        ((ushort*)&pl)[r] = f2bf(v - bf2f(h));
      }
      *(ushort4*)&WtHi[n * SP + mb] = ph;
      *(ushort4*)&WtLo[n * SP + mb] = pl;
    }
  }
  __syncthreads();
  // ---- G4 ----  (A fragments straight from global; Wt from LDS; no barriers)
  const ushort* GAh = AHi + (size_t)s * KH;
  const ushort* GAl = ALo + (size_t)s * KH;
  floatx4 ac2[4][4] = {};
  for (int kt = 0; kt < 4; kt++) {
    const int kb = kt * 32;
    short8 ah[4], al[4], bh[4], bl[4];
#pragma unroll
    for (int i = 0; i < 4; i++) {
      const size_t ro = (size_t)(wm + i * 16 + fr) * 128 + kb + quad * 8;
      ah[i] = *(const short8*)(GAh + ro);
      al[i] = *(const short8*)(GAl + ro);
    }
#pragma unroll
    for (int j = 0; j < 4; j++) {
      bh[j] = *(const short8*)&WtHi[(wn + j * 16 + fr) * SP + kb + quad * 8];
      bl[j] = *(const short8*)&WtLo[(wn + j * 16 + fr) * SP + kb + quad * 8];
    }
#pragma unroll
    for (int i = 0; i < 4; i++)
#pragma unroll
      for (int j = 0; j < 4; j++) {
        ac2[i][j] = __builtin_amdgcn_mfma_f32_16x16x32_bf16(ah[i], bh[j], ac2[i][j], 0, 0, 0);
        ac2[i][j] = __builtin_amdgcn_mfma_f32_16x16x32_bf16(al[i], bh[j], ac2[i][j], 0, 0, 0);
        ac2[i][j] = __builtin_amdgcn_mfma_f32_16x16x32_bf16(ah[i], bl[j], ac2[i][j], 0, 0, 0);
      }
  }
  // all waves must finish READING A before anyone overwrites it in place
  __syncthreads();
  ushort* CH = AHi + (size_t)s * KH;
  ushort* CL = ALo + (size_t)s * KH;
#pragma unroll
  for (int i = 0; i < 4; i++) {
#pragma unroll
    for (int j = 0; j < 4; j++) {
      int n = wn + j * 16 + fr;
#pragma unroll
      for (int r = 0; r < 4; r++) {
        int m = wm + i * 16 + quad * 4 + r;
        float v = ac2[i][j][r];
        ushort h = f2bf(v);
        CH[m * 128 + n] = h;
        CL[m * 128 + n] = f2bf(v - bf2f(h));
      }
    }
  }
  // edge-branch BN stats into replica bucket: channel = row m; this wave's 64
  // cols reduced via 16-lane shfl (cols n>=RR are exact zeros -> harmless)
  float* rep = strep + (size_t)(s & (NREP - 1)) * 512;
#pragma unroll
  for (int i = 0; i < 4; i++) {
#pragma unroll
    for (int r = 0; r < 4; r++) {
      int m = wm + i * 16 + quad * 4 + r;
      float a = 0.f, q = 0.f;
#pragma unroll
      for (int j = 0; j < 4; j++) { float v = ac2[i][j][r]; a += v; q += v * v; }
      a += __shfl_xor(a, 1); q += __shfl_xor(q, 1);
      a += __shfl_xor(a, 2); q += __shfl_xor(q, 2);
      a += __shfl_xor(a, 4); q += __shfl_xor(q, 4);
      a += __shfl_xor(a, 8); q += __shfl_xor(q, 8);
      if ((lane & 15) == 0 && m < RR) {
        atomicAdd(&rep[m], a);
        atomicAdd(&rep[128 + m], q);
      }
    }
  }
}

// fold NREP stat replicas [NREP][512] -> final [512]
__global__ __launch_bounds__(256) void foldstats(
    const float* __restrict__ rep, float* __restrict__ outp)
{
  int c = blockIdx.x * 256 + threadIdx.x;   // 512 channels
  float a = 0.f;
  for (int r = 0; r < NREP; r++) a += rep[(size_t)r * 512 + c];
  outp[c] = a;
}

// K precompute: Kf[s][c*128+l] = conv1_w[c]·X[s][l] + b[c]  (0 for l>=RR)
__global__ void kprep(const float* __restrict__ Xb, const float* __restrict__ kw,
                      const float* __restrict__ kb, float* __restrict__ Kf)
{
  int idx = blockIdx.x * 256 + threadIdx.x;
  if (idx >= NS * 384) return;
  int s = idx / 384, r = idx - s * 384;
  int c = r >> 7, l = r & 127;
  float v = 0.f;
  if (l < RR) {
    const float* xp = Xb + (size_t)s * DN + l * 3;
    v = kw[c * 3 + 0] * xp[0] + kw[c * 3 + 1] * xp[1] + kw[c * 3 + 2] * xp[2] + kb[c];
  }
  Kf[idx] = v;
}

// initial Z -> hi/lo slabs (zero-padded)
__global__ __launch_bounds__(256) void cvtZ0(
    const float* __restrict__ Z, ushort* __restrict__ ZHi, ushort* __restrict__ ZLo)
{
  const int s = blockIdx.x;
  const float* Zp = Z + (size_t)s * DE;
  ushort* h = ZHi + (size_t)s * KH;
  ushort* lo = ZLo + (size_t)s * KH;
  for (int idx = threadIdx.x; idx < KH; idx += 256) {
    int l = idx >> 7, i = idx & 127;
    if ((l < RR) && (i < RR)) {
      float v = Zp[l * RR + i];
      ushort hh = f2bf(v);
      h[idx] = hh; lo[idx] = f2bf(v - bf2f(hh));
    } else { h[idx] = 0; lo[idx] = 0; }
  }
}

// weight prep: w2 pair [o][i]; ewT pair [l][k]=ew[k][l]  (padded, all layers)
__global__ void wprep2(const float* __restrict__ w2, const float* __restrict__ ew,
                       ushort* __restrict__ w2Hi, ushort* __restrict__ w2Lo,
                       ushort* __restrict__ eHi, ushort* __restrict__ eLo)
{
  int idx = blockIdx.x * 256 + threadIdx.x;   // 4*16384
  int ly = idx >> 14, k = idx & (KH - 1);
  int r = k >> 7, c = k & 127;
  bool v = (r < RR) && (c < RR);
  float a = v ? w2[ly * DE + r * RR + c] : 0.f;
  float b = v ? ew[ly * DE + c * RR + r] : 0.f;
  ushort ha = f2bf(a), hb = f2bf(b);
  w2Hi[idx] = ha; w2Lo[idx] = f2bf(a - bf2f(ha));
  eHi[idx] = hb; eLo[idx] = f2bf(b - bf2f(hb));
}

// lew head weights: [384][13456] fp32 -> [384][16384] bf16 hole-padded
__global__ void lewprep(const float* __restrict__ src, ushort* __restrict__ dst)
{
  int idx = blockIdx.x * 256 + threadIdx.x;   // 384*16384
  int h = idx >> 14, k = idx & (KH - 1);
  int l = k >> 7, i = k & 127;
  bool v = (l < RR) && (i < RR);
  dst[idx] = v ? f2bf(src[(size_t)h * DE + l * RR + i]) : (ushort)0;
}

// fp32 -> bf16 plain convert (c1 weights)
__global__ void cvt_pad(const float* __restrict__ src, ushort* __restrict__ dst,
                        long long total)
{
  long long idx = (long long)blockIdx.x * 256 + threadIdx.x;
  if (idx < total) dst[idx] = f2bf(src[idx]);
}

// ---------------------------------------------------------------------------
// BN helpers
// ---------------------------------------------------------------------------
__global__ __launch_bounds__(256) void headpost(
    float* __restrict__ Y, int ldy, int cof, int ncols, int chunk,
    const float* __restrict__ bias,
    float* __restrict__ sum, float* __restrict__ sq)
{
  const int cl = threadIdx.x & 63;
  const int c = blockIdx.x * 64 + cl;
  const int r4 = threadIdx.x >> 6;
  const int s0 = blockIdx.y * chunk;
  float a = 0.f, q = 0.f;
  if (c < ncols) {
    float bb = bias[c];
    for (int r = s0 + r4; r < s0 + chunk; r += 4) {
      size_t o = (size_t)r * ldy + cof + c;
      float v = fmaxf(Y[o] + bb, 0.f);
      Y[o] = v;
      a += v; q += v * v;
    }
  }
  __shared__ float la[4][64], lq[4][64];
  la[r4][cl] = a; lq[r4][cl] = q;
  __syncthreads();
  if (threadIdx.x < 64) {
    int cc = blockIdx.x * 64 + threadIdx.x;
    if (cc < ncols) {
      float aa = la[0][threadIdx.x] + la[1][threadIdx.x] + la[2][threadIdx.x] + la[3][threadIdx.x];
      float qq = lq[0][threadIdx.x] + lq[1][threadIdx.x] + lq[2][threadIdx.x] + lq[3][threadIdx.x];
      atomicAdd(&sum[cc], aa);
      atomicAdd(&sq[cc], qq);
    }
  }
}

template<int NC>
__global__ void colnormb(const float* __restrict__ Y, ushort* __restrict__ Yb,
                         int ldy, int cof, float rinv,
                         const float* __restrict__ sum, const float* __restrict__ sq,
                         const float* __restrict__ g, const float* __restrict__ b,
                         unsigned total)
{
  unsigned idx = blockIdx.x * 256u + threadIdx.x;
  if (idx >= total) return;
  unsigned r = idx / NC, c = idx - r * NC;
  float m = sum[c] * rinv;
  float v = sq[c] * rinv - m * m;
  float iv = rsqrtf(v + EPSF);
  size_t o = (size_t)r * ldy + cof + c;
  Yb[o] = f2bf((Y[o] - m) * iv * g[c] + b[c]);
}

// Z master (hi/lo) += relu(bn(Z2 pair)) — vectorized short8 over padded slabs.
// Thread owns 8 contiguous cols of one row i; row never crossed (128%8==0).
// Pad rows (i>=RR) skipped (stay 0); pad cols masked to 0 within boundary grp.
__global__ __launch_bounds__(256) void ncl_updatez_pair8(
    ushort* __restrict__ ZHi, ushort* __restrict__ ZLo,
    const ushort* __restrict__ Z2Hi, const ushort* __restrict__ Z2Lo,
    const float* __restrict__ g, const float* __restrict__ b,
    const float* __restrict__ sum, const float* __restrict__ sq)
{
  const unsigned idx = blockIdx.x * 256u + threadIdx.x;   // NS*KH/8 threads
  const unsigned e8 = idx * 8u;
  const unsigned s = e8 >> 14;            // /KH
  const unsigned o = e8 & (KH - 1);
  const unsigned i = o >> 7;              // channel (row)
  const unsigned l0 = o & 127;            // col start (multiple of 8)
  if (i >= RR) return;                     // pad rows stay zero
  const float invcnt = 1.f / (float)(NS * RR);
  const float m = sum[i] * invcnt;
  const float v = sq[i] * invcnt - m * m;
  const float iv = rsqrtf(v + EPSF);
  const float gg = g[i], bb = b[i];
  const size_t off = (size_t)s * KH + o;
  short8 z2h = *(const short8*)(Z2Hi + off);
  short8 z2l = *(const short8*)(Z2Lo + off);
  short8 zh  = *(const short8*)(ZHi + off);
  short8 zl  = *(const short8*)(ZLo + off);
  short8 oh, ol;
#pragma unroll
  for (int e = 0; e < 8; e++) {
    unsigned l = l0 + e;
    if (l < RR) {
      float z2 = bf2f(((const ushort*)&z2h)[e]) + bf2f(((const ushort*)&z2l)[e]);
      float z = (z2 - m) * iv * gg + bb;
      float nv = bf2f(((const ushort*)&zh)[e]) + bf2f(((const ushort*)&zl)[e]) + fmaxf(z, 0.f);
      ushort h = f2bf(nv);
      ((ushort*)&oh)[e] = h;
      ((ushort*)&ol)[e] = f2bf(nv - bf2f(h));
    } else {
      ((ushort*)&oh)[e] = 0;
      ((ushort*)&ol)[e] = 0;
    }
  }
  *(short8*)(ZHi + off) = oh;
  *(short8*)(ZLo + off) = ol;
}

template<int LC>
__global__ void ncl_update(float* __restrict__ dst, const float* __restrict__ src,
                           const float* __restrict__ g, const float* __restrict__ b,
                           const float* __restrict__ sum, const float* __restrict__ sq,
                           float invcnt, unsigned total)
{
  unsigned idx = blockIdx.x * 256u + threadIdx.x;
  if (idx >= total) return;
  int c = (int)((idx / LC) % RR);
  float m = sum[c] * invcnt;
  float v = sq[c] * invcnt - m * m;
  float iv = rsqrtf(v + EPSF);
  float z = (src[idx] - m) * iv * g[c] + b[c];
  dst[idx] += fmaxf(z, 0.f);
}

__global__ void hpost(float* __restrict__ Hh, const float* __restrict__ b, unsigned total)
{
  unsigned idx = blockIdx.x * 256u + threadIdx.x;
  if (idx >= total) return;
  Hh[idx] = fmaxf(Hh[idx] + b[idx & (C1O - 1)], 0.f);
}

__global__ __launch_bounds__(256) void c2k(const float* __restrict__ Hh,
                                           const float* __restrict__ w,
                                           const float* __restrict__ b,
                                           float* __restrict__ out)
{
  const int s = blockIdx.x;
  float a0 = 0.f, a1 = 0.f;
  for (int j = threadIdx.x; j < C1O; j += 256) {
    float h = Hh[(size_t)s * C1O + j];
    a0 += h * w[j];
    a1 += h * w[C1O + j];
  }
  for (int o = 32; o; o >>= 1) { a0 += __shfl_down(a0, o); a1 += __shfl_down(a1, o); }
  __shared__ float p0[4], p1[4];
  const int wv = threadIdx.x >> 6;
  if ((threadIdx.x & 63) == 0) { p0[wv] = a0; p1[wv] = a1; }
  __syncthreads();
  if (threadIdx.x == 0) {
    out[s * 2 + 0] = p0[0] + p0[1] + p0[2] + p0[3] + b[0];
    out[s * 2 + 1] = p1[0] + p1[1] + p1[2] + p1[3] + b[1];
  }
}

// ---------------------------------------------------------------------------
extern "C" void kernel_launch(void* const* d_in, const int* in_sizes, int n_in,
                              void* d_out, int out_size, void* d_ws, size_t ws_size,
                              hipStream_t stream)
{
  const float* X    = (const float*)d_in[0];
  const float* Z    = (const float*)d_in[1];
  const float* cv1w = (const float*)d_in[2];
  const float* cv1b = (const float*)d_in[3];
  const float* cv2w = (const float*)d_in[4];
  const float* cv2b = (const float*)d_in[5];
  const float* nw   = (const float*)d_in[6];
  const float* ew   = (const float*)d_in[7];
  const float* bng  = (const float*)d_in[8];
  const float* bnb  = (const float*)d_in[9];
  const float* beg  = (const float*)d_in[10];
  const float* beb  = (const float*)d_in[11];
  const float* lnw  = (const float*)d_in[12];
  const float* lnb  = (const float*)d_in[13];
  const float* lng  = (const float*)d_in[14];
  const float* lnbt = (const float*)d_in[15];
  const float* lew  = (const float*)d_in[16];
  const float* leb  = (const float*)d_in[17];
  const float* leg  = (const float*)d_in[18];
  const float* lebt = (const float*)d_in[19];
  const float* fc1w = (const float*)d_in[20];
  const float* fc1b = (const float*)d_in[21];
  const float* fc2w = (const float*)d_in[22];
  const float* fc2b = (const float*)d_in[23];
  float* out = (float*)d_out;

  // workspace layout (~320 MiB total, well under proven 381.5 MB)
  char* base = (char*)d_ws;
  ushort* ZHi  = (ushort*)base;                     base += (size_t)NS * KH * 2;
  ushort* ZLo  = (ushort*)base;                     base += (size_t)NS * KH * 2;
  ushort* ARHi = (ushort*)base;                     base += (size_t)NS * KH * 2;
  ushort* ARLo = (ushort*)base;                     base += (size_t)NS * KH * 2;
  ushort* XZb  = (ushort*)base;                     base += (size_t)NS * XZC * 2;
  ushort* c1wh = (ushort*)base;                     base += (size_t)C1O * XZC * 2;
  ushort* lewh = (ushort*)base;                     base += (size_t)384 * KH * 2;
  ushort* w2Hi = (ushort*)base;                     base += (size_t)4 * KH * 2;
  ushort* w2Lo = (ushort*)base;                     base += (size_t)4 * KH * 2;
  ushort* eHi  = (ushort*)base;                     base += (size_t)4 * KH * 2;
  ushort* eLo  = (ushort*)base;                     base += (size_t)4 * KH * 2;
  float* Xb = (float*)base;                         base += (size_t)NS * DN * 4;
  float* X1 = (float*)base;                         base += (size_t)NS * DN * 4;
  float* XZ = (float*)base;                         base += (size_t)NS * XZC * 4;
  float* HH = (float*)base;                         base += (size_t)NS * C1O * 4;
  float* Kf = (float*)base;                         base += (size_t)NS * 384 * 4;
  float* ST = (float*)base;                         base += 2048 * 4;
  float* STrep = (float*)base;   // NREP x 512 replicated stat buckets

  hipMemcpyAsync(Xb, X, sizeof(float) * (size_t)NS * DN, hipMemcpyDeviceToDevice, stream);
  hipMemsetAsync(XZ, 0, sizeof(float) * (size_t)NS * XZC, stream);
  hipMemsetAsync(HH, 0, sizeof(float) * (size_t)NS * C1O, stream);
  cvt_pad<<<(unsigned)(((long long)C1O * XZC + 255) / 256), 256, 0, stream>>>(
      fc1w, c1wh, (long long)C1O * XZC);
  wprep2<<<(4 * KH) / 256, 256, 0, stream>>>(cv2w, ew, w2Hi, w2Lo, eHi, eLo);
  cvtZ0<<<NS, 256, 0, stream>>>(Z, ZHi, ZLo);

  const float rinv = 1.f / (float)NS;

  auto head384 = [&](int hd, int cof) {
    lewprep<<<(384 * KH) / 256, 256, 0, stream>>>(lew + (size_t)hd * 384 * DE, lewh);
    gemm_mfma_tn<<<dim3(3, 16, 12), 256, 0, stream>>>(
        ZHi, KH, lewh, KH, XZ, XZC, cof, KH / 32);
    hipMemsetAsync(ST, 0, sizeof(float) * 768, stream);
    headpost<<<dim3(6, 8), 256, 0, stream>>>(XZ, XZC, cof, 384, 256,
                                             leb + hd * 384, ST, ST + 384);
    colnormb<384><<<(NS * 384 + 255) / 256, 256, 0, stream>>>(
        XZ, XZb, XZC, cof, rinv, ST, ST + 384, leg + hd * 384, lebt + hd * 384, NS * 384);
  };
  auto head128 = [&](int hd, int cof) {
    gemm64<<<dim3(2, NS / 64, 4), 256, 0, stream>>>(
        Xb, DN, lnw + (size_t)hd * HD * DN, DN, XZ, XZC, cof, NS, HD, DN);
    hipMemsetAsync(ST, 0, sizeof(float) * 768, stream);
    headpost<<<dim3(2, 8), 256, 0, stream>>>(XZ, XZC, cof, HD, 256,
                                             lnb + hd * HD, ST, ST + 384);
    colnormb<HD><<<(NS * HD + 255) / 256, 256, 0, stream>>>(
        XZ, XZb, XZC, cof, rinv, ST, ST + 384, lng + hd * HD, lnbt + hd * HD, NS * HD);
  };

  head128(0, 0);
  head384(0, 640);

  for (int i = 0; i < LLY; i++) {
    // K for this layer (old X)
    kprep<<<(NS * 384 + 255) / 256, 256, 0, stream>>>(Xb, cv1w + i * 9, cv1b + i * 3, Kf);
    // zero replicated stat buckets (filled by fused epilogues below)
    hipMemsetAsync(STrep, 0, sizeof(float) * NREP * 512, stream);
    // G1+G2 fused + in-block X1 (=pTx_node) + X-branch stats (replicated)
    fusedG12<<<NS, 256, 0, stream>>>(ZHi, ZLo, w2Hi + (size_t)i * KH, w2Lo + (size_t)i * KH,
                                     cv2b + i * RR, Kf, ARHi, ARLo,
                                     Xb, nw + i * 9, X1, STrep);
    // G3+G4 fused: Z2 pair in place over A_ref pair + edge stats (replicated)
    fusedG34<<<NS, 256, 0, stream>>>(ZHi, ZLo, eHi + (size_t)i * KH, eLo + (size_t)i * KH,
                                     ARHi, ARLo, STrep);
    // fold replicas -> final stats [zsum|zsq|xsum|xsq]
    foldstats<<<2, 256, 0, stream>>>(STrep, ST + 768);
    // BN + residual (vectorized short8 update over padded slabs)
    ncl_updatez_pair8<<<(unsigned)((size_t)NS * KH / 8 / 256), 256, 0, stream>>>(
        ZHi, ZLo, ARHi, ARLo, beg + i * RR, beb + i * RR, ST + 768, ST + 768 + 128);
    ncl_update<3><<<((unsigned)NS * DN + 255) / 256, 256, 0, stream>>>(
        Xb, X1, bng + i * RR, bnb + i * RR, ST + 768 + 256, ST + 768 + 384,
        1.f / (float)(NS * 3), (unsigned)NS * DN);
    // heads on updated Z and X
    head384(i + 1, 640 + (i + 1) * 384);
    head128(i + 1, (i + 1) * HD);
  }

  // c1: h = relu(XZb @ c1_w^T + b) via bf16 MFMA split-K=4
  gemm_mfma_tn<<<dim3(C1O / 128, NS / 128, 4), 256, 0, stream>>>(
      XZb, XZC, c1wh, XZC, HH, C1O, 0, XZC / 32);
  hpost<<<((unsigned)NS * C1O + 255) / 256, 256, 0, stream>>>(HH, fc1b, (unsigned)NS * C1O);
  c2k<<<NS, 256, 0, stream>>>(HH, fc2w, fc2b, out);
}

// Round 8
// 2505.464 us; speedup vs baseline: 1.5195x; 1.0241x over previous
//
#include <hip/hip_runtime.h>
#include <hip/hip_bf16.h>

#define NS  2048
#define RR  116
#define LLY 4
#define HD  128
#define DN  348
#define DE  13456
#define KH  16384    // 128x128 per-sample slab
#define SP  136      // padded LDS slab row stride (ushorts)
#define XZC 2560
#define C1O 1024
#define EPSF 1e-5f
#define NREP 64      // stat-replica buckets

typedef __attribute__((ext_vector_type(8))) short short8;
typedef __attribute__((ext_vector_type(4))) float floatx4;

static __device__ __forceinline__ ushort f2bf(float x) {
  union { __hip_bfloat16 b; ushort u; } cv;
  cv.b = __float2bfloat16(x);
  return cv.u;
}
static __device__ __forceinline__ float bf2f(ushort u) {
  union { ushort u; __hip_bfloat16 b; } cv;
  cv.u = u;
  return __bfloat162float(cv.b);
}
static __device__ __forceinline__ float fexp2(float x) {
#if __has_builtin(__builtin_amdgcn_exp2f)
  return __builtin_amdgcn_exp2f(x);
#else
  return exp2f(x);
#endif
}

#define GLDS16(gsrc, ldst) __builtin_amdgcn_global_load_lds( \
    (const __attribute__((address_space(1))) unsigned int*)(gsrc), \
    (__attribute__((address_space(3))) unsigned int*)(ldst), 16, 0, 0)

// ---------------------------------------------------------------------------
// fp32 tiled GEMM (node heads), split-K atomic accumulate (bias/relu/stats in
// headpost afterwards). C must be pre-zeroed.
// ---------------------------------------------------------------------------
__global__ __launch_bounds__(256) void gemm64(
    const float* __restrict__ A, int lda,
    const float* __restrict__ B, int ldb,
    float* __restrict__ C, int ldc, int cof,
    int M, int N, int K)
{
  const int m0 = blockIdx.y * 64, n0 = blockIdx.x * 64;
  const int ktiles = (K + 15) >> 4;
  const int kt0 = (int)((long long)ktiles * blockIdx.z / gridDim.z);
  const int kt1 = (int)((long long)ktiles * (blockIdx.z + 1) / gridDim.z);
  __shared__ float As[16][68];
  __shared__ float Bs[16][68];
  const int t = threadIdx.x;
  const int tx = t & 15, ty = t >> 4;
  float acc[4][4] = {};
  for (int kt = kt0; kt < kt1; kt++) {
    const int kb = kt * 16;
    {
      int mm = t >> 2, kk = (t & 3) << 2;
      int gm = m0 + mm, gk = kb + kk;
      float4 v = make_float4(0.f, 0.f, 0.f, 0.f);
      if (gm < M && gk < K) v = *(const float4*)(A + (size_t)gm * lda + gk);
      As[kk + 0][mm] = v.x; As[kk + 1][mm] = v.y; As[kk + 2][mm] = v.z; As[kk + 3][mm] = v.w;
      int gn = n0 + mm;
      float4 u = make_float4(0.f, 0.f, 0.f, 0.f);
      if (gn < N && gk < K) u = *(const float4*)(B + (size_t)gn * ldb + gk);
      Bs[kk + 0][mm] = u.x; Bs[kk + 1][mm] = u.y; Bs[kk + 2][mm] = u.z; Bs[kk + 3][mm] = u.w;
    }
    __syncthreads();
#pragma unroll
    for (int kk = 0; kk < 16; kk++) {
      float4 av = *(const float4*)&As[kk][ty << 2];
      float4 bv = *(const float4*)&Bs[kk][tx << 2];
      acc[0][0] += av.x * bv.x; acc[0][1] += av.x * bv.y; acc[0][2] += av.x * bv.z; acc[0][3] += av.x * bv.w;
      acc[1][0] += av.y * bv.x; acc[1][1] += av.y * bv.y; acc[1][2] += av.y * bv.z; acc[1][3] += av.y * bv.w;
      acc[2][0] += av.z * bv.x; acc[2][1] += av.z * bv.y; acc[2][2] += av.z * bv.z; acc[2][3] += av.z * bv.w;
      acc[3][0] += av.w * bv.x; acc[3][1] += av.w * bv.y; acc[3][2] += av.w * bv.z; acc[3][3] += av.w * bv.w;
    }
    __syncthreads();
  }
#pragma unroll
  for (int i = 0; i < 4; i++) {
    int m = m0 + (ty << 2) + i;
#pragma unroll
    for (int j = 0; j < 4; j++) {
      int n = n0 + (tx << 2) + j;
      if (m < M && n < N)
        atomicAdd(&C[(size_t)m * ldc + cof + n], acc[i][j]);
    }
  }
}

// ---------------------------------------------------------------------------
// bf16 MFMA TN GEMM (big heads): C += A[M][lka]*B[N][lkb]^T, split-K atomics.
// Single-buffer stage->barrier->compute->barrier (proven R2 structure).
// ---------------------------------------------------------------------------
__global__ __launch_bounds__(256) void gemm_mfma_tn(
    const ushort* __restrict__ A, int lka,
    const ushort* __restrict__ B, int lkb,
    float* __restrict__ C, int ldc, int cof,
    int ktiles)
{
  __shared__ __align__(16) ushort As[128 * 32];
  __shared__ __align__(16) ushort Bs[128 * 32];
  const int t = threadIdx.x;
  const int m0 = blockIdx.y * 128, n0 = blockIdx.x * 128;
  const int kt0 = (int)((long long)ktiles * blockIdx.z / gridDim.z);
  const int kt1 = (int)((long long)ktiles * (blockIdx.z + 1) / gridDim.z);
  const int w = t >> 6, lane = t & 63;
  const int wm = (w >> 1) << 6, wn = (w & 1) << 6;
  const int fr = lane & 15, quad = lane >> 4;
  const int row0 = t >> 2, row1 = (t + 256) >> 2;
  const int ko = (t & 3) * 8;
  floatx4 acc[4][4] = {};
  for (int kt = kt0; kt < kt1; ++kt) {
    const int kb = kt * 32;
    GLDS16(A + (size_t)(m0 + row0) * lka + kb + ko, &As[(size_t)t * 8]);
    GLDS16(A + (size_t)(m0 + row1) * lka + kb + ko, &As[(size_t)(t + 256) * 8]);
    GLDS16(B + (size_t)(n0 + row0) * lkb + kb + ko, &Bs[(size_t)t * 8]);
    GLDS16(B + (size_t)(n0 + row1) * lkb + kb + ko, &Bs[(size_t)(t + 256) * 8]);
    __syncthreads();
    short8 af[4], bf[4];
#pragma unroll
    for (int i = 0; i < 4; i++)
      af[i] = *(const short8*)&As[(wm + i * 16 + fr) * 32 + quad * 8];
#pragma unroll
    for (int j = 0; j < 4; j++)
      bf[j] = *(const short8*)&Bs[(wn + j * 16 + fr) * 32 + quad * 8];
#pragma unroll
    for (int i = 0; i < 4; i++)
#pragma unroll
      for (int j = 0; j < 4; j++)
        acc[i][j] = __builtin_amdgcn_mfma_f32_16x16x32_bf16(af[i], bf[j], acc[i][j], 0, 0, 0);
    __syncthreads();
  }
#pragma unroll
  for (int i = 0; i < 4; i++) {
#pragma unroll
    for (int j = 0; j < 4; j++) {
      int n = n0 + wn + j * 16 + fr;
#pragma unroll
      for (int r = 0; r < 4; r++) {
        int m = m0 + wm + i * 16 + quad * 4 + r;
        atomicAdd(&C[(size_t)m * ldc + cof + n], acc[i][j][r]);
      }
    }
  }
}

// ---------------------------------------------------------------------------
// fusedG12 (8 waves / 512 thr): per sample s:
//   G1: Vt = Z @ w2^T + b2  (split-bf16, acc fp32)
//   G2: A = Vt x att        (att generated in-regs, log2-domain)
//   X1 = (A @ X) @ node_w + X-branch BN stats (replica bucket)
// Wave tiling: wm=(w>>2)*64, wn=(w&3)*32 -> acc[4][2]; 2x waves/CU vs R7.
// Same barrier skeleton + same MFMA term order -> bit-identical results.
// ---------------------------------------------------------------------------
__global__ __launch_bounds__(512, 4) void fusedG12(
    const ushort* __restrict__ ZHi, const ushort* __restrict__ ZLo,
    const ushort* __restrict__ WHi, const ushort* __restrict__ WLo,
    const float* __restrict__ b2, const float* __restrict__ Kf,
    ushort* __restrict__ AHi, ushort* __restrict__ ALo,
    const float* __restrict__ Xg, const float* __restrict__ nw,
    float* __restrict__ X1, float* __restrict__ strep)
{
  __shared__ __align__(16) ushort pool[2 * 128 * SP];   // 69632 B
  ushort* VtHi = pool;
  ushort* VtLo = pool + 128 * SP;
  ushort* tAhi = pool;
  ushort* tAlo = pool + 4096;
  ushort* tBhi = pool + 8192;
  ushort* tBlo = pool + 12288;
  __shared__ float Ks0[128], Ks1[128], Ks2[128], Mrow[128], Minv[128];
  __shared__ float Xs[DN];
  const int s = blockIdx.x;
  const int t = threadIdx.x;
  if (t < 128) {
    const float* kf = Kf + (size_t)s * 384;
    const float lam = 1.2011224087864498f;  // sqrt(log2 e)
    Ks0[t] = kf[t] * lam; Ks1[t] = kf[128 + t] * lam; Ks2[t] = kf[256 + t] * lam;
  }
  for (int ii = t; ii < DN; ii += 512) Xs[ii] = Xg[(size_t)s * DN + ii];
  __syncthreads();
  if (t < 128) {
    if (t < RR) {
      float k0 = Ks0[t], k1 = Ks1[t], k2 = Ks2[t];
      float mx = -3.0e38f;
      for (int k = 0; k < RR; k++)
        mx = fmaxf(mx, k0 * Ks0[k] + k1 * Ks1[k] + k2 * Ks2[k]);
      float sm = 0.f;
      for (int k = 0; k < RR; k++)
        sm += fexp2(k0 * Ks0[k] + k1 * Ks1[k] + k2 * Ks2[k] - mx);
      Mrow[t] = mx; Minv[t] = 1.f / sm;
    } else { Mrow[t] = 0.f; Minv[t] = 0.f; }
  }
  const int w = t >> 6, lane = t & 63;
  const int wm = (w >> 2) << 6, wn = (w & 3) << 5;
  const int fr = lane & 15, quad = lane >> 4;
  const int r0 = t >> 2, c8 = (t & 3) * 8;   // 512 thr: full 128x32 tile, 1 ld/thr
  // ---- G1 ----
  floatx4 acc[4][2] = {};
  for (int kt = 0; kt < 4; kt++) {
    const int kb = kt * 32;
    const size_t go = (size_t)s * KH + (size_t)r0 * 128 + kb + c8;
    GLDS16(ZHi + go, &tAhi[t * 8]);
    GLDS16(ZLo + go, &tAlo[t * 8]);
    const size_t wo = (size_t)r0 * 128 + kb + c8;
    GLDS16(WHi + wo, &tBhi[t * 8]);
    GLDS16(WLo + wo, &tBlo[t * 8]);
    __syncthreads();
    short8 ah[4], al[4], bh[2], bl[2];
#pragma unroll
    for (int i = 0; i < 4; i++) {
      ah[i] = *(const short8*)&tAhi[(wm + i * 16 + fr) * 32 + quad * 8];
      al[i] = *(const short8*)&tAlo[(wm + i * 16 + fr) * 32 + quad * 8];
    }
#pragma unroll
    for (int j = 0; j < 2; j++) {
      bh[j] = *(const short8*)&tBhi[(wn + j * 16 + fr) * 32 + quad * 8];
      bl[j] = *(const short8*)&tBlo[(wn + j * 16 + fr) * 32 + quad * 8];
    }
#pragma unroll
    for (int i = 0; i < 4; i++)
#pragma unroll
      for (int j = 0; j < 2; j++) {
        acc[i][j] = __builtin_amdgcn_mfma_f32_16x16x32_bf16(ah[i], bh[j], acc[i][j], 0, 0, 0);
        acc[i][j] = __builtin_amdgcn_mfma_f32_16x16x32_bf16(al[i], bh[j], acc[i][j], 0, 0, 0);
        acc[i][j] = __builtin_amdgcn_mfma_f32_16x16x32_bf16(ah[i], bl[j], acc[i][j], 0, 0, 0);
      }
    __syncthreads();
  }
  // bias + split into LDS Vt slabs (stage buffers dead past this barrier)
#pragma unroll
  for (int i = 0; i < 4; i++) {
#pragma unroll
    for (int j = 0; j < 2; j++) {
      int n = wn + j * 16 + fr;
      float bb = (n < RR) ? b2[n] : 0.f;
#pragma unroll
      for (int r = 0; r < 4; r++) {
        int m = wm + i * 16 + quad * 4 + r;
        float v = acc[i][j][r] + bb;
        ushort h = f2bf(v);
        VtHi[m * SP + n] = h;
        VtLo[m * SP + n] = f2bf(v - bf2f(h));
      }
    }
  }
  __syncthreads();
  // ---- G2 ----
  float Lk0[2], Lk1[2], Lk2[2], Lnm[2];
#pragma unroll
  for (int j = 0; j < 2; j++) {
    int l = wn + j * 16 + fr;
    Lk0[j] = Ks0[l]; Lk1[j] = Ks1[l]; Lk2[j] = Ks2[l]; Lnm[j] = -Mrow[l];
  }
  floatx4 ac2[4][2] = {};
  for (int kt = 0; kt < 4; kt++) {
    const int kb = kt * 32;
    float K0e[8], K1e[8], K2e[8];
#pragma unroll
    for (int e = 0; e < 8; e++) {
      int k = kb + quad * 8 + e;
      K0e[e] = Ks0[k]; K1e[e] = Ks1[k]; K2e[e] = Ks2[k];
    }
    short8 ah[4], al[4];
#pragma unroll
    for (int i = 0; i < 4; i++) {
      ah[i] = *(const short8*)&VtHi[(wm + i * 16 + fr) * SP + kb + quad * 8];
      al[i] = *(const short8*)&VtLo[(wm + i * 16 + fr) * SP + kb + quad * 8];
    }
#pragma unroll
    for (int j = 0; j < 2; j++) {
      // no l/k guards: Vt[:,k>=RR]=0 kills k-pads; Minv[l>=RR]=0 kills l-pads
      short8 bh, bl;
#pragma unroll
      for (int e = 0; e < 8; e++) {
        float d = fmaf(Lk0[j], K0e[e], Lnm[j]);
        d = fmaf(Lk1[j], K1e[e], d);
        d = fmaf(Lk2[j], K2e[e], d);
        float a = fexp2(d);
        ushort h = f2bf(a);
        ((ushort*)&bh)[e] = h;
        ((ushort*)&bl)[e] = f2bf(a - bf2f(h));
      }
#pragma unroll
      for (int i = 0; i < 4; i++) {
        ac2[i][j] = __builtin_amdgcn_mfma_f32_16x16x32_bf16(ah[i], bh, ac2[i][j], 0, 0, 0);
        ac2[i][j] = __builtin_amdgcn_mfma_f32_16x16x32_bf16(al[i], bh, ac2[i][j], 0, 0, 0);
        ac2[i][j] = __builtin_amdgcn_mfma_f32_16x16x32_bf16(ah[i], bl, ac2[i][j], 0, 0, 0);
      }
    }
  }
  // all Vt reads done -> pool reusable as fp32 A [128][133]
  __syncthreads();
  float* Af = (float*)pool;
  ushort* CH = AHi + (size_t)s * KH;
  ushort* CL = ALo + (size_t)s * KH;
#pragma unroll
  for (int i = 0; i < 4; i++) {
#pragma unroll
    for (int j = 0; j < 2; j++) {
      int n = wn + j * 16 + fr;
      float iv = Minv[n];   // 0 for n>=RR -> pad cols stay 0
#pragma unroll
      for (int r = 0; r < 4; r++) {
        int m = wm + i * 16 + quad * 4 + r;
        float v = ac2[i][j][r] * iv;
        ushort h = f2bf(v);
        CH[m * 128 + n] = h;
        CL[m * 128 + n] = f2bf(v - bf2f(h));
        Af[m * 133 + n] = v;
      }
    }
  }
  __syncthreads();
  // ---- X1 = (A @ X) @ node_w + X-branch BN stats (replica bucket) ----
  if (t < RR) {
    float t0 = 0.f, t1 = 0.f, t2 = 0.f;
    const float* ar = Af + t * 133;
    for (int l = 0; l < RR; l++) {
      float p = ar[l];
      t0 += p * Xs[l * 3 + 0];
      t1 += p * Xs[l * 3 + 1];
      t2 += p * Xs[l * 3 + 2];
    }
    float o0 = t0 * nw[0] + t1 * nw[3] + t2 * nw[6];
    float o1 = t0 * nw[1] + t1 * nw[4] + t2 * nw[7];
    float o2 = t0 * nw[2] + t1 * nw[5] + t2 * nw[8];
    float* Op = X1 + (size_t)s * DN + t * 3;
    Op[0] = o0; Op[1] = o1; Op[2] = o2;
    float* rep = strep + (size_t)(s & (NREP - 1)) * 512;
    atomicAdd(&rep[256 + t], o0 + o1 + o2);
    atomicAdd(&rep[384 + t], o0 * o0 + o1 * o1 + o2 * o2);
  }
}

// ---------------------------------------------------------------------------
// fusedG34 (8 waves / 512 thr): per sample s:
//   G3: W1T = (Z @ ewT^T)^T  -> hi/lo slab in LDS
//   G4: Z2 = A @ W1T^T       -> split store in place over A
//   + edge-branch BN stats (channel = row) into replica bucket (s&63)
// ---------------------------------------------------------------------------
__global__ __launch_bounds__(512, 4) void fusedG34(
    const ushort* __restrict__ ZHi, const ushort* __restrict__ ZLo,
    const ushort* __restrict__ EHi, const ushort* __restrict__ ELo,
    ushort* __restrict__ AHi, ushort* __restrict__ ALo,
    float* __restrict__ strep)
{
  __shared__ __align__(16) ushort pool[2 * 128 * SP];   // 69632 B
  ushort* WtHi = pool;
  ushort* WtLo = pool + 128 * SP;
  ushort* tAhi = pool;
  ushort* tAlo = pool + 4096;
  ushort* tBhi = pool + 8192;
  ushort* tBlo = pool + 12288;
  const int s = blockIdx.x;
  const int t = threadIdx.x;
  const int w = t >> 6, lane = t & 63;
  const int wm = (w >> 2) << 6, wn = (w & 3) << 5;
  const int fr = lane & 15, quad = lane >> 4;
  const int r0 = t >> 2, c8 = (t & 3) * 8;
  // ---- G3 ----
  floatx4 acc[4][2] = {};
  for (int kt = 0; kt < 4; kt++) {
    const int kb = kt * 32;
    const size_t go = (size_t)s * KH + (size_t)r0 * 128 + kb + c8;
    GLDS16(ZHi + go, &tAhi[t * 8]);
    GLDS16(ZLo + go, &tAlo[t * 8]);
    const size_t eo = (size_t)r0 * 128 + kb + c8;
    GLDS16(EHi + eo, &tBhi[t * 8]);
    GLDS16(ELo + eo, &tBlo[t * 8]);
    __syncthreads();
    short8 ah[4], al[4], bh[2], bl[2];
#pragma unroll
    for (int i = 0; i < 4; i++) {
      ah[i] = *(const short8*)&tAhi[(wm + i * 16 + fr) * 32 + quad * 8];
      al[i] = *(const short8*)&tAlo[(wm + i * 16 + fr) * 32 + quad * 8];
    }
#pragma unroll
    for (int j = 0; j < 2; j++) {
      bh[j] = *(const short8*)&tBhi[(wn + j * 16 + fr) * 32 + quad * 8];
      bl[j] = *(const short8*)&tBlo[(wn + j * 16 + fr) * 32 + quad * 8];
    }
#pragma unroll
    for (int i = 0; i < 4; i++)
#pragma unroll
      for (int j = 0; j < 2; j++) {
        acc[i][j] = __builtin_amdgcn_mfma_f32_16x16x32_bf16(ah[i], bh[j], acc[i][j], 0, 0, 0);
        acc[i][j] = __builtin_amdgcn_mfma_f32_16x16x32_bf16(al[i], bh[j], acc[i][j], 0, 0, 0);
        acc[i][j] = __builtin_amdgcn_mfma_f32_16x16x32_bf16(ah[i], bl[j], acc[i][j], 0, 0, 0);
      }
    __syncthreads();
  }
  // transposed split store W1 -> W1T slabs (stage buffers dead past barrier)
#pragma unroll
  for (int i = 0; i < 4; i++) {
#pragma unroll
    for (int j = 0; j < 2; j++) {
      int n = wn + j * 16 + fr;
      int mb = wm + i * 16 + quad * 4;
      ushort4 ph, pl;
#pragma unroll
      for (int r = 0; r < 4; r++) {
        float v = acc[i][j][r];
        ushort h = f2bf(v);
        ((ushort*)&ph)[r] = h;
        ((ushort*)&pl)[r] = f2bf(v - bf2f(h));
      }
      *(ushort4*)&WtHi[n * SP + mb] = ph;
      *(ushort4*)&WtLo[n * SP + mb] = pl;
    }
  }
  __syncthreads();
  // ---- G4 ----  (A straight from global; Wt from LDS; no barriers in loop)
  const ushort* GAh = AHi + (size_t)s * KH;
  const ushort* GAl = ALo + (size_t)s * KH;
  floatx4 ac2[4][2] = {};
  for (int kt = 0; kt < 4; kt++) {
    const int kb = kt * 32;
    short8 ah[4], al[4], bh[2], bl[2];
#pragma unroll
    for (int i = 0; i < 4; i++) {
      const size_t ro = (size_t)(wm + i * 16 + fr) * 128 + kb + quad * 8;
      ah[i] = *(const short8*)(GAh + ro);
      al[i] = *(const short8*)(GAl + ro);
    }
#pragma unroll
    for (int j = 0; j < 2; j++) {
      bh[j] = *(const short8*)&WtHi[(wn + j * 16 + fr) * SP + kb + quad * 8];
      bl[j] = *(const short8*)&WtLo[(wn + j * 16 + fr) * SP + kb + quad * 8];
    }
#pragma unroll
    for (int i = 0; i < 4; i++)
#pragma unroll
      for (int j = 0; j < 2; j++) {
        ac2[i][j] = __builtin_amdgcn_mfma_f32_16x16x32_bf16(ah[i], bh[j], ac2[i][j], 0, 0, 0);
        ac2[i][j] = __builtin_amdgcn_mfma_f32_16x16x32_bf16(al[i], bh[j], ac2[i][j], 0, 0, 0);
        ac2[i][j] = __builtin_amdgcn_mfma_f32_16x16x32_bf16(ah[i], bl[j], ac2[i][j], 0, 0, 0);
      }
  }
  // all waves must finish READING A before anyone overwrites it in place
  __syncthreads();
  ushort* CH = AHi + (size_t)s * KH;
  ushort* CL = ALo + (size_t)s * KH;
#pragma unroll
  for (int i = 0; i < 4; i++) {
#pragma unroll
    for (int j = 0; j < 2; j++) {
      int n = wn + j * 16 + fr;
#pragma unroll
      for (int r = 0; r < 4; r++) {
        int m = wm + i * 16 + quad * 4 + r;
        float v = ac2[i][j][r];
        ushort h = f2bf(v);
        CH[m * 128 + n] = h;
        CL[m * 128 + n] = f2bf(v - bf2f(h));
      }
    }
  }
  // edge-branch BN stats: channel = row m; wave's 32 cols via 16-lane shfl
  float* rep = strep + (size_t)(s & (NREP - 1)) * 512;
#pragma unroll
  for (int i = 0; i < 4; i++) {
#pragma unroll
    for (int r = 0; r < 4; r++) {
      int m = wm + i * 16 + quad * 4 + r;
      float a = 0.f, q = 0.f;
#pragma unroll
      for (int j = 0; j < 2; j++) { float v = ac2[i][j][r]; a += v; q += v * v; }
      a += __shfl_xor(a, 1); q += __shfl_xor(q, 1);
      a += __shfl_xor(a, 2); q += __shfl_xor(q, 2);
      a += __shfl_xor(a, 4); q += __shfl_xor(q, 4);
      a += __shfl_xor(a, 8); q += __shfl_xor(q, 8);
      if ((lane & 15) == 0 && m < RR) {
        atomicAdd(&rep[m], a);
        atomicAdd(&rep[128 + m], q);
      }
    }
  }
}

// fold NREP stat replicas [NREP][512] -> final [512]
__global__ __launch_bounds__(256) void foldstats(
    const float* __restrict__ rep, float* __restrict__ outp)
{
  int c = blockIdx.x * 256 + threadIdx.x;   // 512 channels
  float a = 0.f;
  for (int r = 0; r < NREP; r++) a += rep[(size_t)r * 512 + c];
  outp[c] = a;
}

// K precompute: Kf[s][c*128+l] = conv1_w[c]·X[s][l] + b[c]  (0 for l>=RR)
__global__ void kprep(const float* __restrict__ Xb, const float* __restrict__ kw,
                      const float* __restrict__ kb, float* __restrict__ Kf)
{
  int idx = blockIdx.x * 256 + threadIdx.x;
  if (idx >= NS * 384) return;
  int s = idx / 384, r = idx - s * 384;
  int c = r >> 7, l = r & 127;
  float v = 0.f;
  if (l < RR) {
    const float* xp = Xb + (size_t)s * DN + l * 3;
    v = kw[c * 3 + 0] * xp[0] + kw[c * 3 + 1] * xp[1] + kw[c * 3 + 2] * xp[2] + kb[c];
  }
  Kf[idx] = v;
}

// initial Z -> hi/lo slabs (zero-padded)
__global__ __launch_bounds__(256) void cvtZ0(
    const float* __restrict__ Z, ushort* __restrict__ ZHi, ushort* __restrict__ ZLo)
{
  const int s = blockIdx.x;
  const float* Zp = Z + (size_t)s * DE;
  ushort* h = ZHi + (size_t)s * KH;
  ushort* lo = ZLo + (size_t)s * KH;
  for (int idx = threadIdx.x; idx < KH; idx += 256) {
    int l = idx >> 7, i = idx & 127;
    if ((l < RR) && (i < RR)) {
      float v = Zp[l * RR + i];
      ushort hh = f2bf(v);
      h[idx] = hh; lo[idx] = f2bf(v - bf2f(hh));
    } else { h[idx] = 0; lo[idx] = 0; }
  }
}

// weight prep: w2 pair [o][i]; ewT pair [l][k]=ew[k][l]  (padded, all layers)
__global__ void wprep2(const float* __restrict__ w2, const float* __restrict__ ew,
                       ushort* __restrict__ w2Hi, ushort* __restrict__ w2Lo,
                       ushort* __restrict__ eHi, ushort* __restrict__ eLo)
{
  int idx = blockIdx.x * 256 + threadIdx.x;   // 4*16384
  int ly = idx >> 14, k = idx & (KH - 1);
  int r = k >> 7, c = k & 127;
  bool v = (r < RR) && (c < RR);
  float a = v ? w2[ly * DE + r * RR + c] : 0.f;
  float b = v ? ew[ly * DE + c * RR + r] : 0.f;
  ushort ha = f2bf(a), hb = f2bf(b);
  w2Hi[idx] = ha; w2Lo[idx] = f2bf(a - bf2f(ha));
  eHi[idx] = hb; eLo[idx] = f2bf(b - bf2f(hb));
}

// lew head weights: [384][13456] fp32 -> [384][16384] bf16 hole-padded
__global__ void lewprep(const float* __restrict__ src, ushort* __restrict__ dst)
{
  int idx = blockIdx.x * 256 + threadIdx.x;   // 384*16384
  int h = idx >> 14, k = idx & (KH - 1);
  int l = k >> 7, i = k & 127;
  bool v = (l < RR) && (i < RR);
  dst[idx] = v ? f2bf(src[(size_t)h * DE + l * RR + i]) : (ushort)0;
}

// fp32 -> bf16 plain convert (c1 weights)
__global__ void cvt_pad(const float* __restrict__ src, ushort* __restrict__ dst,
                        long long total)
{
  long long idx = (long long)blockIdx.x * 256 + threadIdx.x;
  if (idx < total) dst[idx] = f2bf(src[idx]);
}

// ---------------------------------------------------------------------------
// BN helpers
// ---------------------------------------------------------------------------
__global__ __launch_bounds__(256) void headpost(
    float* __restrict__ Y, int ldy, int cof, int ncols, int chunk,
    const float* __restrict__ bias,
    float* __restrict__ sum, float* __restrict__ sq)
{
  const int cl = threadIdx.x & 63;
  const int c = blockIdx.x * 64 + cl;
  const int r4 = threadIdx.x >> 6;
  const int s0 = blockIdx.y * chunk;
  float a = 0.f, q = 0.f;
  if (c < ncols) {
    float bb = bias[c];
    for (int r = s0 + r4; r < s0 + chunk; r += 4) {
      size_t o = (size_t)r * ldy + cof + c;
      float v = fmaxf(Y[o] + bb, 0.f);
      Y[o] = v;
      a += v; q += v * v;
    }
  }
  __shared__ float la[4][64], lq[4][64];
  la[r4][cl] = a; lq[r4][cl] = q;
  __syncthreads();
  if (threadIdx.x < 64) {
    int cc = blockIdx.x * 64 + threadIdx.x;
    if (cc < ncols) {
      float aa = la[0][threadIdx.x] + la[1][threadIdx.x] + la[2][threadIdx.x] + la[3][threadIdx.x];
      float qq = lq[0][threadIdx.x] + lq[1][threadIdx.x] + lq[2][threadIdx.x] + lq[3][threadIdx.x];
      atomicAdd(&sum[cc], aa);
      atomicAdd(&sq[cc], qq);
    }
  }
}

template<int NC>
__global__ void colnormb(const float* __restrict__ Y, ushort* __restrict__ Yb,
                         int ldy, int cof, float rinv,
                         const float* __restrict__ sum, const float* __restrict__ sq,
                         const float* __restrict__ g, const float* __restrict__ b,
                         unsigned total)
{
  unsigned idx = blockIdx.x * 256u + threadIdx.x;
  if (idx >= total) return;
  unsigned r = idx / NC, c = idx - r * NC;
  float m = sum[c] * rinv;
  float v = sq[c] * rinv - m * m;
  float iv = rsqrtf(v + EPSF);
  size_t o = (size_t)r * ldy + cof + c;
  Yb[o] = f2bf((Y[o] - m) * iv * g[c] + b[c]);
}

// Z master (hi/lo) += relu(bn(Z2 pair)) — vectorized short8 over padded slabs.
__global__ __launch_bounds__(256) void ncl_updatez_pair8(
    ushort* __restrict__ ZHi, ushort* __restrict__ ZLo,
    const ushort* __restrict__ Z2Hi, const ushort* __restrict__ Z2Lo,
    const float* __restrict__ g, const float* __restrict__ b,
    const float* __restrict__ sum, const float* __restrict__ sq)
{
  const unsigned idx = blockIdx.x * 256u + threadIdx.x;   // NS*KH/8 threads
  const unsigned e8 = idx * 8u;
  const unsigned s = e8 >> 14;            // /KH
  const unsigned o = e8 & (KH - 1);
  const unsigned i = o >> 7;              // channel (row)
  const unsigned l0 = o & 127;            // col start (multiple of 8)
  if (i >= RR) return;                     // pad rows stay zero
  const float invcnt = 1.f / (float)(NS * RR);
  const float m = sum[i] * invcnt;
  const float v = sq[i] * invcnt - m * m;
  const float iv = rsqrtf(v + EPSF);
  const float gg = g[i], bb = b[i];
  const size_t off = (size_t)s * KH + o;
  short8 z2h = *(const short8*)(Z2Hi + off);
  short8 z2l = *(const short8*)(Z2Lo + off);
  short8 zh  = *(const short8*)(ZHi + off);
  short8 zl  = *(const short8*)(ZLo + off);
  short8 oh, ol;
#pragma unroll
  for (int e = 0; e < 8; e++) {
    unsigned l = l0 + e;
    if (l < RR) {
      float z2 = bf2f(((const ushort*)&z2h)[e]) + bf2f(((const ushort*)&z2l)[e]);
      float z = (z2 - m) * iv * gg + bb;
      float nv = bf2f(((const ushort*)&zh)[e]) + bf2f(((const ushort*)&zl)[e]) + fmaxf(z, 0.f);
      ushort h = f2bf(nv);
      ((ushort*)&oh)[e] = h;
      ((ushort*)&ol)[e] = f2bf(nv - bf2f(h));
    } else {
      ((ushort*)&oh)[e] = 0;
      ((ushort*)&ol)[e] = 0;
    }
  }
  *(short8*)(ZHi + off) = oh;
  *(short8*)(ZLo + off) = ol;
}

template<int LC>
__global__ void ncl_update(float* __restrict__ dst, const float* __restrict__ src,
                           const float* __restrict__ g, const float* __restrict__ b,
                           const float* __restrict__ sum, const float* __restrict__ sq,
                           float invcnt, unsigned total)
{
  unsigned idx = blockIdx.x * 256u + threadIdx.x;
  if (idx >= total) return;
  int c = (int)((idx / LC) % RR);
  float m = sum[c] * invcnt;
  float v = sq[c] * invcnt - m * m;
  float iv = rsqrtf(v + EPSF);
  float z = (src[idx] - m) * iv * g[c] + b[c];
  dst[idx] += fmaxf(z, 0.f);
}

__global__ void hpost(float* __restrict__ Hh, const float* __restrict__ b, unsigned total)
{
  unsigned idx = blockIdx.x * 256u + threadIdx.x;
  if (idx >= total) return;
  Hh[idx] = fmaxf(Hh[idx] + b[idx & (C1O - 1)], 0.f);
}

__global__ __launch_bounds__(256) void c2k(const float* __restrict__ Hh,
                                           const float* __restrict__ w,
                                           const float* __restrict__ b,
                                           float* __restrict__ out)
{
  const int s = blockIdx.x;
  float a0 = 0.f, a1 = 0.f;
  for (int j = threadIdx.x; j < C1O; j += 256) {
    float h = Hh[(size_t)s * C1O + j];
    a0 += h * w[j];
    a1 += h * w[C1O + j];
  }
  for (int o = 32; o; o >>= 1) { a0 += __shfl_down(a0, o); a1 += __shfl_down(a1, o); }
  __shared__ float p0[4], p1[4];
  const int wv = threadIdx.x >> 6;
  if ((threadIdx.x & 63) == 0) { p0[wv] = a0; p1[wv] = a1; }
  __syncthreads();
  if (threadIdx.x == 0) {
    out[s * 2 + 0] = p0[0] + p0[1] + p0[2] + p0[3] + b[0];
    out[s * 2 + 1] = p1[0] + p1[1] + p1[2] + p1[3] + b[1];
  }
}

// ---------------------------------------------------------------------------
extern "C" void kernel_launch(void* const* d_in, const int* in_sizes, int n_in,
                              void* d_out, int out_size, void* d_ws, size_t ws_size,
                              hipStream_t stream)
{
  const float* X    = (const float*)d_in[0];
  const float* Z    = (const float*)d_in[1];
  const float* cv1w = (const float*)d_in[2];
  const float* cv1b = (const float*)d_in[3];
  const float* cv2w = (const float*)d_in[4];
  const float* cv2b = (const float*)d_in[5];
  const float* nw   = (const float*)d_in[6];
  const float* ew   = (const float*)d_in[7];
  const float* bng  = (const float*)d_in[8];
  const float* bnb  = (const float*)d_in[9];
  const float* beg  = (const float*)d_in[10];
  const float* beb  = (const float*)d_in[11];
  const float* lnw  = (const float*)d_in[12];
  const float* lnb  = (const float*)d_in[13];
  const float* lng  = (const float*)d_in[14];
  const float* lnbt = (const float*)d_in[15];
  const float* lew  = (const float*)d_in[16];
  const float* leb  = (const float*)d_in[17];
  const float* leg  = (const float*)d_in[18];
  const float* lebt = (const float*)d_in[19];
  const float* fc1w = (const float*)d_in[20];
  const float* fc1b = (const float*)d_in[21];
  const float* fc2w = (const float*)d_in[22];
  const float* fc2b = (const float*)d_in[23];
  float* out = (float*)d_out;

  // workspace layout (~320 MiB total, well under proven 381.5 MB)
  char* base = (char*)d_ws;
  ushort* ZHi  = (ushort*)base;                     base += (size_t)NS * KH * 2;
  ushort* ZLo  = (ushort*)base;                     base += (size_t)NS * KH * 2;
  ushort* ARHi = (ushort*)base;                     base += (size_t)NS * KH * 2;
  ushort* ARLo = (ushort*)base;                     base += (size_t)NS * KH * 2;
  ushort* XZb  = (ushort*)base;                     base += (size_t)NS * XZC * 2;
  ushort* c1wh = (ushort*)base;                     base += (size_t)C1O * XZC * 2;
  ushort* lewh = (ushort*)base;                     base += (size_t)384 * KH * 2;
  ushort* w2Hi = (ushort*)base;                     base += (size_t)4 * KH * 2;
  ushort* w2Lo = (ushort*)base;                     base += (size_t)4 * KH * 2;
  ushort* eHi  = (ushort*)base;                     base += (size_t)4 * KH * 2;
  ushort* eLo  = (ushort*)base;                     base += (size_t)4 * KH * 2;
  float* Xb = (float*)base;                         base += (size_t)NS * DN * 4;
  float* X1 = (float*)base;                         base += (size_t)NS * DN * 4;
  float* XZ = (float*)base;                         base += (size_t)NS * XZC * 4;
  float* HH = (float*)base;                         base += (size_t)NS * C1O * 4;
  float* Kf = (float*)base;                         base += (size_t)NS * 384 * 4;
  float* ST = (float*)base;                         base += 2048 * 4;
  float* STrep = (float*)base;   // NREP x 512 replicated stat buckets

  hipMemcpyAsync(Xb, X, sizeof(float) * (size_t)NS * DN, hipMemcpyDeviceToDevice, stream);
  hipMemsetAsync(XZ, 0, sizeof(float) * (size_t)NS * XZC, stream);
  hipMemsetAsync(HH, 0, sizeof(float) * (size_t)NS * C1O, stream);
  cvt_pad<<<(unsigned)(((long long)C1O * XZC + 255) / 256), 256, 0, stream>>>(
      fc1w, c1wh, (long long)C1O * XZC);
  wprep2<<<(4 * KH) / 256, 256, 0, stream>>>(cv2w, ew, w2Hi, w2Lo, eHi, eLo);
  cvtZ0<<<NS, 256, 0, stream>>>(Z, ZHi, ZLo);

  const float rinv = 1.f / (float)NS;

  auto head384 = [&](int hd, int cof) {
    lewprep<<<(384 * KH) / 256, 256, 0, stream>>>(lew + (size_t)hd * 384 * DE, lewh);
    gemm_mfma_tn<<<dim3(3, 16, 12), 256, 0, stream>>>(
        ZHi, KH, lewh, KH, XZ, XZC, cof, KH / 32);
    hipMemsetAsync(ST, 0, sizeof(float) * 768, stream);
    headpost<<<dim3(6, 8), 256, 0, stream>>>(XZ, XZC, cof, 384, 256,
                                             leb + hd * 384, ST, ST + 384);
    colnormb<384><<<(NS * 384 + 255) / 256, 256, 0, stream>>>(
        XZ, XZb, XZC, cof, rinv, ST, ST + 384, leg + hd * 384, lebt + hd * 384, NS * 384);
  };
  auto head128 = [&](int hd, int cof) {
    gemm64<<<dim3(2, NS / 64, 4), 256, 0, stream>>>(
        Xb, DN, lnw + (size_t)hd * HD * DN, DN, XZ, XZC, cof, NS, HD, DN);
    hipMemsetAsync(ST, 0, sizeof(float) * 768, stream);
    headpost<<<dim3(2, 8), 256, 0, stream>>>(XZ, XZC, cof, HD, 256,
                                             lnb + hd * HD, ST, ST + 384);
    colnormb<HD><<<(NS * HD + 255) / 256, 256, 0, stream>>>(
        XZ, XZb, XZC, cof, rinv, ST, ST + 384, lng + hd * HD, lnbt + hd * HD, NS * HD);
  };

  head128(0, 0);
  head384(0, 640);

  for (int i = 0; i < LLY; i++) {
    // K for this layer (old X)
    kprep<<<(NS * 384 + 255) / 256, 256, 0, stream>>>(Xb, cv1w + i * 9, cv1b + i * 3, Kf);
    // zero replicated stat buckets (filled by fused epilogues below)
    hipMemsetAsync(STrep, 0, sizeof(float) * NREP * 512, stream);
    // G1+G2 fused + in-block X1 (=pTx_node) + X-branch stats (replicated)
    fusedG12<<<NS, 512, 0, stream>>>(ZHi, ZLo, w2Hi + (size_t)i * KH, w2Lo + (size_t)i * KH,
                                     cv2b + i * RR, Kf, ARHi, ARLo,
                                     Xb, nw + i * 9, X1, STrep);
    // G3+G4 fused: Z2 pair in place over A_ref pair + edge stats (replicated)
    fusedG34<<<NS, 512, 0, stream>>>(ZHi, ZLo, eHi + (size_t)i * KH, eLo + (size_t)i * KH,
                                     ARHi, ARLo, STrep);
    // fold replicas -> final stats [zsum|zsq|xsum|xsq]
    foldstats<<<2, 256, 0, stream>>>(STrep, ST + 768);
    // BN + residual (vectorized short8 update over padded slabs)
    ncl_updatez_pair8<<<(unsigned)((size_t)NS * KH / 8 / 256), 256, 0, stream>>>(
        ZHi, ZLo, ARHi, ARLo, beg + i * RR, beb + i * RR, ST + 768, ST + 768 + 128);
    ncl_update<3><<<((unsigned)NS * DN + 255) / 256, 256, 0, stream>>>(
        Xb, X1, bng + i * RR, bnb + i * RR, ST + 768 + 256, ST + 768 + 384,
        1.f / (float)(NS * 3), (unsigned)NS * DN);
    // heads on updated Z and X
    head384(i + 1, 640 + (i + 1) * 384);
    head128(i + 1, (i + 1) * HD);
  }

  // c1: h = relu(XZb @ c1_w^T + b) via bf16 MFMA split-K=4
  gemm_mfma_tn<<<dim3(C1O / 128, NS / 128, 4), 256, 0, stream>>>(
      XZb, XZC, c1wh, XZC, HH, C1O, 0, XZC / 32);
  hpost<<<((unsigned)NS * C1O + 255) / 256, 256, 0, stream>>>(HH, fc1b, (unsigned)NS * C1O);
  c2k<<<NS, 256, 0, stream>>>(HH, fc2w, fc2b, out);
}